// Round 8
// baseline (1316.575 us; speedup 1.0000x reference)
//
#include <hip/hip_runtime.h>
#include <hip/hip_bf16.h>

// ============================================================================
// TransformerChoiceNet forward. Round 22: r6 full-N weight-resident GEMM +
// (1) split W-stage: half staged before barrier1, half loaded to regs AFTER
//     barrier1 (flies under half-1 MFMAs), ds_write + barrier2, compute rest.
// (2) independent GEMMs merged into multi-job dispatches (emb pair, 3x QKV).
// (3) A-prefetch 2 kc deep. Attention = r7 (process-before-PV, K 3-deep).
// B=128 S=512 D=64 H=256 NH=8 HD=32, M=B*S=65536.
// ============================================================================

#define Bb  128
#define Ss  512
#define Hh  256
#define NHh 8
#define Mm  (Bb*Ss)

typedef unsigned short bf16_t;
typedef __attribute__((ext_vector_type(8))) short short8;
typedef __attribute__((ext_vector_type(4))) float f32x4;

__device__ __forceinline__ float bf2f(bf16_t h){
  union { unsigned int u; float f; } v; v.u = ((unsigned int)h)<<16; return v.f;
}
__device__ __forceinline__ bf16_t f2bf(float f){
  union { float f; unsigned int u; } v; v.f = f;
  unsigned int r = (v.u + 0x7fffu + ((v.u>>16)&1u)) >> 16;   // RNE
  return (bf16_t)r;
}
__device__ __forceinline__ unsigned pk_bf16(float a, float b){  // packed RNE cvt
  union { __hip_bfloat162 h; unsigned u; } v;
  v.h = __float22bfloat162_rn(float2{a,b});
  return v.u;
}
__device__ __forceinline__ short8 ld_bf8(const bf16_t* p){   // 16B load
  union { uint4 u; short8 s; } v; v.u = *(const uint4*)p; return v.s;
}
__device__ __forceinline__ void gload16(const bf16_t* g, bf16_t* l){
  __builtin_amdgcn_global_load_lds(
      (const __attribute__((address_space(1))) void*)g,
      (__attribute__((address_space(3))) void*)l, 16, 0, 0);
}
__device__ __forceinline__ float exp2_hw(float x){           // native 2^x
  float r; asm("v_exp_f32 %0, %1" : "=v"(r) : "v"(x)); return r;
}
__device__ __forceinline__ float gelu_f(float x){
  // NewGELU; tanh via native exp + rcp: tanh(u) = 1 - 2/(e^{2u}+1)
  float u = 0.7978845608028654f*(x + 0.044715f*x*x*x);
  float e = __expf(2.0f*u);
  float th = 1.0f - 2.0f*__builtin_amdgcn_rcpf(e + 1.0f);
  return 0.5f*x*(1.0f + th);
}

// ---------------- weight prep: fp32 W[k][n] -> bf16 Wt[n][k] ------------------
struct PrepDesc { const float* s; unsigned off; int K; };
struct Prep18  { PrepDesc d[18]; };

__global__ __launch_bounds__(256) void k_prep(Prep18 p, bf16_t* __restrict__ arena)
{
  PrepDesc dd = p.d[blockIdx.y];
  int i = blockIdx.x*256 + threadIdx.x;
  if (i < dd.K*256){
    int k = i>>8, n = i&255;
    arena[dd.off + n*dd.K + k] = f2bf(dd.s[i]);
  }
}

// ---------------- LN0 (two gains) + valid mask; bf16 out ----------------------
__global__ __launch_bounds__(256) void k_ln0(const float* __restrict__ src,
    const float* __restrict__ gs, const float* __restrict__ bs,
    const float* __restrict__ gt, const float* __restrict__ bt,
    bf16_t* __restrict__ xs, bf16_t* __restrict__ xt, float* __restrict__ valid)
{
  int row  = blockIdx.x*4 + (threadIdx.x>>6);
  int lane = threadIdx.x & 63;
  float x = src[(size_t)row*64 + lane];
  float s = x;
  #pragma unroll
  for (int o=32;o>0;o>>=1) s += __shfl_xor(s,o);
  float mean = s*(1.0f/64.0f);
  float d = x - mean;
  float ss = d*d;
  #pragma unroll
  for (int o=32;o>0;o>>=1) ss += __shfl_xor(ss,o);
  float r = rsqrtf(ss*(1.0f/64.0f) + 1e-5f);
  float xn = d*r;
  xs[(size_t)row*64+lane] = f2bf(xn*gs[lane] + bs[lane]);
  xt[(size_t)row*64+lane] = f2bf(xn*gt[lane] + bt[lane]);
  if (lane==0) valid[row] = (s != 0.0f) ? 1.0f : 0.0f;
}

// ---------------- weight-resident GEMM core (split stage, 2-deep A) -----------
// Block = 512 thr (8 waves), 256 rows/block, 32 rows/wave, full N=256.
// Ws frag layout: Ws[(kc*16+nt)*512 + lane*8] (16B per lane slot).
// Wave w stages nt = {2w, 2w+1} for every kc. Half1 (kc<NKC/2) -> gload16
// before barrier1; half2 -> reg loads AFTER barrier1 (fly under half-1 MFMA),
// ds_write, barrier2, compute.
template<int KK>
__device__ __forceinline__ void wgemm_core(const bf16_t* __restrict__ A,
    const bf16_t* __restrict__ Wt, bf16_t* Ws,
    int r0, int w, int lane, int l15, int quad,
    f32x4 (&acc0)[16], f32x4 (&acc1)[16])
{
  constexpr int NKC = KK/32;        // 8 (K=256) / 2 (K=64)
  constexpr int H1  = NKC/2;
  constexpr int WH  = NKC;          // per-thread reg loads in half2 = NKC... (2 per kc, NKC/2 kcs)

  // A prefetch ring, 2 deep
  short8 af[3][2];
  af[0][0] = ld_bf8(A + (size_t)(r0      + l15)*KK + quad*8);
  af[0][1] = ld_bf8(A + (size_t)(r0 + 16 + l15)*KK + quad*8);
  af[1][0] = ld_bf8(A + (size_t)(r0      + l15)*KK + 32 + quad*8);
  af[1][1] = ld_bf8(A + (size_t)(r0 + 16 + l15)*KK + 32 + quad*8);

  // W half1 -> LDS direct (2 nt per kc per wave)
  #pragma unroll
  for (int j=0; j<H1*2; j++){
    int kc = j>>1, nt = w*2 + (j&1);
    gload16(Wt + (size_t)(nt*16 + l15)*KK + kc*32 + quad*8,
            &Ws[(kc*16 + nt)*512]);
  }
  __syncthreads();                       // half1 in LDS (+A0/A1 in regs)

  // W half2 -> regs (in flight under half-1 compute)
  uint4 wreg[H1*2];
  #pragma unroll
  for (int j=0; j<H1*2; j++){
    int kc = H1 + (j>>1), nt = w*2 + (j&1);
    wreg[j] = *(const uint4*)(Wt + (size_t)(nt*16 + l15)*KK + kc*32 + quad*8);
  }

  f32x4 z = {0.f,0.f,0.f,0.f};
  #pragma unroll
  for (int nt=0; nt<16; nt++){ acc0[nt] = z; acc1[nt] = z; }

  #pragma unroll
  for (int kc=0; kc<H1; kc++){
    if (kc+2 < NKC){
      af[(kc+2)%3][0] = ld_bf8(A + (size_t)(r0      + l15)*KK + (kc+2)*32 + quad*8);
      af[(kc+2)%3][1] = ld_bf8(A + (size_t)(r0 + 16 + l15)*KK + (kc+2)*32 + quad*8);
    }
    short8 a0 = af[kc%3][0], a1 = af[kc%3][1];
    #pragma unroll
    for (int nt=0; nt<16; nt++){
      short8 b = ld_bf8(&Ws[(kc*16 + nt)*512 + lane*8]);
      acc0[nt] = __builtin_amdgcn_mfma_f32_16x16x32_bf16(a0, b, acc0[nt], 0,0,0);
      acc1[nt] = __builtin_amdgcn_mfma_f32_16x16x32_bf16(a1, b, acc1[nt], 0,0,0);
    }
  }
  // write half2 W to LDS (waits only on wreg arrival)
  #pragma unroll
  for (int j=0; j<H1*2; j++){
    int kc = H1 + (j>>1), nt = w*2 + (j&1);
    *(uint4*)&Ws[(kc*16 + nt)*512 + lane*8] = wreg[j];
  }
  __syncthreads();                       // half2 visible
  #pragma unroll
  for (int kc=H1; kc<NKC; kc++){
    if (kc+2 < NKC){
      af[(kc+2)%3][0] = ld_bf8(A + (size_t)(r0      + l15)*KK + (kc+2)*32 + quad*8);
      af[(kc+2)%3][1] = ld_bf8(A + (size_t)(r0 + 16 + l15)*KK + (kc+2)*32 + quad*8);
    }
    short8 a0 = af[kc%3][0], a1 = af[kc%3][1];
    #pragma unroll
    for (int nt=0; nt<16; nt++){
      short8 b = ld_bf8(&Ws[(kc*16 + nt)*512 + lane*8]);
      acc0[nt] = __builtin_amdgcn_mfma_f32_16x16x32_bf16(a0, b, acc0[nt], 0,0,0);
      acc1[nt] = __builtin_amdgcn_mfma_f32_16x16x32_bf16(a1, b, acc1[nt], 0,0,0);
    }
  }
}

// ---------------- merged independent GEMMs (jobs via blockIdx.y) --------------
struct WJob  { const bf16_t* A; const bf16_t* Wt; const float* bias; bf16_t* C;
               int outm; float cs; };   // outm: 0 = C[M,256]*cs, 2 = VT pack
struct WJobs { WJob j[3]; };

template<int KK>
__global__ __launch_bounds__(512,2) void k_wqkv(WJobs jobs)
{
  constexpr int NKC = KK/32;
  __shared__ bf16_t Ws[16*NKC*512];
  WJob jb = jobs.j[blockIdx.y];
  int t = threadIdx.x, w = t>>6, lane = t&63, l15 = lane&15, quad = lane>>4;
  int r0 = blockIdx.x*256 + w*32;

  f32x4 acc0[16], acc1[16];
  wgemm_core<KK>(jb.A, jb.Wt, Ws, r0, w, lane, l15, quad, acc0, acc1);

  float bv[16];
  #pragma unroll
  for (int nt=0; nt<16; nt++) bv[nt] = jb.bias[nt*16 + l15];

  if (jb.outm == 0){
    float cs = jb.cs;
    auto epi = [&](f32x4 (&ac)[16], int tt){
      int rowb = r0 + tt*16 + quad*4;
      #pragma unroll
      for (int nt=0; nt<16; nt++)
        #pragma unroll
        for (int r=0; r<4; r++)
          jb.C[(size_t)(rowb + r)*256 + nt*16 + l15] = f2bf((ac[nt][r] + bv[nt])*cs);
    };
    epi(acc0, 0); epi(acc1, 1);
  } else {
    auto epi = [&](f32x4 (&ac)[16], int tt){
      int m = r0 + tt*16 + quad*4;
      #pragma unroll
      for (int nt=0; nt<16; nt++){
        int col = nt*16 + l15;
        uint2 pk = { pk_bf16(ac[nt][0]+bv[nt], ac[nt][1]+bv[nt]),
                     pk_bf16(ac[nt][2]+bv[nt], ac[nt][3]+bv[nt]) };
        *(uint2*)&jb.C[((size_t)((m>>9)*256 + col))*512 + (m&511)] = pk;
      }
    };
    epi(acc0, 0); epi(acc1, 1);
  }
}

// ---------------- single GEMMs with fused epilogues ---------------------------
// OUTM: 0 bf16 C (EPI 0=id / 1=gelu) | 3 LN(Pres+(acc+b)) -> bf16 |
//       5 LN -> dot outW -> fp32 logits.
template<int EPI, int OUTM, int KK>
__global__ __launch_bounds__(512,2) void k_wgemm(const bf16_t* __restrict__ A,
    const bf16_t* __restrict__ Wt, const float* __restrict__ bias,
    void* __restrict__ Cv, const bf16_t* __restrict__ Pres,
    const float* __restrict__ g, const float* __restrict__ bb,
    const float* __restrict__ oW, const float* __restrict__ obp)
{
  constexpr int NKC = KK/32;
  __shared__ bf16_t Ws[16*NKC*512];
  int t = threadIdx.x, w = t>>6, lane = t&63, l15 = lane&15, quad = lane>>4;
  int r0 = blockIdx.x*256 + w*32;

  f32x4 acc0[16], acc1[16];
  wgemm_core<KK>(A, Wt, Ws, r0, w, lane, l15, quad, acc0, acc1);

  float bv[16];
  #pragma unroll
  for (int nt=0; nt<16; nt++) bv[nt] = bias[nt*16 + l15];

  if (OUTM==0){
    auto epi = [&](f32x4 (&ac)[16], int tt){
      int rowb = r0 + tt*16 + quad*4;
      #pragma unroll
      for (int nt=0; nt<16; nt++)
        #pragma unroll
        for (int r=0; r<4; r++){
          float v = ac[nt][r] + bv[nt];
          if (EPI==1) v = gelu_f(v);
          ((bf16_t*)Cv)[(size_t)(rowb + r)*256 + nt*16 + l15] = f2bf(v);
        }
    };
    epi(acc0, 0); epi(acc1, 1);
  } else {
    float gv[16], bbv[16], wv[16];
    #pragma unroll
    for (int nt=0; nt<16; nt++){ gv[nt] = g[nt*16+l15]; bbv[nt] = bb[nt*16+l15]; }
    if (OUTM==5)
      #pragma unroll
      for (int nt=0; nt<16; nt++) wv[nt] = oW[nt*16+l15];
    float ob0 = (OUTM==5) ? obp[0] : 0.f;

    auto epi = [&](f32x4 (&ac)[16], int tt){
      #pragma unroll
      for (int r=0; r<4; r++){
        int row = r0 + tt*16 + quad*4 + r;
        const bf16_t* pr = Pres + (size_t)row*256;
        float v[16]; float s = 0.f, q = 0.f;
        #pragma unroll
        for (int nt=0; nt<16; nt++){
          v[nt] = ac[nt][r] + bv[nt] + bf2f(pr[nt*16 + l15]);
          s += v[nt]; q += v[nt]*v[nt];
        }
        s += __shfl_xor(s,1); s += __shfl_xor(s,2);
        s += __shfl_xor(s,4); s += __shfl_xor(s,8);
        q += __shfl_xor(q,1); q += __shfl_xor(q,2);
        q += __shfl_xor(q,4); q += __shfl_xor(q,8);
        float mean = s*(1.0f/256.0f);
        float var  = q*(1.0f/256.0f) - mean*mean;
        float rstd = rsqrtf(var + 1e-5f);
        if (OUTM==3){
          bf16_t* po = (bf16_t*)Cv + (size_t)row*256;
          #pragma unroll
          for (int nt=0; nt<16; nt++)
            po[nt*16 + l15] = f2bf((v[nt]-mean)*rstd*gv[nt] + bbv[nt]);
        } else {
          float s2 = 0.f;
          #pragma unroll
          for (int nt=0; nt<16; nt++)
            s2 += ((v[nt]-mean)*rstd*gv[nt] + bbv[nt]) * wv[nt];
          s2 += __shfl_xor(s2,1); s2 += __shfl_xor(s2,2);
          s2 += __shfl_xor(s2,4); s2 += __shfl_xor(s2,8);
          if (l15==0) ((float*)Cv)[row] = s2 + ob0;
        }
      }
    };
    epi(acc0, 0); epi(acc1, 1);
  }
}

// ---------------- MFMA attention (r7: process-before-PV, K 3-deep) ------------
__global__ __launch_bounds__(256) void k_attn(const bf16_t* __restrict__ Qm,
    const bf16_t* __restrict__ Km, const bf16_t* __restrict__ VT,
    const float* __restrict__ valid, bf16_t* __restrict__ AO)
{
  __shared__ bf16_t Pbuf[4][2][2][16][40];   // [wave][qtile][slot][q][key] 20 KB
  __shared__ float  Smask[512];              // 0 or -1e10*log2e
  int t = threadIdx.x, wave = t>>6, lane = t&63, l15 = lane&15, quad = lane>>4;
  int lid = blockIdx.x + 8*blockIdx.y + 1024*blockIdx.z;    // dispatch order
  int hp = lid & 3, pb = (lid>>2)&1, g = (lid>>3)&7, bh = lid>>6;
  int h  = hp*2 + (g&1);          // head: pair hp, parity from g
  int qc = g>>1;
  int b  = bh*2 + pb;
  int q0 = qc*128;

  Smask[t]     = (valid[b*Ss + t      ] != 0.f) ? 0.f : -1.44269504e10f;
  Smask[t+256] = (valid[b*Ss + t + 256] != 0.f) ? 0.f : -1.44269504e10f;
  __syncthreads();

  short8 aQ0 = ld_bf8(Qm + (size_t)(b*Ss + q0 + (wave*2  )*16 + l15)*256 + h*32 + quad*8);
  short8 aQ1 = ld_bf8(Qm + (size_t)(b*Ss + q0 + (wave*2+1)*16 + l15)*256 + h*32 + quad*8);
  const bf16_t* Kb = Km + (size_t)(b*Ss)*256 + h*32;          // + key*256
  const bf16_t* Vb = VT + ((size_t)b*256 + h*32)*512;         // + d*512 + key

  f32x4 z = {0.f,0.f,0.f,0.f};
  f32x4 O0[2] = {z,z}, O1[2] = {z,z};
  float ls0 = 0.f, ls1 = 0.f;

  auto process = [&](int kt2n, short8 K0, short8 K1){
    int s = kt2n & 1;
    #pragma unroll
    for (int half=0; half<2; half++){
      short8 aK = half ? K1 : K0;
      int ktile = kt2n*2 + half;
      __builtin_amdgcn_s_setprio(1);
      f32x4 s0 = __builtin_amdgcn_mfma_f32_16x16x32_bf16(aK, aQ0, z, 0,0,0);
      f32x4 s1 = __builtin_amdgcn_mfma_f32_16x16x32_bf16(aK, aQ1, z, 0,0,0);
      __builtin_amdgcn_s_setprio(0);
      float4 mb = *(const float4*)&Smask[ktile*16 + quad*4];
      float p00 = exp2_hw(s0[0] + mb.x);    // Q pre-scaled by QS*log2e
      float p01 = exp2_hw(s0[1] + mb.y);
      float p02 = exp2_hw(s0[2] + mb.z);
      float p03 = exp2_hw(s0[3] + mb.w);
      float p10 = exp2_hw(s1[0] + mb.x);
      float p11 = exp2_hw(s1[1] + mb.y);
      float p12 = exp2_hw(s1[2] + mb.z);
      float p13 = exp2_hw(s1[3] + mb.w);
      ls0 += (p00+p01)+(p02+p03);
      ls1 += (p10+p11)+(p12+p13);
      uint2 w0 = { pk_bf16(p00,p01), pk_bf16(p02,p03) };
      uint2 w1 = { pk_bf16(p10,p11), pk_bf16(p12,p13) };
      *(uint2*)&Pbuf[wave][0][s][l15][half*16 + quad*4] = w0;
      *(uint2*)&Pbuf[wave][1][s][l15][half*16 + quad*4] = w1;
    }
  };
  auto loadK = [&](int n, short8& K0, short8& K1){
    K0 = ld_bf8(Kb + (size_t)((n*2  )*16 + l15)*256 + quad*8);
    K1 = ld_bf8(Kb + (size_t)((n*2+1)*16 + l15)*256 + quad*8);
  };
  auto loadV = [&](int n, short8& V0, short8& V1){
    V0 = ld_bf8(Vb + (size_t)(l15   )*512 + n*32 + quad*8);
    V1 = ld_bf8(Vb + (size_t)(16+l15)*512 + n*32 + quad*8);
  };

  short8 cK0, cK1, pK0, pK1, nK0, nK1, qK0, qK1;
  short8 cV0, cV1, mV0, mV1, nV0, nV1;
  loadK(0, cK0, cK1);
  loadK(1, pK0, pK1);
  loadK(2, nK0, nK1);
  loadV(0, cV0, cV1);
  loadV(1, mV0, mV1);
  process(0, cK0, cK1);            // writes slot 0

  #pragma unroll 2
  for (int kt2=0; kt2<16; kt2++){
    if (kt2+3 < 16) loadK(kt2+3, qK0, qK1);
    if (kt2+2 < 16) loadV(kt2+2, nV0, nV1);
    if (kt2+1 < 16) process(kt2+1, pK0, pK1);   // writes slot (kt2+1)&1
    int s = kt2 & 1;
    short8 aP0 = ld_bf8(&Pbuf[wave][0][s][l15][quad*8]);   // written 1 iter ago
    short8 aP1 = ld_bf8(&Pbuf[wave][1][s][l15][quad*8]);
    __builtin_amdgcn_s_setprio(1);
    O0[0] = __builtin_amdgcn_mfma_f32_16x16x32_bf16(aP0, cV0, O0[0], 0,0,0);
    O0[1] = __builtin_amdgcn_mfma_f32_16x16x32_bf16(aP0, cV1, O0[1], 0,0,0);
    O1[0] = __builtin_amdgcn_mfma_f32_16x16x32_bf16(aP1, cV0, O1[0], 0,0,0);
    O1[1] = __builtin_amdgcn_mfma_f32_16x16x32_bf16(aP1, cV1, O1[1], 0,0,0);
    __builtin_amdgcn_s_setprio(0);
    pK0 = nK0; pK1 = nK1; nK0 = qK0; nK1 = qK1;
    cV0 = mV0; cV1 = mV1; mV0 = nV0; mV1 = nV1;
  }

  ls0 += __shfl_xor(ls0,16); ls0 += __shfl_xor(ls0,32);
  ls1 += __shfl_xor(ls1,16); ls1 += __shfl_xor(ls1,32);
  float linv0 = (ls0 > 0.f) ? 1.0f/ls0 : 0.f;
  float linv1 = (ls1 > 0.f) ? 1.0f/ls1 : 0.f;
  float i0[4], i1[4];
  #pragma unroll
  for (int r=0; r<4; r++){
    i0[r] = __shfl(linv0, quad*4 + r);
    i1[r] = __shfl(linv1, quad*4 + r);
  }
  size_t r0 = (size_t)(b*Ss + q0 + (wave*2  )*16);
  size_t r1 = (size_t)(b*Ss + q0 + (wave*2+1)*16);
  #pragma unroll
  for (int nt=0; nt<2; nt++)
    #pragma unroll
    for (int r=0; r<4; r++){
      AO[(r0 + quad*4 + r)*256 + h*32 + nt*16 + l15] = f2bf(O0[nt][r]*i0[r]);
      AO[(r1 + quad*4 + r)*256 + h*32 + nt*16 + l15] = f2bf(O1[nt][r]*i1[r]);
    }
}

// ---------------- final: p = exp(logits)*valid, normalize per batch -----------
__global__ __launch_bounds__(256) void k_final(const float* __restrict__ L,
    const float* __restrict__ valid, float* __restrict__ out)
{
  __shared__ float wsum[4];
  int b = blockIdx.x, t = threadIdx.x;
  float e0 = __expf(L[b*Ss + t      ]) * valid[b*Ss + t      ];
  float e1 = __expf(L[b*Ss + 256 + t]) * valid[b*Ss + 256 + t];
  float s = e0 + e1;
  #pragma unroll
  for (int o=32;o>0;o>>=1) s += __shfl_xor(s,o);
  if ((t&63)==0) wsum[t>>6] = s;
  __syncthreads();
  float tot = wsum[0]+wsum[1]+wsum[2]+wsum[3];
  out[b*Ss + t      ] = e0/tot;
  out[b*Ss + 256 + t] = e1/tot;
}

// ============================================================================
extern "C" void kernel_launch(void* const* d_in, const int* in_sizes, int n_in,
                              void* d_out, int out_size, void* d_ws, size_t ws_size,
                              hipStream_t stream)
{
  #define F(i) ((const float*)d_in[(i)])
  bool sig = (in_sizes[33] == 256);   // signature order vs dict order
  const float* d_eqW  = F(sig?35:33); const float* d_eqb  = F(sig?36:34);
  const float* d_ekW  = F(sig?37:35); const float* d_ekb  = F(sig?38:36);
  const float* d_evW  = F(sig?39:37); const float* d_evb  = F(sig?40:38);
  const float* d_eoW  = F(sig?41:39); const float* d_eob  = F(sig?42:40);
  const float* d_ln1g = F(sig?33:41); const float* d_ln1b = F(sig?34:42);

  // ---- workspace (~163 MiB) ----
  char* w = (char*)d_ws;
  bf16_t* P0 = (bf16_t*)w; w += (size_t)Mm*Hh*2;   // 32 MiB residual (enc)
  bf16_t* P1 = (bf16_t*)w; w += (size_t)Mm*Hh*2;   // 32 MiB residual (dec)
  bf16_t* H0 = (bf16_t*)w; w += (size_t)Mm*Hh*2;   // 32 MiB Q / AO / gelu
  bf16_t* H1 = (bf16_t*)w;                          // 32 MiB K / xs alias
  bf16_t* xs = (bf16_t*)w; w += (size_t)Mm*Hh*2;
  bf16_t* H2 = (bf16_t*)w;                          // 32 MiB VT / xt alias
  bf16_t* xt = (bf16_t*)w; w += (size_t)Mm*Hh*2;
  bf16_t* Wa = (bf16_t*)w; w += (size_t)(2*16384 + 16*65536)*2;  // 2.1 MiB
  float*  valid  = (float*)w; w += (size_t)Mm*4;
  float*  logits = (float*)w; w += (size_t)Mm*4;
  float* out = (float*)d_out;

  unsigned o_sem = 0, o_tem = 16384;
  unsigned o_w[16]; for (int i=0;i<16;i++) o_w[i] = 32768 + i*65536u;
  Prep18 pp;
  const float* srcs[18] = { F(5), F(7), F(9), F(11), F(13), F(15), F(19), F(21),
                            F(25), F(27), F(29), F(31), d_eqW, d_ekW, d_evW, d_eoW,
                            F(45), F(47) };
  unsigned offs[18] = { o_sem, o_tem, o_w[0],o_w[1],o_w[2],o_w[3],o_w[4],o_w[5],
                        o_w[6],o_w[7],o_w[8],o_w[9],o_w[10],o_w[11],o_w[12],o_w[13],
                        o_w[14],o_w[15] };
  for (int i=0;i<18;i++){ pp.d[i].s = srcs[i]; pp.d[i].off = offs[i]; pp.d[i].K = (i<2)?64:256; }

  dim3 blk(256);
  dim3 blk512(512);
  dim3 gLN(Mm/4);
  dim3 gW(256);                     // 256 rows/block
  dim3 gA(NHh, Bb, 4);
  dim3 gP(256, 18);
  const float* NF = nullptr; const bf16_t* NB = nullptr;
  // 1/sqrt(32) * log2(e) folded into Q so attention uses native exp2
  const float QS = 0.17677669529663687f * 1.4426950408889634f;

  k_prep<<<gP, blk, 0, stream>>>(pp, Wa);
  k_ln0<<<gLN, blk, 0, stream>>>(F(0), F(1),F(2), F(3),F(4), xs, xt, valid);

  // emb pair merged (K=64)
  {
    WJobs js;
    js.j[0] = { xs, Wa+o_sem, F(6), P0, 0, 1.0f };
    js.j[1] = { xt, Wa+o_tem, F(8), P1, 0, 1.0f };
    js.j[2] = js.j[0];
    k_wqkv<64><<<dim3(256,2), blk512, 0, stream>>>(js);
  }

  // ---- encoder ----
  {
    WJobs js;
    js.j[0] = { P0, Wa+o_w[0], F(10), H0, 0, QS  };
    js.j[1] = { P0, Wa+o_w[1], F(12), H1, 0, 1.0f };
    js.j[2] = { P0, Wa+o_w[2], F(14), H2, 2, 1.0f };
    k_wqkv<256><<<dim3(256,3), blk512, 0, stream>>>(js);
  }
  k_attn<<<gA, blk, 0, stream>>>(H0, H1, H2, valid, H0);
  k_wgemm<0,3,256><<<gW, blk512, 0, stream>>>(H0, Wa+o_w[3], F(16), P0, P0, F(17),F(18), NF,NF);
  k_wgemm<1,0,256><<<gW, blk512, 0, stream>>>(P0, Wa+o_w[4], F(20), H0, NB, NF,NF,NF,NF);
  k_wgemm<0,3,256><<<gW, blk512, 0, stream>>>(H0, Wa+o_w[5], F(22), P0, P0, F(23),F(24), NF,NF);

  // ---- decoder self-attention ----
  {
    WJobs js;
    js.j[0] = { P1, Wa+o_w[6], F(26), H0, 0, QS  };
    js.j[1] = { P1, Wa+o_w[7], F(28), H1, 0, 1.0f };
    js.j[2] = { P1, Wa+o_w[8], F(30), H2, 2, 1.0f };
    k_wqkv<256><<<dim3(256,3), blk512, 0, stream>>>(js);
  }
  k_attn<<<gA, blk, 0, stream>>>(H0, H1, H2, valid, H0);
  k_wgemm<0,3,256><<<gW, blk512, 0, stream>>>(H0, Wa+o_w[9], F(32), P1, P1, d_ln1g,d_ln1b, NF,NF);

  // ---- decoder cross-attention: Q from P1, K/V from P0 ----
  {
    WJobs js;
    js.j[0] = { P1, Wa+o_w[10], d_eqb, H0, 0, QS  };
    js.j[1] = { P0, Wa+o_w[11], d_ekb, H1, 0, 1.0f };
    js.j[2] = { P0, Wa+o_w[12], d_evb, H2, 2, 1.0f };
    k_wqkv<256><<<dim3(256,3), blk512, 0, stream>>>(js);
  }
  k_attn<<<gA, blk, 0, stream>>>(H0, H1, H2, valid, H0);
  k_wgemm<0,3,256><<<gW, blk512, 0, stream>>>(H0, Wa+o_w[13], d_eob, P1, P1, F(43),F(44), NF,NF);

  // ---- decoder FFN + fused ln3 + logits ----
  k_wgemm<1,0,256><<<gW, blk512, 0, stream>>>(P1, Wa+o_w[14], F(46), H0, NB, NF,NF,NF,NF);
  k_wgemm<0,5,256><<<gW, blk512, 0, stream>>>(H0, Wa+o_w[15], F(48), logits, P1, F(49),F(50), F(51),F(52));

  k_final<<<dim3(Bb), blk, 0, stream>>>(logits, valid, out);
  #undef F
}

// Round 10
// 1210.839 us; speedup vs baseline: 1.0873x; 1.0873x over previous
//
#include <hip/hip_runtime.h>
#include <hip/hip_bf16.h>

// ============================================================================
// TransformerChoiceNet forward. Round 24: correctness bisection — r9 kernel
// with k_attn reverted VERBATIM to the r8 256-thread version (passed r7+r8).
// wgemm family stays r6-core + multi-job wrappers (emb pair / QKV trios
// merged). If this passes, the 64-thr attention was the r9 breakage.
// B=128 S=512 D=64 H=256 NH=8 HD=32, M=B*S=65536.
// ============================================================================

#define Bb  128
#define Ss  512
#define Hh  256
#define NHh 8
#define Mm  (Bb*Ss)

typedef unsigned short bf16_t;
typedef __attribute__((ext_vector_type(8))) short short8;
typedef __attribute__((ext_vector_type(4))) float f32x4;

__device__ __forceinline__ float bf2f(bf16_t h){
  union { unsigned int u; float f; } v; v.u = ((unsigned int)h)<<16; return v.f;
}
__device__ __forceinline__ bf16_t f2bf(float f){
  union { float f; unsigned int u; } v; v.f = f;
  unsigned int r = (v.u + 0x7fffu + ((v.u>>16)&1u)) >> 16;   // RNE
  return (bf16_t)r;
}
__device__ __forceinline__ unsigned pk_bf16(float a, float b){  // packed RNE cvt
  union { __hip_bfloat162 h; unsigned u; } v;
  v.h = __float22bfloat162_rn(float2{a,b});
  return v.u;
}
__device__ __forceinline__ short8 ld_bf8(const bf16_t* p){   // 16B load
  union { uint4 u; short8 s; } v; v.u = *(const uint4*)p; return v.s;
}
__device__ __forceinline__ void gload16(const bf16_t* g, bf16_t* l){
  __builtin_amdgcn_global_load_lds(
      (const __attribute__((address_space(1))) void*)g,
      (__attribute__((address_space(3))) void*)l, 16, 0, 0);
}
__device__ __forceinline__ float exp2_hw(float x){           // native 2^x
  float r; asm("v_exp_f32 %0, %1" : "=v"(r) : "v"(x)); return r;
}
__device__ __forceinline__ float gelu_f(float x){
  // NewGELU; tanh via native exp + rcp: tanh(u) = 1 - 2/(e^{2u}+1)
  float u = 0.7978845608028654f*(x + 0.044715f*x*x*x);
  float e = __expf(2.0f*u);
  float th = 1.0f - 2.0f*__builtin_amdgcn_rcpf(e + 1.0f);
  return 0.5f*x*(1.0f + th);
}

// ---------------- weight prep: fp32 W[k][n] -> bf16 Wt[n][k] ------------------
struct PrepDesc { const float* s; unsigned off; int K; };
struct Prep18  { PrepDesc d[18]; };

__global__ __launch_bounds__(256) void k_prep(Prep18 p, bf16_t* __restrict__ arena)
{
  PrepDesc dd = p.d[blockIdx.y];
  int i = blockIdx.x*256 + threadIdx.x;
  if (i < dd.K*256){
    int k = i>>8, n = i&255;
    arena[dd.off + n*dd.K + k] = f2bf(dd.s[i]);
  }
}

// ---------------- LN0 (two gains) + valid mask; bf16 out ----------------------
__global__ __launch_bounds__(256) void k_ln0(const float* __restrict__ src,
    const float* __restrict__ gs, const float* __restrict__ bs,
    const float* __restrict__ gt, const float* __restrict__ bt,
    bf16_t* __restrict__ xs, bf16_t* __restrict__ xt, float* __restrict__ valid)
{
  int row  = blockIdx.x*4 + (threadIdx.x>>6);
  int lane = threadIdx.x & 63;
  float x = src[(size_t)row*64 + lane];
  float s = x;
  #pragma unroll
  for (int o=32;o>0;o>>=1) s += __shfl_xor(s,o);
  float mean = s*(1.0f/64.0f);
  float d = x - mean;
  float ss = d*d;
  #pragma unroll
  for (int o=32;o>0;o>>=1) ss += __shfl_xor(ss,o);
  float r = rsqrtf(ss*(1.0f/64.0f) + 1e-5f);
  float xn = d*r;
  xs[(size_t)row*64+lane] = f2bf(xn*gs[lane] + bs[lane]);
  xt[(size_t)row*64+lane] = f2bf(xn*gt[lane] + bt[lane]);
  if (lane==0) valid[row] = (s != 0.0f) ? 1.0f : 0.0f;
}

// ---------------- weight-resident GEMM core (r6 exact) ------------------------
// Block = 512 thr (8 waves), 256 rows/block, 32 rows/wave, full N=256.
// Ws frag layout: Ws[(kc*16+nt)*512 + lane*8]; stage 16B/lane, conflict-free.
template<int KK>
__device__ __forceinline__ void wgemm_core(const bf16_t* __restrict__ A,
    const bf16_t* __restrict__ Wt, bf16_t* Ws,
    int r0, int w, int lane, int l15, int quad,
    f32x4 (&acc0)[16], f32x4 (&acc1)[16])
{
  constexpr int NKC  = KK/32;
  constexpr int IDS  = 16*NKC;
  constexpr int PERW = IDS/8;

  #pragma unroll
  for (int j=0; j<PERW; j++){       // stage FULL W once
    int id = w*PERW + j; int kc = id>>4, nt = id&15;
    gload16(Wt + (size_t)(nt*16 + l15)*KK + kc*32 + quad*8, &Ws[id*512]);
  }
  // first A frags issued before the barrier (complete during W drain)
  short8 a0 = ld_bf8(A + (size_t)(r0      + l15)*KK + quad*8);
  short8 a1 = ld_bf8(A + (size_t)(r0 + 16 + l15)*KK + quad*8);
  __syncthreads();                  // ONLY barrier

  f32x4 z = {0.f,0.f,0.f,0.f};
  #pragma unroll
  for (int nt=0; nt<16; nt++){ acc0[nt] = z; acc1[nt] = z; }

  #pragma unroll
  for (int kc=0; kc<NKC; kc++){
    short8 a0n, a1n;
    if (kc+1 < NKC){                // 1-deep A prefetch (L2/L3-resident)
      a0n = ld_bf8(A + (size_t)(r0      + l15)*KK + (kc+1)*32 + quad*8);
      a1n = ld_bf8(A + (size_t)(r0 + 16 + l15)*KK + (kc+1)*32 + quad*8);
    }
    #pragma unroll
    for (int nt=0; nt<16; nt++){
      short8 b = ld_bf8(&Ws[(kc*16 + nt)*512 + lane*8]);
      acc0[nt] = __builtin_amdgcn_mfma_f32_16x16x32_bf16(a0, b, acc0[nt], 0,0,0);
      acc1[nt] = __builtin_amdgcn_mfma_f32_16x16x32_bf16(a1, b, acc1[nt], 0,0,0);
    }
    a0 = a0n; a1 = a1n;
  }
}

// ---------------- merged independent GEMMs (jobs via blockIdx.y) --------------
struct WJob  { const bf16_t* A; const bf16_t* Wt; const float* bias; bf16_t* C;
               int outm; float cs; };   // outm: 0 = C[M,256]*cs, 2 = VT pack
struct WJobs { WJob j[3]; };

template<int KK>
__global__ __launch_bounds__(512,2) void k_wqkv(WJobs jobs)
{
  constexpr int NKC = KK/32;
  __shared__ bf16_t Ws[16*NKC*512];
  WJob jb = jobs.j[blockIdx.y];
  int t = threadIdx.x, w = t>>6, lane = t&63, l15 = lane&15, quad = lane>>4;
  int r0 = blockIdx.x*256 + w*32;

  f32x4 acc0[16], acc1[16];
  wgemm_core<KK>(jb.A, jb.Wt, Ws, r0, w, lane, l15, quad, acc0, acc1);

  float bv[16];
  #pragma unroll
  for (int nt=0; nt<16; nt++) bv[nt] = jb.bias[nt*16 + l15];

  if (jb.outm == 0){
    float cs = jb.cs;
    auto epi = [&](f32x4 (&ac)[16], int tt){
      int rowb = r0 + tt*16 + quad*4;
      #pragma unroll
      for (int nt=0; nt<16; nt++)
        #pragma unroll
        for (int r=0; r<4; r++)
          jb.C[(size_t)(rowb + r)*256 + nt*16 + l15] = f2bf((ac[nt][r] + bv[nt])*cs);
    };
    epi(acc0, 0); epi(acc1, 1);
  } else {
    auto epi = [&](f32x4 (&ac)[16], int tt){
      int m = r0 + tt*16 + quad*4;
      #pragma unroll
      for (int nt=0; nt<16; nt++){
        int col = nt*16 + l15;
        uint2 pk = { pk_bf16(ac[nt][0]+bv[nt], ac[nt][1]+bv[nt]),
                     pk_bf16(ac[nt][2]+bv[nt], ac[nt][3]+bv[nt]) };
        *(uint2*)&jb.C[((size_t)((m>>9)*256 + col))*512 + (m&511)] = pk;
      }
    };
    epi(acc0, 0); epi(acc1, 1);
  }
}

// ---------------- single GEMMs with fused epilogues ---------------------------
// OUTM: 0 bf16 C (EPI 0=id / 1=gelu) | 3 LN(Pres+(acc+b)) -> bf16 |
//       5 LN -> dot outW -> fp32 logits.
template<int EPI, int OUTM, int KK>
__global__ __launch_bounds__(512,2) void k_wgemm(const bf16_t* __restrict__ A,
    const bf16_t* __restrict__ Wt, const float* __restrict__ bias,
    void* __restrict__ Cv, const bf16_t* __restrict__ Pres,
    const float* __restrict__ g, const float* __restrict__ bb,
    const float* __restrict__ oW, const float* __restrict__ obp)
{
  constexpr int NKC = KK/32;
  __shared__ bf16_t Ws[16*NKC*512];
  int t = threadIdx.x, w = t>>6, lane = t&63, l15 = lane&15, quad = lane>>4;
  int r0 = blockIdx.x*256 + w*32;

  f32x4 acc0[16], acc1[16];
  wgemm_core<KK>(A, Wt, Ws, r0, w, lane, l15, quad, acc0, acc1);

  float bv[16];
  #pragma unroll
  for (int nt=0; nt<16; nt++) bv[nt] = bias[nt*16 + l15];

  if (OUTM==0){
    auto epi = [&](f32x4 (&ac)[16], int tt){
      int rowb = r0 + tt*16 + quad*4;
      #pragma unroll
      for (int nt=0; nt<16; nt++)
        #pragma unroll
        for (int r=0; r<4; r++){
          float v = ac[nt][r] + bv[nt];
          if (EPI==1) v = gelu_f(v);
          ((bf16_t*)Cv)[(size_t)(rowb + r)*256 + nt*16 + l15] = f2bf(v);
        }
    };
    epi(acc0, 0); epi(acc1, 1);
  } else {
    float gv[16], bbv[16], wv[16];
    #pragma unroll
    for (int nt=0; nt<16; nt++){ gv[nt] = g[nt*16+l15]; bbv[nt] = bb[nt*16+l15]; }
    if (OUTM==5)
      #pragma unroll
      for (int nt=0; nt<16; nt++) wv[nt] = oW[nt*16+l15];
    float ob0 = (OUTM==5) ? obp[0] : 0.f;

    auto epi = [&](f32x4 (&ac)[16], int tt){
      #pragma unroll
      for (int r=0; r<4; r++){
        int row = r0 + tt*16 + quad*4 + r;
        const bf16_t* pr = Pres + (size_t)row*256;
        float v[16]; float s = 0.f, q = 0.f;
        #pragma unroll
        for (int nt=0; nt<16; nt++){
          v[nt] = ac[nt][r] + bv[nt] + bf2f(pr[nt*16 + l15]);
          s += v[nt]; q += v[nt]*v[nt];
        }
        s += __shfl_xor(s,1); s += __shfl_xor(s,2);
        s += __shfl_xor(s,4); s += __shfl_xor(s,8);
        q += __shfl_xor(q,1); q += __shfl_xor(q,2);
        q += __shfl_xor(q,4); q += __shfl_xor(q,8);
        float mean = s*(1.0f/256.0f);
        float var  = q*(1.0f/256.0f) - mean*mean;
        float rstd = rsqrtf(var + 1e-5f);
        if (OUTM==3){
          bf16_t* po = (bf16_t*)Cv + (size_t)row*256;
          #pragma unroll
          for (int nt=0; nt<16; nt++)
            po[nt*16 + l15] = f2bf((v[nt]-mean)*rstd*gv[nt] + bbv[nt]);
        } else {
          float s2 = 0.f;
          #pragma unroll
          for (int nt=0; nt<16; nt++)
            s2 += ((v[nt]-mean)*rstd*gv[nt] + bbv[nt]) * wv[nt];
          s2 += __shfl_xor(s2,1); s2 += __shfl_xor(s2,2);
          s2 += __shfl_xor(s2,4); s2 += __shfl_xor(s2,8);
          if (l15==0) ((float*)Cv)[row] = s2 + ob0;
        }
      }
    };
    epi(acc0, 0); epi(acc1, 1);
  }
}

// ---------------- MFMA attention (r8 verbatim: 256 thr, process-before-PV) ----
__global__ __launch_bounds__(256) void k_attn(const bf16_t* __restrict__ Qm,
    const bf16_t* __restrict__ Km, const bf16_t* __restrict__ VT,
    const float* __restrict__ valid, bf16_t* __restrict__ AO)
{
  __shared__ bf16_t Pbuf[4][2][2][16][40];   // [wave][qtile][slot][q][key] 20 KB
  __shared__ float  Smask[512];              // 0 or -1e10*log2e
  int t = threadIdx.x, wave = t>>6, lane = t&63, l15 = lane&15, quad = lane>>4;
  int lid = blockIdx.x + 8*blockIdx.y + 1024*blockIdx.z;    // dispatch order
  int hp = lid & 3, pb = (lid>>2)&1, g = (lid>>3)&7, bh = lid>>6;
  int h  = hp*2 + (g&1);          // head: pair hp, parity from g
  int qc = g>>1;
  int b  = bh*2 + pb;
  int q0 = qc*128;

  Smask[t]     = (valid[b*Ss + t      ] != 0.f) ? 0.f : -1.44269504e10f;
  Smask[t+256] = (valid[b*Ss + t + 256] != 0.f) ? 0.f : -1.44269504e10f;
  __syncthreads();

  short8 aQ0 = ld_bf8(Qm + (size_t)(b*Ss + q0 + (wave*2  )*16 + l15)*256 + h*32 + quad*8);
  short8 aQ1 = ld_bf8(Qm + (size_t)(b*Ss + q0 + (wave*2+1)*16 + l15)*256 + h*32 + quad*8);
  const bf16_t* Kb = Km + (size_t)(b*Ss)*256 + h*32;          // + key*256
  const bf16_t* Vb = VT + ((size_t)b*256 + h*32)*512;         // + d*512 + key

  f32x4 z = {0.f,0.f,0.f,0.f};
  f32x4 O0[2] = {z,z}, O1[2] = {z,z};
  float ls0 = 0.f, ls1 = 0.f;

  auto process = [&](int kt2n, short8 K0, short8 K1){
    int s = kt2n & 1;
    #pragma unroll
    for (int half=0; half<2; half++){
      short8 aK = half ? K1 : K0;
      int ktile = kt2n*2 + half;
      __builtin_amdgcn_s_setprio(1);
      f32x4 s0 = __builtin_amdgcn_mfma_f32_16x16x32_bf16(aK, aQ0, z, 0,0,0);
      f32x4 s1 = __builtin_amdgcn_mfma_f32_16x16x32_bf16(aK, aQ1, z, 0,0,0);
      __builtin_amdgcn_s_setprio(0);
      float4 mb = *(const float4*)&Smask[ktile*16 + quad*4];
      float p00 = exp2_hw(s0[0] + mb.x);    // Q pre-scaled by QS*log2e
      float p01 = exp2_hw(s0[1] + mb.y);
      float p02 = exp2_hw(s0[2] + mb.z);
      float p03 = exp2_hw(s0[3] + mb.w);
      float p10 = exp2_hw(s1[0] + mb.x);
      float p11 = exp2_hw(s1[1] + mb.y);
      float p12 = exp2_hw(s1[2] + mb.z);
      float p13 = exp2_hw(s1[3] + mb.w);
      ls0 += (p00+p01)+(p02+p03);
      ls1 += (p10+p11)+(p12+p13);
      uint2 w0 = { pk_bf16(p00,p01), pk_bf16(p02,p03) };
      uint2 w1 = { pk_bf16(p10,p11), pk_bf16(p12,p13) };
      *(uint2*)&Pbuf[wave][0][s][l15][half*16 + quad*4] = w0;
      *(uint2*)&Pbuf[wave][1][s][l15][half*16 + quad*4] = w1;
    }
  };
  auto loadK = [&](int n, short8& K0, short8& K1){
    K0 = ld_bf8(Kb + (size_t)((n*2  )*16 + l15)*256 + quad*8);
    K1 = ld_bf8(Kb + (size_t)((n*2+1)*16 + l15)*256 + quad*8);
  };
  auto loadV = [&](int n, short8& V0, short8& V1){
    V0 = ld_bf8(Vb + (size_t)(l15   )*512 + n*32 + quad*8);
    V1 = ld_bf8(Vb + (size_t)(16+l15)*512 + n*32 + quad*8);
  };

  short8 cK0, cK1, pK0, pK1, nK0, nK1, qK0, qK1;
  short8 cV0, cV1, mV0, mV1, nV0, nV1;
  loadK(0, cK0, cK1);
  loadK(1, pK0, pK1);
  loadK(2, nK0, nK1);
  loadV(0, cV0, cV1);
  loadV(1, mV0, mV1);
  process(0, cK0, cK1);            // writes slot 0

  #pragma unroll 2
  for (int kt2=0; kt2<16; kt2++){
    if (kt2+3 < 16) loadK(kt2+3, qK0, qK1);
    if (kt2+2 < 16) loadV(kt2+2, nV0, nV1);
    if (kt2+1 < 16) process(kt2+1, pK0, pK1);   // writes slot (kt2+1)&1
    int s = kt2 & 1;
    short8 aP0 = ld_bf8(&Pbuf[wave][0][s][l15][quad*8]);   // written 1 iter ago
    short8 aP1 = ld_bf8(&Pbuf[wave][1][s][l15][quad*8]);
    __builtin_amdgcn_s_setprio(1);
    O0[0] = __builtin_amdgcn_mfma_f32_16x16x32_bf16(aP0, cV0, O0[0], 0,0,0);
    O0[1] = __builtin_amdgcn_mfma_f32_16x16x32_bf16(aP0, cV1, O0[1], 0,0,0);
    O1[0] = __builtin_amdgcn_mfma_f32_16x16x32_bf16(aP1, cV0, O1[0], 0,0,0);
    O1[1] = __builtin_amdgcn_mfma_f32_16x16x32_bf16(aP1, cV1, O1[1], 0,0,0);
    __builtin_amdgcn_s_setprio(0);
    pK0 = nK0; pK1 = nK1; nK0 = qK0; nK1 = qK1;
    cV0 = mV0; cV1 = mV1; mV0 = nV0; mV1 = nV1;
  }

  ls0 += __shfl_xor(ls0,16); ls0 += __shfl_xor(ls0,32);
  ls1 += __shfl_xor(ls1,16); ls1 += __shfl_xor(ls1,32);
  float linv0 = (ls0 > 0.f) ? 1.0f/ls0 : 0.f;
  float linv1 = (ls1 > 0.f) ? 1.0f/ls1 : 0.f;
  float i0[4], i1[4];
  #pragma unroll
  for (int r=0; r<4; r++){
    i0[r] = __shfl(linv0, quad*4 + r);
    i1[r] = __shfl(linv1, quad*4 + r);
  }
  size_t r0 = (size_t)(b*Ss + q0 + (wave*2  )*16);
  size_t r1 = (size_t)(b*Ss + q0 + (wave*2+1)*16);
  #pragma unroll
  for (int nt=0; nt<2; nt++)
    #pragma unroll
    for (int r=0; r<4; r++){
      AO[(r0 + quad*4 + r)*256 + h*32 + nt*16 + l15] = f2bf(O0[nt][r]*i0[r]);
      AO[(r1 + quad*4 + r)*256 + h*32 + nt*16 + l15] = f2bf(O1[nt][r]*i1[r]);
    }
}

// ---------------- final: p = exp(logits)*valid, normalize per batch -----------
__global__ __launch_bounds__(256) void k_final(const float* __restrict__ L,
    const float* __restrict__ valid, float* __restrict__ out)
{
  __shared__ float wsum[4];
  int b = blockIdx.x, t = threadIdx.x;
  float e0 = __expf(L[b*Ss + t      ]) * valid[b*Ss + t      ];
  float e1 = __expf(L[b*Ss + 256 + t]) * valid[b*Ss + 256 + t];
  float s = e0 + e1;
  #pragma unroll
  for (int o=32;o>0;o>>=1) s += __shfl_xor(s,o);
  if ((t&63)==0) wsum[t>>6] = s;
  __syncthreads();
  float tot = wsum[0]+wsum[1]+wsum[2]+wsum[3];
  out[b*Ss + t      ] = e0/tot;
  out[b*Ss + 256 + t] = e1/tot;
}

// ============================================================================
extern "C" void kernel_launch(void* const* d_in, const int* in_sizes, int n_in,
                              void* d_out, int out_size, void* d_ws, size_t ws_size,
                              hipStream_t stream)
{
  #define F(i) ((const float*)d_in[(i)])
  bool sig = (in_sizes[33] == 256);   // signature order vs dict order
  const float* d_eqW  = F(sig?35:33); const float* d_eqb  = F(sig?36:34);
  const float* d_ekW  = F(sig?37:35); const float* d_ekb  = F(sig?38:36);
  const float* d_evW  = F(sig?39:37); const float* d_evb  = F(sig?40:38);
  const float* d_eoW  = F(sig?41:39); const float* d_eob  = F(sig?42:40);
  const float* d_ln1g = F(sig?33:41); const float* d_ln1b = F(sig?34:42);

  // ---- workspace (~163 MiB) ----
  char* w = (char*)d_ws;
  bf16_t* P0 = (bf16_t*)w; w += (size_t)Mm*Hh*2;   // 32 MiB residual (enc)
  bf16_t* P1 = (bf16_t*)w; w += (size_t)Mm*Hh*2;   // 32 MiB residual (dec)
  bf16_t* H0 = (bf16_t*)w; w += (size_t)Mm*Hh*2;   // 32 MiB Q / AO / gelu
  bf16_t* H1 = (bf16_t*)w;                          // 32 MiB K / xs alias
  bf16_t* xs = (bf16_t*)w; w += (size_t)Mm*Hh*2;
  bf16_t* H2 = (bf16_t*)w;                          // 32 MiB VT / xt alias
  bf16_t* xt = (bf16_t*)w; w += (size_t)Mm*Hh*2;
  bf16_t* Wa = (bf16_t*)w; w += (size_t)(2*16384 + 16*65536)*2;  // 2.1 MiB
  float*  valid  = (float*)w; w += (size_t)Mm*4;
  float*  logits = (float*)w; w += (size_t)Mm*4;
  float* out = (float*)d_out;

  unsigned o_sem = 0, o_tem = 16384;
  unsigned o_w[16]; for (int i=0;i<16;i++) o_w[i] = 32768 + i*65536u;
  Prep18 pp;
  const float* srcs[18] = { F(5), F(7), F(9), F(11), F(13), F(15), F(19), F(21),
                            F(25), F(27), F(29), F(31), d_eqW, d_ekW, d_evW, d_eoW,
                            F(45), F(47) };
  unsigned offs[18] = { o_sem, o_tem, o_w[0],o_w[1],o_w[2],o_w[3],o_w[4],o_w[5],
                        o_w[6],o_w[7],o_w[8],o_w[9],o_w[10],o_w[11],o_w[12],o_w[13],
                        o_w[14],o_w[15] };
  for (int i=0;i<18;i++){ pp.d[i].s = srcs[i]; pp.d[i].off = offs[i]; pp.d[i].K = (i<2)?64:256; }

  dim3 blk(256);
  dim3 blk512(512);
  dim3 gLN(Mm/4);
  dim3 gW(256);                     // 256 rows/block
  dim3 gA(NHh, Bb, 4);
  dim3 gP(256, 18);
  const float* NF = nullptr; const bf16_t* NB = nullptr;
  // 1/sqrt(32) * log2(e) folded into Q so attention uses native exp2
  const float QS = 0.17677669529663687f * 1.4426950408889634f;

  k_prep<<<gP, blk, 0, stream>>>(pp, Wa);
  k_ln0<<<gLN, blk, 0, stream>>>(F(0), F(1),F(2), F(3),F(4), xs, xt, valid);

  // emb pair merged (K=64)
  {
    WJobs js;
    js.j[0] = { xs, Wa+o_sem, F(6), P0, 0, 1.0f };
    js.j[1] = { xt, Wa+o_tem, F(8), P1, 0, 1.0f };
    js.j[2] = js.j[0];
    k_wqkv<64><<<dim3(256,2), blk512, 0, stream>>>(js);
  }

  // ---- encoder ----
  {
    WJobs js;
    js.j[0] = { P0, Wa+o_w[0], F(10), H0, 0, QS  };
    js.j[1] = { P0, Wa+o_w[1], F(12), H1, 0, 1.0f };
    js.j[2] = { P0, Wa+o_w[2], F(14), H2, 2, 1.0f };
    k_wqkv<256><<<dim3(256,3), blk512, 0, stream>>>(js);
  }
  k_attn<<<gA, blk, 0, stream>>>(H0, H1, H2, valid, H0);
  k_wgemm<0,3,256><<<gW, blk512, 0, stream>>>(H0, Wa+o_w[3], F(16), P0, P0, F(17),F(18), NF,NF);
  k_wgemm<1,0,256><<<gW, blk512, 0, stream>>>(P0, Wa+o_w[4], F(20), H0, NB, NF,NF,NF,NF);
  k_wgemm<0,3,256><<<gW, blk512, 0, stream>>>(H0, Wa+o_w[5], F(22), P0, P0, F(23),F(24), NF,NF);

  // ---- decoder self-attention ----
  {
    WJobs js;
    js.j[0] = { P1, Wa+o_w[6], F(26), H0, 0, QS  };
    js.j[1] = { P1, Wa+o_w[7], F(28), H1, 0, 1.0f };
    js.j[2] = { P1, Wa+o_w[8], F(30), H2, 2, 1.0f };
    k_wqkv<256><<<dim3(256,3), blk512, 0, stream>>>(js);
  }
  k_attn<<<gA, blk, 0, stream>>>(H0, H1, H2, valid, H0);
  k_wgemm<0,3,256><<<gW, blk512, 0, stream>>>(H0, Wa+o_w[9], F(32), P1, P1, d_ln1g,d_ln1b, NF,NF);

  // ---- decoder cross-attention: Q from P1, K/V from P0 ----
  {
    WJobs js;
    js.j[0] = { P1, Wa+o_w[10], d_eqb, H0, 0, QS  };
    js.j[1] = { P0, Wa+o_w[11], d_ekb, H1, 0, 1.0f };
    js.j[2] = { P0, Wa+o_w[12], d_evb, H2, 2, 1.0f };
    k_wqkv<256><<<dim3(256,3), blk512, 0, stream>>>(js);
  }
  k_attn<<<gA, blk, 0, stream>>>(H0, H1, H2, valid, H0);
  k_wgemm<0,3,256><<<gW, blk512, 0, stream>>>(H0, Wa+o_w[13], d_eob, P1, P1, F(43),F(44), NF,NF);

  // ---- decoder FFN + fused ln3 + logits ----
  k_wgemm<1,0,256><<<gW, blk512, 0, stream>>>(P1, Wa+o_w[14], F(46), H0, NB, NF,NF,NF,NF);
  k_wgemm<0,5,256><<<gW, blk512, 0, stream>>>(H0, Wa+o_w[15], F(48), logits, P1, F(49),F(50), F(51),F(52));

  k_final<<<dim3(Bb), blk, 0, stream>>>(logits, valid, out);
  #undef F
}

// Round 11
// 950.945 us; speedup vs baseline: 1.3845x; 1.2733x over previous
//
#include <hip/hip_runtime.h>
#include <hip/hip_bf16.h>

// ============================================================================
// TransformerChoiceNet forward. Round 25: consolidation. Exactly r6's wgemm
// family (separate template dispatches, full-N weight-resident, single-barrier
// core — 929.6us verified, absmax 3.05e-05) + r7's attention (process-before-
// PV, K 3-deep — 137.6us, passed twice). Multi-job merge wrappers REMOVED
// (r9 fail / r10 marginal-absmax + ~280us regression traced to them).
// B=128 S=512 D=64 H=256 NH=8 HD=32, M=B*S=65536.
// ============================================================================

#define Bb  128
#define Ss  512
#define Hh  256
#define NHh 8
#define Mm  (Bb*Ss)

typedef unsigned short bf16_t;
typedef __attribute__((ext_vector_type(8))) short short8;
typedef __attribute__((ext_vector_type(4))) float f32x4;

__device__ __forceinline__ float bf2f(bf16_t h){
  union { unsigned int u; float f; } v; v.u = ((unsigned int)h)<<16; return v.f;
}
__device__ __forceinline__ bf16_t f2bf(float f){
  union { float f; unsigned int u; } v; v.f = f;
  unsigned int r = (v.u + 0x7fffu + ((v.u>>16)&1u)) >> 16;   // RNE
  return (bf16_t)r;
}
__device__ __forceinline__ unsigned pk_bf16(float a, float b){  // packed RNE cvt
  union { __hip_bfloat162 h; unsigned u; } v;
  v.h = __float22bfloat162_rn(float2{a,b});
  return v.u;
}
__device__ __forceinline__ short8 ld_bf8(const bf16_t* p){   // 16B load
  union { uint4 u; short8 s; } v; v.u = *(const uint4*)p; return v.s;
}
__device__ __forceinline__ void gload16(const bf16_t* g, bf16_t* l){
  __builtin_amdgcn_global_load_lds(
      (const __attribute__((address_space(1))) void*)g,
      (__attribute__((address_space(3))) void*)l, 16, 0, 0);
}
__device__ __forceinline__ float exp2_hw(float x){           // native 2^x
  float r; asm("v_exp_f32 %0, %1" : "=v"(r) : "v"(x)); return r;
}
__device__ __forceinline__ float gelu_f(float x){
  // NewGELU; tanh via native exp + rcp: tanh(u) = 1 - 2/(e^{2u}+1)
  float u = 0.7978845608028654f*(x + 0.044715f*x*x*x);
  float e = __expf(2.0f*u);
  float th = 1.0f - 2.0f*__builtin_amdgcn_rcpf(e + 1.0f);
  return 0.5f*x*(1.0f + th);
}

// ---------------- weight prep: fp32 W[k][n] -> bf16 Wt[n][k] ------------------
struct PrepDesc { const float* s; unsigned off; int K; };
struct Prep18  { PrepDesc d[18]; };

__global__ __launch_bounds__(256) void k_prep(Prep18 p, bf16_t* __restrict__ arena)
{
  PrepDesc dd = p.d[blockIdx.y];
  int i = blockIdx.x*256 + threadIdx.x;
  if (i < dd.K*256){
    int k = i>>8, n = i&255;
    arena[dd.off + n*dd.K + k] = f2bf(dd.s[i]);
  }
}

// ---------------- LN0 (two gains) + valid mask; bf16 out ----------------------
__global__ __launch_bounds__(256) void k_ln0(const float* __restrict__ src,
    const float* __restrict__ gs, const float* __restrict__ bs,
    const float* __restrict__ gt, const float* __restrict__ bt,
    bf16_t* __restrict__ xs, bf16_t* __restrict__ xt, float* __restrict__ valid)
{
  int row  = blockIdx.x*4 + (threadIdx.x>>6);
  int lane = threadIdx.x & 63;
  float x = src[(size_t)row*64 + lane];
  float s = x;
  #pragma unroll
  for (int o=32;o>0;o>>=1) s += __shfl_xor(s,o);
  float mean = s*(1.0f/64.0f);
  float d = x - mean;
  float ss = d*d;
  #pragma unroll
  for (int o=32;o>0;o>>=1) ss += __shfl_xor(ss,o);
  float r = rsqrtf(ss*(1.0f/64.0f) + 1e-5f);
  float xn = d*r;
  xs[(size_t)row*64+lane] = f2bf(xn*gs[lane] + bs[lane]);
  xt[(size_t)row*64+lane] = f2bf(xn*gt[lane] + bt[lane]);
  if (lane==0) valid[row] = (s != 0.0f) ? 1.0f : 0.0f;
}

// ---------------- weight-resident GEMM, barrier-free main loop (r6 exact) -----
// Block = 512 thr (8 waves), grid = 256 blocks, 256 rows/block, 32 rows/wave.
// W fully LDS-resident, frag-blocked: Ws[(kc*16+nt)*512 + lane*8].
// OUTM: 0 bf16 C[M,256] (EPI 0=id(*cs) / 1=gelu) | 2 bf16 VT[b][n][s] |
//       3 LN(Pres+(acc+b)) -> bf16 | 5 LN -> dot outW -> fp32 logits.
template<int EPI, int OUTM, int KK>
__global__ __launch_bounds__(512,2) void k_wgemm(const bf16_t* __restrict__ A,
    const bf16_t* __restrict__ Wt, const float* __restrict__ bias,
    void* __restrict__ Cv, const bf16_t* __restrict__ Pres,
    const float* __restrict__ g, const float* __restrict__ bb,
    const float* __restrict__ oW, const float* __restrict__ obp, float cs)
{
  constexpr int NKC  = KK/32;       // 8 (K=256) or 2 (K=64)
  constexpr int IDS  = 16*NKC;      // frag blocks
  constexpr int PERW = IDS/8;
  __shared__ bf16_t Ws[IDS*512];    // 128 KB (K=256) / 32 KB (K=64)

  int t = threadIdx.x, w = t>>6, lane = t&63, l15 = lane&15, quad = lane>>4;
  int r0 = blockIdx.x*256 + w*32;

  #pragma unroll
  for (int j=0; j<PERW; j++){       // stage FULL W once, conflict-free layout
    int id = w*PERW + j; int kc = id>>4, nt = id&15;
    gload16(Wt + (size_t)(nt*16 + l15)*KK + kc*32 + quad*8, &Ws[id*512]);
  }
  // first A frags issued before the barrier (complete during W drain)
  short8 a0 = ld_bf8(A + (size_t)(r0      + l15)*KK + quad*8);
  short8 a1 = ld_bf8(A + (size_t)(r0 + 16 + l15)*KK + quad*8);
  __syncthreads();                  // ONLY barrier in the kernel

  f32x4 z = {0.f,0.f,0.f,0.f};
  f32x4 acc0[16], acc1[16];
  #pragma unroll
  for (int nt=0; nt<16; nt++){ acc0[nt] = z; acc1[nt] = z; }

  #pragma unroll
  for (int kc=0; kc<NKC; kc++){
    short8 a0n, a1n;
    if (kc+1 < NKC){                // prefetch next kc's A frags (L3-resident)
      a0n = ld_bf8(A + (size_t)(r0      + l15)*KK + (kc+1)*32 + quad*8);
      a1n = ld_bf8(A + (size_t)(r0 + 16 + l15)*KK + (kc+1)*32 + quad*8);
    }
    #pragma unroll
    for (int nt=0; nt<16; nt++){
      short8 b = ld_bf8(&Ws[(kc*16 + nt)*512 + lane*8]);
      acc0[nt] = __builtin_amdgcn_mfma_f32_16x16x32_bf16(a0, b, acc0[nt], 0,0,0);
      acc1[nt] = __builtin_amdgcn_mfma_f32_16x16x32_bf16(a1, b, acc1[nt], 0,0,0);
    }
    a0 = a0n; a1 = a1n;
  }

  float bv[16];
  #pragma unroll
  for (int nt=0; nt<16; nt++) bv[nt] = bias[nt*16 + l15];

  if (OUTM==0){
    auto epi = [&](f32x4 (&ac)[16], int tt){
      int rowb = r0 + tt*16 + quad*4;
      #pragma unroll
      for (int nt=0; nt<16; nt++)
        #pragma unroll
        for (int r=0; r<4; r++){
          float v = ac[nt][r] + bv[nt];
          v = (EPI==1) ? gelu_f(v) : v*cs;
          ((bf16_t*)Cv)[(size_t)(rowb + r)*256 + nt*16 + l15] = f2bf(v);
        }
    };
    epi(acc0, 0); epi(acc1, 1);
  } else if (OUTM==2){
    auto epi = [&](f32x4 (&ac)[16], int tt){
      int m = r0 + tt*16 + quad*4;
      #pragma unroll
      for (int nt=0; nt<16; nt++){
        int col = nt*16 + l15;
        uint2 pk = { pk_bf16(ac[nt][0]+bv[nt], ac[nt][1]+bv[nt]),
                     pk_bf16(ac[nt][2]+bv[nt], ac[nt][3]+bv[nt]) };
        *(uint2*)&((bf16_t*)Cv)[((size_t)((m>>9)*256 + col))*512 + (m&511)] = pk;
      }
    };
    epi(acc0, 0); epi(acc1, 1);
  } else {
    float gv[16], bbv[16], wv[16];
    #pragma unroll
    for (int nt=0; nt<16; nt++){ gv[nt] = g[nt*16+l15]; bbv[nt] = bb[nt*16+l15]; }
    if (OUTM==5)
      #pragma unroll
      for (int nt=0; nt<16; nt++) wv[nt] = oW[nt*16+l15];
    float ob0 = (OUTM==5) ? obp[0] : 0.f;

    auto epi = [&](f32x4 (&ac)[16], int tt){
      #pragma unroll
      for (int r=0; r<4; r++){
        int row = r0 + tt*16 + quad*4 + r;
        const bf16_t* pr = Pres + (size_t)row*256;
        float v[16]; float s = 0.f, q = 0.f;
        #pragma unroll
        for (int nt=0; nt<16; nt++){
          v[nt] = ac[nt][r] + bv[nt] + bf2f(pr[nt*16 + l15]);
          s += v[nt]; q += v[nt]*v[nt];
        }
        s += __shfl_xor(s,1); s += __shfl_xor(s,2);
        s += __shfl_xor(s,4); s += __shfl_xor(s,8);
        q += __shfl_xor(q,1); q += __shfl_xor(q,2);
        q += __shfl_xor(q,4); q += __shfl_xor(q,8);
        float mean = s*(1.0f/256.0f);
        float var  = q*(1.0f/256.0f) - mean*mean;
        float rstd = rsqrtf(var + 1e-5f);
        if (OUTM==3){
          bf16_t* po = (bf16_t*)Cv + (size_t)row*256;
          #pragma unroll
          for (int nt=0; nt<16; nt++)
            po[nt*16 + l15] = f2bf((v[nt]-mean)*rstd*gv[nt] + bbv[nt]);
        } else {
          float s2 = 0.f;
          #pragma unroll
          for (int nt=0; nt<16; nt++)
            s2 += ((v[nt]-mean)*rstd*gv[nt] + bbv[nt]) * wv[nt];
          s2 += __shfl_xor(s2,1); s2 += __shfl_xor(s2,2);
          s2 += __shfl_xor(s2,4); s2 += __shfl_xor(s2,8);
          if (l15==0) ((float*)Cv)[row] = s2 + ob0;
        }
      }
    };
    epi(acc0, 0); epi(acc1, 1);
  }
}

// ---------------- MFMA attention (r7: process-before-PV, K 3-deep) ------------
__global__ __launch_bounds__(256) void k_attn(const bf16_t* __restrict__ Qm,
    const bf16_t* __restrict__ Km, const bf16_t* __restrict__ VT,
    const float* __restrict__ valid, bf16_t* __restrict__ AO)
{
  __shared__ bf16_t Pbuf[4][2][2][16][40];   // [wave][qtile][slot][q][key] 20 KB
  __shared__ float  Smask[512];              // 0 or -1e10*log2e
  int t = threadIdx.x, wave = t>>6, lane = t&63, l15 = lane&15, quad = lane>>4;
  int lid = blockIdx.x + 8*blockIdx.y + 1024*blockIdx.z;    // dispatch order
  int hp = lid & 3, pb = (lid>>2)&1, g = (lid>>3)&7, bh = lid>>6;
  int h  = hp*2 + (g&1);          // head: pair hp, parity from g
  int qc = g>>1;
  int b  = bh*2 + pb;
  int q0 = qc*128;

  Smask[t]     = (valid[b*Ss + t      ] != 0.f) ? 0.f : -1.44269504e10f;
  Smask[t+256] = (valid[b*Ss + t + 256] != 0.f) ? 0.f : -1.44269504e10f;
  __syncthreads();

  short8 aQ0 = ld_bf8(Qm + (size_t)(b*Ss + q0 + (wave*2  )*16 + l15)*256 + h*32 + quad*8);
  short8 aQ1 = ld_bf8(Qm + (size_t)(b*Ss + q0 + (wave*2+1)*16 + l15)*256 + h*32 + quad*8);
  const bf16_t* Kb = Km + (size_t)(b*Ss)*256 + h*32;          // + key*256
  const bf16_t* Vb = VT + ((size_t)b*256 + h*32)*512;         // + d*512 + key

  f32x4 z = {0.f,0.f,0.f,0.f};
  f32x4 O0[2] = {z,z}, O1[2] = {z,z};
  float ls0 = 0.f, ls1 = 0.f;

  auto process = [&](int kt2n, short8 K0, short8 K1){
    int s = kt2n & 1;
    #pragma unroll
    for (int half=0; half<2; half++){
      short8 aK = half ? K1 : K0;
      int ktile = kt2n*2 + half;
      __builtin_amdgcn_s_setprio(1);
      f32x4 s0 = __builtin_amdgcn_mfma_f32_16x16x32_bf16(aK, aQ0, z, 0,0,0);
      f32x4 s1 = __builtin_amdgcn_mfma_f32_16x16x32_bf16(aK, aQ1, z, 0,0,0);
      __builtin_amdgcn_s_setprio(0);
      float4 mb = *(const float4*)&Smask[ktile*16 + quad*4];
      float p00 = exp2_hw(s0[0] + mb.x);    // Q pre-scaled by QS*log2e
      float p01 = exp2_hw(s0[1] + mb.y);
      float p02 = exp2_hw(s0[2] + mb.z);
      float p03 = exp2_hw(s0[3] + mb.w);
      float p10 = exp2_hw(s1[0] + mb.x);
      float p11 = exp2_hw(s1[1] + mb.y);
      float p12 = exp2_hw(s1[2] + mb.z);
      float p13 = exp2_hw(s1[3] + mb.w);
      ls0 += (p00+p01)+(p02+p03);
      ls1 += (p10+p11)+(p12+p13);
      uint2 w0 = { pk_bf16(p00,p01), pk_bf16(p02,p03) };
      uint2 w1 = { pk_bf16(p10,p11), pk_bf16(p12,p13) };
      *(uint2*)&Pbuf[wave][0][s][l15][half*16 + quad*4] = w0;
      *(uint2*)&Pbuf[wave][1][s][l15][half*16 + quad*4] = w1;
    }
  };
  auto loadK = [&](int n, short8& K0, short8& K1){
    K0 = ld_bf8(Kb + (size_t)((n*2  )*16 + l15)*256 + quad*8);
    K1 = ld_bf8(Kb + (size_t)((n*2+1)*16 + l15)*256 + quad*8);
  };
  auto loadV = [&](int n, short8& V0, short8& V1){
    V0 = ld_bf8(Vb + (size_t)(l15   )*512 + n*32 + quad*8);
    V1 = ld_bf8(Vb + (size_t)(16+l15)*512 + n*32 + quad*8);
  };

  short8 cK0, cK1, pK0, pK1, nK0, nK1, qK0, qK1;
  short8 cV0, cV1, mV0, mV1, nV0, nV1;
  loadK(0, cK0, cK1);
  loadK(1, pK0, pK1);
  loadK(2, nK0, nK1);
  loadV(0, cV0, cV1);
  loadV(1, mV0, mV1);
  process(0, cK0, cK1);            // writes slot 0

  #pragma unroll 2
  for (int kt2=0; kt2<16; kt2++){
    if (kt2+3 < 16) loadK(kt2+3, qK0, qK1);
    if (kt2+2 < 16) loadV(kt2+2, nV0, nV1);
    if (kt2+1 < 16) process(kt2+1, pK0, pK1);   // writes slot (kt2+1)&1
    int s = kt2 & 1;
    short8 aP0 = ld_bf8(&Pbuf[wave][0][s][l15][quad*8]);   // written 1 iter ago
    short8 aP1 = ld_bf8(&Pbuf[wave][1][s][l15][quad*8]);
    __builtin_amdgcn_s_setprio(1);
    O0[0] = __builtin_amdgcn_mfma_f32_16x16x32_bf16(aP0, cV0, O0[0], 0,0,0);
    O0[1] = __builtin_amdgcn_mfma_f32_16x16x32_bf16(aP0, cV1, O0[1], 0,0,0);
    O1[0] = __builtin_amdgcn_mfma_f32_16x16x32_bf16(aP1, cV0, O1[0], 0,0,0);
    O1[1] = __builtin_amdgcn_mfma_f32_16x16x32_bf16(aP1, cV1, O1[1], 0,0,0);
    __builtin_amdgcn_s_setprio(0);
    pK0 = nK0; pK1 = nK1; nK0 = qK0; nK1 = qK1;
    cV0 = mV0; cV1 = mV1; mV0 = nV0; mV1 = nV1;
  }

  ls0 += __shfl_xor(ls0,16); ls0 += __shfl_xor(ls0,32);
  ls1 += __shfl_xor(ls1,16); ls1 += __shfl_xor(ls1,32);
  float linv0 = (ls0 > 0.f) ? 1.0f/ls0 : 0.f;
  float linv1 = (ls1 > 0.f) ? 1.0f/ls1 : 0.f;
  float i0[4], i1[4];
  #pragma unroll
  for (int r=0; r<4; r++){
    i0[r] = __shfl(linv0, quad*4 + r);
    i1[r] = __shfl(linv1, quad*4 + r);
  }
  size_t r0 = (size_t)(b*Ss + q0 + (wave*2  )*16);
  size_t r1 = (size_t)(b*Ss + q0 + (wave*2+1)*16);
  #pragma unroll
  for (int nt=0; nt<2; nt++)
    #pragma unroll
    for (int r=0; r<4; r++){
      AO[(r0 + quad*4 + r)*256 + h*32 + nt*16 + l15] = f2bf(O0[nt][r]*i0[r]);
      AO[(r1 + quad*4 + r)*256 + h*32 + nt*16 + l15] = f2bf(O1[nt][r]*i1[r]);
    }
}

// ---------------- final: p = exp(logits)*valid, normalize per batch -----------
__global__ __launch_bounds__(256) void k_final(const float* __restrict__ L,
    const float* __restrict__ valid, float* __restrict__ out)
{
  __shared__ float wsum[4];
  int b = blockIdx.x, t = threadIdx.x;
  float e0 = __expf(L[b*Ss + t      ]) * valid[b*Ss + t      ];
  float e1 = __expf(L[b*Ss + 256 + t]) * valid[b*Ss + 256 + t];
  float s = e0 + e1;
  #pragma unroll
  for (int o=32;o>0;o>>=1) s += __shfl_xor(s,o);
  if ((t&63)==0) wsum[t>>6] = s;
  __syncthreads();
  float tot = wsum[0]+wsum[1]+wsum[2]+wsum[3];
  out[b*Ss + t      ] = e0/tot;
  out[b*Ss + 256 + t] = e1/tot;
}

// ============================================================================
extern "C" void kernel_launch(void* const* d_in, const int* in_sizes, int n_in,
                              void* d_out, int out_size, void* d_ws, size_t ws_size,
                              hipStream_t stream)
{
  #define F(i) ((const float*)d_in[(i)])
  bool sig = (in_sizes[33] == 256);   // signature order vs dict order
  const float* d_eqW  = F(sig?35:33); const float* d_eqb  = F(sig?36:34);
  const float* d_ekW  = F(sig?37:35); const float* d_ekb  = F(sig?38:36);
  const float* d_evW  = F(sig?39:37); const float* d_evb  = F(sig?40:38);
  const float* d_eoW  = F(sig?41:39); const float* d_eob  = F(sig?42:40);
  const float* d_ln1g = F(sig?33:41); const float* d_ln1b = F(sig?34:42);

  // ---- workspace (~163 MiB) ----
  char* w = (char*)d_ws;
  bf16_t* P0 = (bf16_t*)w; w += (size_t)Mm*Hh*2;   // 32 MiB residual (enc)
  bf16_t* P1 = (bf16_t*)w; w += (size_t)Mm*Hh*2;   // 32 MiB residual (dec)
  bf16_t* H0 = (bf16_t*)w; w += (size_t)Mm*Hh*2;   // 32 MiB Q / AO / gelu
  bf16_t* H1 = (bf16_t*)w;                          // 32 MiB K / xs alias
  bf16_t* xs = (bf16_t*)w; w += (size_t)Mm*Hh*2;
  bf16_t* H2 = (bf16_t*)w;                          // 32 MiB VT / xt alias
  bf16_t* xt = (bf16_t*)w; w += (size_t)Mm*Hh*2;
  bf16_t* Wa = (bf16_t*)w; w += (size_t)(2*16384 + 16*65536)*2;  // 2.1 MiB
  float*  valid  = (float*)w; w += (size_t)Mm*4;
  float*  logits = (float*)w; w += (size_t)Mm*4;
  float* out = (float*)d_out;

  unsigned o_sem = 0, o_tem = 16384;
  unsigned o_w[16]; for (int i=0;i<16;i++) o_w[i] = 32768 + i*65536u;
  Prep18 pp;
  const float* srcs[18] = { F(5), F(7), F(9), F(11), F(13), F(15), F(19), F(21),
                            F(25), F(27), F(29), F(31), d_eqW, d_ekW, d_evW, d_eoW,
                            F(45), F(47) };
  unsigned offs[18] = { o_sem, o_tem, o_w[0],o_w[1],o_w[2],o_w[3],o_w[4],o_w[5],
                        o_w[6],o_w[7],o_w[8],o_w[9],o_w[10],o_w[11],o_w[12],o_w[13],
                        o_w[14],o_w[15] };
  for (int i=0;i<18;i++){ pp.d[i].s = srcs[i]; pp.d[i].off = offs[i]; pp.d[i].K = (i<2)?64:256; }

  dim3 blk(256);
  dim3 blk512(512);
  dim3 gLN(Mm/4);
  dim3 gW(256);                     // 256 rows/block
  dim3 gA(NHh, Bb, 4);
  dim3 gP(256, 18);
  const float* NF = nullptr; const bf16_t* NB = nullptr;
  // 1/sqrt(32) * log2(e) folded into Q so attention uses native exp2
  const float QS = 0.17677669529663687f * 1.4426950408889634f;

  k_prep<<<gP, blk, 0, stream>>>(pp, Wa);
  k_ln0<<<gLN, blk, 0, stream>>>(F(0), F(1),F(2), F(3),F(4), xs, xt, valid);

  // emb pair (K=64)
  k_wgemm<0,0,64><<<gW, blk512, 0, stream>>>(xs, Wa+o_sem, F(6), P0, NB, NF,NF,NF,NF, 1.0f);
  k_wgemm<0,0,64><<<gW, blk512, 0, stream>>>(xt, Wa+o_tem, F(8), P1, NB, NF,NF,NF,NF, 1.0f);

  // ---- encoder ----
  k_wgemm<0,0,256><<<gW, blk512, 0, stream>>>(P0, Wa+o_w[0], F(10), H0, NB, NF,NF,NF,NF, QS);
  k_wgemm<0,0,256><<<gW, blk512, 0, stream>>>(P0, Wa+o_w[1], F(12), H1, NB, NF,NF,NF,NF, 1.0f);
  k_wgemm<0,2,256><<<gW, blk512, 0, stream>>>(P0, Wa+o_w[2], F(14), H2, NB, NF,NF,NF,NF, 1.0f);
  k_attn<<<gA, blk, 0, stream>>>(H0, H1, H2, valid, H0);
  k_wgemm<0,3,256><<<gW, blk512, 0, stream>>>(H0, Wa+o_w[3], F(16), P0, P0, F(17),F(18), NF,NF, 1.0f);
  k_wgemm<1,0,256><<<gW, blk512, 0, stream>>>(P0, Wa+o_w[4], F(20), H0, NB, NF,NF,NF,NF, 1.0f);
  k_wgemm<0,3,256><<<gW, blk512, 0, stream>>>(H0, Wa+o_w[5], F(22), P0, P0, F(23),F(24), NF,NF, 1.0f);

  // ---- decoder self-attention ----
  k_wgemm<0,0,256><<<gW, blk512, 0, stream>>>(P1, Wa+o_w[6], F(26), H0, NB, NF,NF,NF,NF, QS);
  k_wgemm<0,0,256><<<gW, blk512, 0, stream>>>(P1, Wa+o_w[7], F(28), H1, NB, NF,NF,NF,NF, 1.0f);
  k_wgemm<0,2,256><<<gW, blk512, 0, stream>>>(P1, Wa+o_w[8], F(30), H2, NB, NF,NF,NF,NF, 1.0f);
  k_attn<<<gA, blk, 0, stream>>>(H0, H1, H2, valid, H0);
  k_wgemm<0,3,256><<<gW, blk512, 0, stream>>>(H0, Wa+o_w[9], F(32), P1, P1, d_ln1g,d_ln1b, NF,NF, 1.0f);

  // ---- decoder cross-attention: Q from P1, K/V from P0 ----
  k_wgemm<0,0,256><<<gW, blk512, 0, stream>>>(P1, Wa+o_w[10], d_eqb, H0, NB, NF,NF,NF,NF, QS);
  k_wgemm<0,0,256><<<gW, blk512, 0, stream>>>(P0, Wa+o_w[11], d_ekb, H1, NB, NF,NF,NF,NF, 1.0f);
  k_wgemm<0,2,256><<<gW, blk512, 0, stream>>>(P0, Wa+o_w[12], d_evb, H2, NB, NF,NF,NF,NF, 1.0f);
  k_attn<<<gA, blk, 0, stream>>>(H0, H1, H2, valid, H0);
  k_wgemm<0,3,256><<<gW, blk512, 0, stream>>>(H0, Wa+o_w[13], d_eob, P1, P1, F(43),F(44), NF,NF, 1.0f);

  // ---- decoder FFN + fused ln3 + logits ----
  k_wgemm<1,0,256><<<gW, blk512, 0, stream>>>(P1, Wa+o_w[14], F(46), H0, NB, NF,NF,NF,NF, 1.0f);
  k_wgemm<0,5,256><<<gW, blk512, 0, stream>>>(H0, Wa+o_w[15], F(48), logits, P1, F(49),F(50), F(51),F(52), 1.0f);

  k_final<<<dim3(Bb), blk, 0, stream>>>(logits, valid, out);
  #undef F
}

// Round 13
// 946.415 us; speedup vs baseline: 1.3911x; 1.0048x over previous
//
#include <hip/hip_runtime.h>
#include <hip/hip_bf16.h>

// ============================================================================
// TransformerChoiceNet forward. Round 27 (= r26 resubmit after infra failure):
// r11 (clean consolidation) + ONE isolated k_attn change: aP fragments
// software-pipelined — reads for iter kt2+1 issued right after process(kt2+1)
// writes them, consumed next iter (~full-iter slack covers the ~120cy
// ds_read_b128 latency that previously sat exposed before the PV MFMAs).
// Everything else byte-identical to r11 (950.9us, absmax 3.05e-05).
// B=128 S=512 D=64 H=256 NH=8 HD=32, M=B*S=65536.
// ============================================================================

#define Bb  128
#define Ss  512
#define Hh  256
#define NHh 8
#define Mm  (Bb*Ss)

typedef unsigned short bf16_t;
typedef __attribute__((ext_vector_type(8))) short short8;
typedef __attribute__((ext_vector_type(4))) float f32x4;

__device__ __forceinline__ float bf2f(bf16_t h){
  union { unsigned int u; float f; } v; v.u = ((unsigned int)h)<<16; return v.f;
}
__device__ __forceinline__ bf16_t f2bf(float f){
  union { float f; unsigned int u; } v; v.f = f;
  unsigned int r = (v.u + 0x7fffu + ((v.u>>16)&1u)) >> 16;   // RNE
  return (bf16_t)r;
}
__device__ __forceinline__ unsigned pk_bf16(float a, float b){  // packed RNE cvt
  union { __hip_bfloat162 h; unsigned u; } v;
  v.h = __float22bfloat162_rn(float2{a,b});
  return v.u;
}
__device__ __forceinline__ short8 ld_bf8(const bf16_t* p){   // 16B load
  union { uint4 u; short8 s; } v; v.u = *(const uint4*)p; return v.s;
}
__device__ __forceinline__ void gload16(const bf16_t* g, bf16_t* l){
  __builtin_amdgcn_global_load_lds(
      (const __attribute__((address_space(1))) void*)g,
      (__attribute__((address_space(3))) void*)l, 16, 0, 0);
}
__device__ __forceinline__ float exp2_hw(float x){           // native 2^x
  float r; asm("v_exp_f32 %0, %1" : "=v"(r) : "v"(x)); return r;
}
__device__ __forceinline__ float gelu_f(float x){
  // NewGELU; tanh via native exp + rcp: tanh(u) = 1 - 2/(e^{2u}+1)
  float u = 0.7978845608028654f*(x + 0.044715f*x*x*x);
  float e = __expf(2.0f*u);
  float th = 1.0f - 2.0f*__builtin_amdgcn_rcpf(e + 1.0f);
  return 0.5f*x*(1.0f + th);
}

// ---------------- weight prep: fp32 W[k][n] -> bf16 Wt[n][k] ------------------
struct PrepDesc { const float* s; unsigned off; int K; };
struct Prep18  { PrepDesc d[18]; };

__global__ __launch_bounds__(256) void k_prep(Prep18 p, bf16_t* __restrict__ arena)
{
  PrepDesc dd = p.d[blockIdx.y];
  int i = blockIdx.x*256 + threadIdx.x;
  if (i < dd.K*256){
    int k = i>>8, n = i&255;
    arena[dd.off + n*dd.K + k] = f2bf(dd.s[i]);
  }
}

// ---------------- LN0 (two gains) + valid mask; bf16 out ----------------------
__global__ __launch_bounds__(256) void k_ln0(const float* __restrict__ src,
    const float* __restrict__ gs, const float* __restrict__ bs,
    const float* __restrict__ gt, const float* __restrict__ bt,
    bf16_t* __restrict__ xs, bf16_t* __restrict__ xt, float* __restrict__ valid)
{
  int row  = blockIdx.x*4 + (threadIdx.x>>6);
  int lane = threadIdx.x & 63;
  float x = src[(size_t)row*64 + lane];
  float s = x;
  #pragma unroll
  for (int o=32;o>0;o>>=1) s += __shfl_xor(s,o);
  float mean = s*(1.0f/64.0f);
  float d = x - mean;
  float ss = d*d;
  #pragma unroll
  for (int o=32;o>0;o>>=1) ss += __shfl_xor(ss,o);
  float r = rsqrtf(ss*(1.0f/64.0f) + 1e-5f);
  float xn = d*r;
  xs[(size_t)row*64+lane] = f2bf(xn*gs[lane] + bs[lane]);
  xt[(size_t)row*64+lane] = f2bf(xn*gt[lane] + bt[lane]);
  if (lane==0) valid[row] = (s != 0.0f) ? 1.0f : 0.0f;
}

// ---------------- weight-resident GEMM, barrier-free main loop (r6 exact) -----
// Block = 512 thr (8 waves), grid = 256 blocks, 256 rows/block, 32 rows/wave.
// W fully LDS-resident, frag-blocked: Ws[(kc*16+nt)*512 + lane*8].
// OUTM: 0 bf16 C[M,256] (EPI 0=id(*cs) / 1=gelu) | 2 bf16 VT[b][n][s] |
//       3 LN(Pres+(acc+b)) -> bf16 | 5 LN -> dot outW -> fp32 logits.
template<int EPI, int OUTM, int KK>
__global__ __launch_bounds__(512,2) void k_wgemm(const bf16_t* __restrict__ A,
    const bf16_t* __restrict__ Wt, const float* __restrict__ bias,
    void* __restrict__ Cv, const bf16_t* __restrict__ Pres,
    const float* __restrict__ g, const float* __restrict__ bb,
    const float* __restrict__ oW, const float* __restrict__ obp, float cs)
{
  constexpr int NKC  = KK/32;       // 8 (K=256) or 2 (K=64)
  constexpr int IDS  = 16*NKC;      // frag blocks
  constexpr int PERW = IDS/8;
  __shared__ bf16_t Ws[IDS*512];    // 128 KB (K=256) / 32 KB (K=64)

  int t = threadIdx.x, w = t>>6, lane = t&63, l15 = lane&15, quad = lane>>4;
  int r0 = blockIdx.x*256 + w*32;

  #pragma unroll
  for (int j=0; j<PERW; j++){       // stage FULL W once, conflict-free layout
    int id = w*PERW + j; int kc = id>>4, nt = id&15;
    gload16(Wt + (size_t)(nt*16 + l15)*KK + kc*32 + quad*8, &Ws[id*512]);
  }
  // first A frags issued before the barrier (complete during W drain)
  short8 a0 = ld_bf8(A + (size_t)(r0      + l15)*KK + quad*8);
  short8 a1 = ld_bf8(A + (size_t)(r0 + 16 + l15)*KK + quad*8);
  __syncthreads();                  // ONLY barrier in the kernel

  f32x4 z = {0.f,0.f,0.f,0.f};
  f32x4 acc0[16], acc1[16];
  #pragma unroll
  for (int nt=0; nt<16; nt++){ acc0[nt] = z; acc1[nt] = z; }

  #pragma unroll
  for (int kc=0; kc<NKC; kc++){
    short8 a0n, a1n;
    if (kc+1 < NKC){                // prefetch next kc's A frags (L3-resident)
      a0n = ld_bf8(A + (size_t)(r0      + l15)*KK + (kc+1)*32 + quad*8);
      a1n = ld_bf8(A + (size_t)(r0 + 16 + l15)*KK + (kc+1)*32 + quad*8);
    }
    #pragma unroll
    for (int nt=0; nt<16; nt++){
      short8 b = ld_bf8(&Ws[(kc*16 + nt)*512 + lane*8]);
      acc0[nt] = __builtin_amdgcn_mfma_f32_16x16x32_bf16(a0, b, acc0[nt], 0,0,0);
      acc1[nt] = __builtin_amdgcn_mfma_f32_16x16x32_bf16(a1, b, acc1[nt], 0,0,0);
    }
    a0 = a0n; a1 = a1n;
  }

  float bv[16];
  #pragma unroll
  for (int nt=0; nt<16; nt++) bv[nt] = bias[nt*16 + l15];

  if (OUTM==0){
    auto epi = [&](f32x4 (&ac)[16], int tt){
      int rowb = r0 + tt*16 + quad*4;
      #pragma unroll
      for (int nt=0; nt<16; nt++)
        #pragma unroll
        for (int r=0; r<4; r++){
          float v = ac[nt][r] + bv[nt];
          v = (EPI==1) ? gelu_f(v) : v*cs;
          ((bf16_t*)Cv)[(size_t)(rowb + r)*256 + nt*16 + l15] = f2bf(v);
        }
    };
    epi(acc0, 0); epi(acc1, 1);
  } else if (OUTM==2){
    auto epi = [&](f32x4 (&ac)[16], int tt){
      int m = r0 + tt*16 + quad*4;
      #pragma unroll
      for (int nt=0; nt<16; nt++){
        int col = nt*16 + l15;
        uint2 pk = { pk_bf16(ac[nt][0]+bv[nt], ac[nt][1]+bv[nt]),
                     pk_bf16(ac[nt][2]+bv[nt], ac[nt][3]+bv[nt]) };
        *(uint2*)&((bf16_t*)Cv)[((size_t)((m>>9)*256 + col))*512 + (m&511)] = pk;
      }
    };
    epi(acc0, 0); epi(acc1, 1);
  } else {
    float gv[16], bbv[16], wv[16];
    #pragma unroll
    for (int nt=0; nt<16; nt++){ gv[nt] = g[nt*16+l15]; bbv[nt] = bb[nt*16+l15]; }
    if (OUTM==5)
      #pragma unroll
      for (int nt=0; nt<16; nt++) wv[nt] = oW[nt*16+l15];
    float ob0 = (OUTM==5) ? obp[0] : 0.f;

    auto epi = [&](f32x4 (&ac)[16], int tt){
      #pragma unroll
      for (int r=0; r<4; r++){
        int row = r0 + tt*16 + quad*4 + r;
        const bf16_t* pr = Pres + (size_t)row*256;
        float v[16]; float s = 0.f, q = 0.f;
        #pragma unroll
        for (int nt=0; nt<16; nt++){
          v[nt] = ac[nt][r] + bv[nt] + bf2f(pr[nt*16 + l15]);
          s += v[nt]; q += v[nt]*v[nt];
        }
        s += __shfl_xor(s,1); s += __shfl_xor(s,2);
        s += __shfl_xor(s,4); s += __shfl_xor(s,8);
        q += __shfl_xor(q,1); q += __shfl_xor(q,2);
        q += __shfl_xor(q,4); q += __shfl_xor(q,8);
        float mean = s*(1.0f/256.0f);
        float var  = q*(1.0f/256.0f) - mean*mean;
        float rstd = rsqrtf(var + 1e-5f);
        if (OUTM==3){
          bf16_t* po = (bf16_t*)Cv + (size_t)row*256;
          #pragma unroll
          for (int nt=0; nt<16; nt++)
            po[nt*16 + l15] = f2bf((v[nt]-mean)*rstd*gv[nt] + bbv[nt]);
        } else {
          float s2 = 0.f;
          #pragma unroll
          for (int nt=0; nt<16; nt++)
            s2 += ((v[nt]-mean)*rstd*gv[nt] + bbv[nt]) * wv[nt];
          s2 += __shfl_xor(s2,1); s2 += __shfl_xor(s2,2);
          s2 += __shfl_xor(s2,4); s2 += __shfl_xor(s2,8);
          if (l15==0) ((float*)Cv)[row] = s2 + ob0;
        }
      }
    };
    epi(acc0, 0); epi(acc1, 1);
  }
}

// ---------------- MFMA attention (r7 + aP software pipeline) ------------------
__global__ __launch_bounds__(256) void k_attn(const bf16_t* __restrict__ Qm,
    const bf16_t* __restrict__ Km, const bf16_t* __restrict__ VT,
    const float* __restrict__ valid, bf16_t* __restrict__ AO)
{
  __shared__ bf16_t Pbuf[4][2][2][16][40];   // [wave][qtile][slot][q][key] 20 KB
  __shared__ float  Smask[512];              // 0 or -1e10*log2e
  int t = threadIdx.x, wave = t>>6, lane = t&63, l15 = lane&15, quad = lane>>4;
  int lid = blockIdx.x + 8*blockIdx.y + 1024*blockIdx.z;    // dispatch order
  int hp = lid & 3, pb = (lid>>2)&1, g = (lid>>3)&7, bh = lid>>6;
  int h  = hp*2 + (g&1);          // head: pair hp, parity from g
  int qc = g>>1;
  int b  = bh*2 + pb;
  int q0 = qc*128;

  Smask[t]     = (valid[b*Ss + t      ] != 0.f) ? 0.f : -1.44269504e10f;
  Smask[t+256] = (valid[b*Ss + t + 256] != 0.f) ? 0.f : -1.44269504e10f;
  __syncthreads();

  short8 aQ0 = ld_bf8(Qm + (size_t)(b*Ss + q0 + (wave*2  )*16 + l15)*256 + h*32 + quad*8);
  short8 aQ1 = ld_bf8(Qm + (size_t)(b*Ss + q0 + (wave*2+1)*16 + l15)*256 + h*32 + quad*8);
  const bf16_t* Kb = Km + (size_t)(b*Ss)*256 + h*32;          // + key*256
  const bf16_t* Vb = VT + ((size_t)b*256 + h*32)*512;         // + d*512 + key

  f32x4 z = {0.f,0.f,0.f,0.f};
  f32x4 O0[2] = {z,z}, O1[2] = {z,z};
  float ls0 = 0.f, ls1 = 0.f;

  auto process = [&](int kt2n, short8 K0, short8 K1){
    int s = kt2n & 1;
    #pragma unroll
    for (int half=0; half<2; half++){
      short8 aK = half ? K1 : K0;
      int ktile = kt2n*2 + half;
      __builtin_amdgcn_s_setprio(1);
      f32x4 s0 = __builtin_amdgcn_mfma_f32_16x16x32_bf16(aK, aQ0, z, 0,0,0);
      f32x4 s1 = __builtin_amdgcn_mfma_f32_16x16x32_bf16(aK, aQ1, z, 0,0,0);
      __builtin_amdgcn_s_setprio(0);
      float4 mb = *(const float4*)&Smask[ktile*16 + quad*4];
      float p00 = exp2_hw(s0[0] + mb.x);    // Q pre-scaled by QS*log2e
      float p01 = exp2_hw(s0[1] + mb.y);
      float p02 = exp2_hw(s0[2] + mb.z);
      float p03 = exp2_hw(s0[3] + mb.w);
      float p10 = exp2_hw(s1[0] + mb.x);
      float p11 = exp2_hw(s1[1] + mb.y);
      float p12 = exp2_hw(s1[2] + mb.z);
      float p13 = exp2_hw(s1[3] + mb.w);
      ls0 += (p00+p01)+(p02+p03);
      ls1 += (p10+p11)+(p12+p13);
      uint2 w0 = { pk_bf16(p00,p01), pk_bf16(p02,p03) };
      uint2 w1 = { pk_bf16(p10,p11), pk_bf16(p12,p13) };
      *(uint2*)&Pbuf[wave][0][s][l15][half*16 + quad*4] = w0;
      *(uint2*)&Pbuf[wave][1][s][l15][half*16 + quad*4] = w1;
    }
  };
  auto loadK = [&](int n, short8& K0, short8& K1){
    K0 = ld_bf8(Kb + (size_t)((n*2  )*16 + l15)*256 + quad*8);
    K1 = ld_bf8(Kb + (size_t)((n*2+1)*16 + l15)*256 + quad*8);
  };
  auto loadV = [&](int n, short8& V0, short8& V1){
    V0 = ld_bf8(Vb + (size_t)(l15   )*512 + n*32 + quad*8);
    V1 = ld_bf8(Vb + (size_t)(16+l15)*512 + n*32 + quad*8);
  };

  short8 cK0, cK1, pK0, pK1, nK0, nK1, qK0, qK1;
  short8 cV0, cV1, mV0, mV1, nV0, nV1;
  short8 aPc0, aPc1, aPn0, aPn1;
  loadK(0, cK0, cK1);
  loadK(1, pK0, pK1);
  loadK(2, nK0, nK1);
  loadV(0, cV0, cV1);
  loadV(1, mV0, mV1);
  process(0, cK0, cK1);            // writes slot 0
  aPc0 = ld_bf8(&Pbuf[wave][0][0][l15][quad*8]);   // prologue: read slot 0
  aPc1 = ld_bf8(&Pbuf[wave][1][0][l15][quad*8]);

  #pragma unroll 2
  for (int kt2=0; kt2<16; kt2++){
    if (kt2+3 < 16) loadK(kt2+3, qK0, qK1);
    if (kt2+2 < 16) loadV(kt2+2, nV0, nV1);
    if (kt2+1 < 16){
      process(kt2+1, pK0, pK1);    // writes slot (kt2+1)&1
      int sn = (kt2+1) & 1;        // prefetch NEXT iter's aP (full-iter slack)
      aPn0 = ld_bf8(&Pbuf[wave][0][sn][l15][quad*8]);
      aPn1 = ld_bf8(&Pbuf[wave][1][sn][l15][quad*8]);
    }
    __builtin_amdgcn_s_setprio(1);
    O0[0] = __builtin_amdgcn_mfma_f32_16x16x32_bf16(aPc0, cV0, O0[0], 0,0,0);
    O0[1] = __builtin_amdgcn_mfma_f32_16x16x32_bf16(aPc0, cV1, O0[1], 0,0,0);
    O1[0] = __builtin_amdgcn_mfma_f32_16x16x32_bf16(aPc1, cV0, O1[0], 0,0,0);
    O1[1] = __builtin_amdgcn_mfma_f32_16x16x32_bf16(aPc1, cV1, O1[1], 0,0,0);
    __builtin_amdgcn_s_setprio(0);
    aPc0 = aPn0; aPc1 = aPn1;
    pK0 = nK0; pK1 = nK1; nK0 = qK0; nK1 = qK1;
    cV0 = mV0; cV1 = mV1; mV0 = nV0; mV1 = nV1;
  }

  ls0 += __shfl_xor(ls0,16); ls0 += __shfl_xor(ls0,32);
  ls1 += __shfl_xor(ls1,16); ls1 += __shfl_xor(ls1,32);
  float linv0 = (ls0 > 0.f) ? 1.0f/ls0 : 0.f;
  float linv1 = (ls1 > 0.f) ? 1.0f/ls1 : 0.f;
  float i0[4], i1[4];
  #pragma unroll
  for (int r=0; r<4; r++){
    i0[r] = __shfl(linv0, quad*4 + r);
    i1[r] = __shfl(linv1, quad*4 + r);
  }
  size_t r0 = (size_t)(b*Ss + q0 + (wave*2  )*16);
  size_t r1 = (size_t)(b*Ss + q0 + (wave*2+1)*16);
  #pragma unroll
  for (int nt=0; nt<2; nt++)
    #pragma unroll
    for (int r=0; r<4; r++){
      AO[(r0 + quad*4 + r)*256 + h*32 + nt*16 + l15] = f2bf(O0[nt][r]*i0[r]);
      AO[(r1 + quad*4 + r)*256 + h*32 + nt*16 + l15] = f2bf(O1[nt][r]*i1[r]);
    }
}

// ---------------- final: p = exp(logits)*valid, normalize per batch -----------
__global__ __launch_bounds__(256) void k_final(const float* __restrict__ L,
    const float* __restrict__ valid, float* __restrict__ out)
{
  __shared__ float wsum[4];
  int b = blockIdx.x, t = threadIdx.x;
  float e0 = __expf(L[b*Ss + t      ]) * valid[b*Ss + t      ];
  float e1 = __expf(L[b*Ss + 256 + t]) * valid[b*Ss + 256 + t];
  float s = e0 + e1;
  #pragma unroll
  for (int o=32;o>0;o>>=1) s += __shfl_xor(s,o);
  if ((t&63)==0) wsum[t>>6] = s;
  __syncthreads();
  float tot = wsum[0]+wsum[1]+wsum[2]+wsum[3];
  out[b*Ss + t      ] = e0/tot;
  out[b*Ss + 256 + t] = e1/tot;
}

// ============================================================================
extern "C" void kernel_launch(void* const* d_in, const int* in_sizes, int n_in,
                              void* d_out, int out_size, void* d_ws, size_t ws_size,
                              hipStream_t stream)
{
  #define F(i) ((const float*)d_in[(i)])
  bool sig = (in_sizes[33] == 256);   // signature order vs dict order
  const float* d_eqW  = F(sig?35:33); const float* d_eqb  = F(sig?36:34);
  const float* d_ekW  = F(sig?37:35); const float* d_ekb  = F(sig?38:36);
  const float* d_evW  = F(sig?39:37); const float* d_evb  = F(sig?40:38);
  const float* d_eoW  = F(sig?41:39); const float* d_eob  = F(sig?42:40);
  const float* d_ln1g = F(sig?33:41); const float* d_ln1b = F(sig?34:42);

  // ---- workspace (~163 MiB) ----
  char* w = (char*)d_ws;
  bf16_t* P0 = (bf16_t*)w; w += (size_t)Mm*Hh*2;   // 32 MiB residual (enc)
  bf16_t* P1 = (bf16_t*)w; w += (size_t)Mm*Hh*2;   // 32 MiB residual (dec)
  bf16_t* H0 = (bf16_t*)w; w += (size_t)Mm*Hh*2;   // 32 MiB Q / AO / gelu
  bf16_t* H1 = (bf16_t*)w;                          // 32 MiB K / xs alias
  bf16_t* xs = (bf16_t*)w; w += (size_t)Mm*Hh*2;
  bf16_t* H2 = (bf16_t*)w;                          // 32 MiB VT / xt alias
  bf16_t* xt = (bf16_t*)w; w += (size_t)Mm*Hh*2;
  bf16_t* Wa = (bf16_t*)w; w += (size_t)(2*16384 + 16*65536)*2;  // 2.1 MiB
  float*  valid  = (float*)w; w += (size_t)Mm*4;
  float*  logits = (float*)w; w += (size_t)Mm*4;
  float* out = (float*)d_out;

  unsigned o_sem = 0, o_tem = 16384;
  unsigned o_w[16]; for (int i=0;i<16;i++) o_w[i] = 32768 + i*65536u;
  Prep18 pp;
  const float* srcs[18] = { F(5), F(7), F(9), F(11), F(13), F(15), F(19), F(21),
                            F(25), F(27), F(29), F(31), d_eqW, d_ekW, d_evW, d_eoW,
                            F(45), F(47) };
  unsigned offs[18] = { o_sem, o_tem, o_w[0],o_w[1],o_w[2],o_w[3],o_w[4],o_w[5],
                        o_w[6],o_w[7],o_w[8],o_w[9],o_w[10],o_w[11],o_w[12],o_w[13],
                        o_w[14],o_w[15] };
  for (int i=0;i<18;i++){ pp.d[i].s = srcs[i]; pp.d[i].off = offs[i]; pp.d[i].K = (i<2)?64:256; }

  dim3 blk(256);
  dim3 blk512(512);
  dim3 gLN(Mm/4);
  dim3 gW(256);                     // 256 rows/block
  dim3 gA(NHh, Bb, 4);
  dim3 gP(256, 18);
  const float* NF = nullptr; const bf16_t* NB = nullptr;
  // 1/sqrt(32) * log2(e) folded into Q so attention uses native exp2
  const float QS = 0.17677669529663687f * 1.4426950408889634f;

  k_prep<<<gP, blk, 0, stream>>>(pp, Wa);
  k_ln0<<<gLN, blk, 0, stream>>>(F(0), F(1),F(2), F(3),F(4), xs, xt, valid);

  // emb pair (K=64)
  k_wgemm<0,0,64><<<gW, blk512, 0, stream>>>(xs, Wa+o_sem, F(6), P0, NB, NF,NF,NF,NF, 1.0f);
  k_wgemm<0,0,64><<<gW, blk512, 0, stream>>>(xt, Wa+o_tem, F(8), P1, NB, NF,NF,NF,NF, 1.0f);

  // ---- encoder ----
  k_wgemm<0,0,256><<<gW, blk512, 0, stream>>>(P0, Wa+o_w[0], F(10), H0, NB, NF,NF,NF,NF, QS);
  k_wgemm<0,0,256><<<gW, blk512, 0, stream>>>(P0, Wa+o_w[1], F(12), H1, NB, NF,NF,NF,NF, 1.0f);
  k_wgemm<0,2,256><<<gW, blk512, 0, stream>>>(P0, Wa+o_w[2], F(14), H2, NB, NF,NF,NF,NF, 1.0f);
  k_attn<<<gA, blk, 0, stream>>>(H0, H1, H2, valid, H0);
  k_wgemm<0,3,256><<<gW, blk512, 0, stream>>>(H0, Wa+o_w[3], F(16), P0, P0, F(17),F(18), NF,NF, 1.0f);
  k_wgemm<1,0,256><<<gW, blk512, 0, stream>>>(P0, Wa+o_w[4], F(20), H0, NB, NF,NF,NF,NF, 1.0f);
  k_wgemm<0,3,256><<<gW, blk512, 0, stream>>>(H0, Wa+o_w[5], F(22), P0, P0, F(23),F(24), NF,NF, 1.0f);

  // ---- decoder self-attention ----
  k_wgemm<0,0,256><<<gW, blk512, 0, stream>>>(P1, Wa+o_w[6], F(26), H0, NB, NF,NF,NF,NF, QS);
  k_wgemm<0,0,256><<<gW, blk512, 0, stream>>>(P1, Wa+o_w[7], F(28), H1, NB, NF,NF,NF,NF, 1.0f);
  k_wgemm<0,2,256><<<gW, blk512, 0, stream>>>(P1, Wa+o_w[8], F(30), H2, NB, NF,NF,NF,NF, 1.0f);
  k_attn<<<gA, blk, 0, stream>>>(H0, H1, H2, valid, H0);
  k_wgemm<0,3,256><<<gW, blk512, 0, stream>>>(H0, Wa+o_w[9], F(32), P1, P1, d_ln1g,d_ln1b, NF,NF, 1.0f);

  // ---- decoder cross-attention: Q from P1, K/V from P0 ----
  k_wgemm<0,0,256><<<gW, blk512, 0, stream>>>(P1, Wa+o_w[10], d_eqb, H0, NB, NF,NF,NF,NF, QS);
  k_wgemm<0,0,256><<<gW, blk512, 0, stream>>>(P0, Wa+o_w[11], d_ekb, H1, NB, NF,NF,NF,NF, 1.0f);
  k_wgemm<0,2,256><<<gW, blk512, 0, stream>>>(P0, Wa+o_w[12], d_evb, H2, NB, NF,NF,NF,NF, 1.0f);
  k_attn<<<gA, blk, 0, stream>>>(H0, H1, H2, valid, H0);
  k_wgemm<0,3,256><<<gW, blk512, 0, stream>>>(H0, Wa+o_w[13], d_eob, P1, P1, F(43),F(44), NF,NF, 1.0f);

  // ---- decoder FFN + fused ln3 + logits ----
  k_wgemm<1,0,256><<<gW, blk512, 0, stream>>>(P1, Wa+o_w[14], F(46), H0, NB, NF,NF,NF,NF, 1.0f);
  k_wgemm<0,5,256><<<gW, blk512, 0, stream>>>(H0, Wa+o_w[15], F(48), logits, P1, F(49),F(50), F(51),F(52), 1.0f);

  k_final<<<dim3(Bb), blk, 0, stream>>>(logits, valid, out);
  #undef F
}

// Round 14
// 928.771 us; speedup vs baseline: 1.4175x; 1.0190x over previous
//
#include <hip/hip_runtime.h>
#include <hip/hip_bf16.h>

// ============================================================================
// TransformerChoiceNet forward. Round 28: FINAL consolidation — r6 verbatim,
// the session's best verified configuration (929.6us, absmax 3.05e-05).
// Weight-resident barrier-free GEMM (full W in LDS, single barrier, free-run
// MFMA loop) + XCD-remapped exp2/setprio attention. Later structural variants
// (N-split, split-stage, merges, 64-thr attn, aP pipeline) all regressed,
// broke, or were neutral; this is the measured floor of this structure family.
// B=128 S=512 D=64 H=256 NH=8 HD=32, M=B*S=65536.
// ============================================================================

#define Bb  128
#define Ss  512
#define Hh  256
#define NHh 8
#define Mm  (Bb*Ss)

typedef unsigned short bf16_t;
typedef __attribute__((ext_vector_type(8))) short short8;
typedef __attribute__((ext_vector_type(4))) float f32x4;

__device__ __forceinline__ float bf2f(bf16_t h){
  union { unsigned int u; float f; } v; v.u = ((unsigned int)h)<<16; return v.f;
}
__device__ __forceinline__ bf16_t f2bf(float f){
  union { float f; unsigned int u; } v; v.f = f;
  unsigned int r = (v.u + 0x7fffu + ((v.u>>16)&1u)) >> 16;   // RNE
  return (bf16_t)r;
}
__device__ __forceinline__ unsigned pk_bf16(float a, float b){  // packed RNE cvt
  union { __hip_bfloat162 h; unsigned u; } v;
  v.h = __float22bfloat162_rn(float2{a,b});
  return v.u;
}
__device__ __forceinline__ short8 ld_bf8(const bf16_t* p){   // 16B load
  union { uint4 u; short8 s; } v; v.u = *(const uint4*)p; return v.s;
}
__device__ __forceinline__ void gload16(const bf16_t* g, bf16_t* l){
  __builtin_amdgcn_global_load_lds(
      (const __attribute__((address_space(1))) void*)g,
      (__attribute__((address_space(3))) void*)l, 16, 0, 0);
}
__device__ __forceinline__ float exp2_hw(float x){           // native 2^x
  float r; asm("v_exp_f32 %0, %1" : "=v"(r) : "v"(x)); return r;
}
__device__ __forceinline__ float gelu_f(float x){
  // NewGELU; tanh via native exp + rcp: tanh(u) = 1 - 2/(e^{2u}+1)
  float u = 0.7978845608028654f*(x + 0.044715f*x*x*x);
  float e = __expf(2.0f*u);
  float th = 1.0f - 2.0f*__builtin_amdgcn_rcpf(e + 1.0f);
  return 0.5f*x*(1.0f + th);
}

// ---------------- weight prep: fp32 W[k][n] -> bf16 Wt[n][k] ------------------
struct PrepDesc { const float* s; unsigned off; int K; };
struct Prep18  { PrepDesc d[18]; };

__global__ __launch_bounds__(256) void k_prep(Prep18 p, bf16_t* __restrict__ arena)
{
  PrepDesc dd = p.d[blockIdx.y];
  int i = blockIdx.x*256 + threadIdx.x;
  if (i < dd.K*256){
    int k = i>>8, n = i&255;
    arena[dd.off + n*dd.K + k] = f2bf(dd.s[i]);
  }
}

// ---------------- LN0 (two gains) + valid mask; bf16 out ----------------------
__global__ __launch_bounds__(256) void k_ln0(const float* __restrict__ src,
    const float* __restrict__ gs, const float* __restrict__ bs,
    const float* __restrict__ gt, const float* __restrict__ bt,
    bf16_t* __restrict__ xs, bf16_t* __restrict__ xt, float* __restrict__ valid)
{
  int row  = blockIdx.x*4 + (threadIdx.x>>6);
  int lane = threadIdx.x & 63;
  float x = src[(size_t)row*64 + lane];
  float s = x;
  #pragma unroll
  for (int o=32;o>0;o>>=1) s += __shfl_xor(s,o);
  float mean = s*(1.0f/64.0f);
  float d = x - mean;
  float ss = d*d;
  #pragma unroll
  for (int o=32;o>0;o>>=1) ss += __shfl_xor(ss,o);
  float r = rsqrtf(ss*(1.0f/64.0f) + 1e-5f);
  float xn = d*r;
  xs[(size_t)row*64+lane] = f2bf(xn*gs[lane] + bs[lane]);
  xt[(size_t)row*64+lane] = f2bf(xn*gt[lane] + bt[lane]);
  if (lane==0) valid[row] = (s != 0.0f) ? 1.0f : 0.0f;
}

// ---------------- weight-resident GEMM, barrier-free main loop ----------------
// Block = 512 thr (8 waves), grid = 256 blocks, 256 rows/block, 32 rows/wave.
// W fully LDS-resident, frag-blocked: Ws[(kc*16+nt)*512 + lane*8].
// OUTM: 0 bf16 C[M,256] (EPI 0=id(*cs) / 1=gelu) | 2 bf16 VT[b][n][s] |
//       3 LN(Pres+(acc+b)) -> bf16 | 5 LN -> dot outW -> fp32 logits.
template<int EPI, int OUTM, int KK>
__global__ __launch_bounds__(512,2) void k_wgemm(const bf16_t* __restrict__ A,
    const bf16_t* __restrict__ Wt, const float* __restrict__ bias,
    void* __restrict__ Cv, const bf16_t* __restrict__ Pres,
    const float* __restrict__ g, const float* __restrict__ bb,
    const float* __restrict__ oW, const float* __restrict__ obp, float cs)
{
  constexpr int NKC  = KK/32;       // 8 (K=256) or 2 (K=64)
  constexpr int IDS  = 16*NKC;      // frag blocks
  constexpr int PERW = IDS/8;
  __shared__ bf16_t Ws[IDS*512];    // 128 KB (K=256) / 32 KB (K=64)

  int t = threadIdx.x, w = t>>6, lane = t&63, l15 = lane&15, quad = lane>>4;
  int r0 = blockIdx.x*256 + w*32;

  #pragma unroll
  for (int j=0; j<PERW; j++){       // stage FULL W once, conflict-free layout
    int id = w*PERW + j; int kc = id>>4, nt = id&15;
    gload16(Wt + (size_t)(nt*16 + l15)*KK + kc*32 + quad*8, &Ws[id*512]);
  }
  // first A frags issued before the barrier (complete during W drain)
  short8 a0 = ld_bf8(A + (size_t)(r0      + l15)*KK + quad*8);
  short8 a1 = ld_bf8(A + (size_t)(r0 + 16 + l15)*KK + quad*8);
  __syncthreads();                  // ONLY barrier in the kernel

  f32x4 z = {0.f,0.f,0.f,0.f};
  f32x4 acc0[16], acc1[16];
  #pragma unroll
  for (int nt=0; nt<16; nt++){ acc0[nt] = z; acc1[nt] = z; }

  #pragma unroll
  for (int kc=0; kc<NKC; kc++){
    short8 a0n, a1n;
    if (kc+1 < NKC){                // prefetch next kc's A frags (L3-resident)
      a0n = ld_bf8(A + (size_t)(r0      + l15)*KK + (kc+1)*32 + quad*8);
      a1n = ld_bf8(A + (size_t)(r0 + 16 + l15)*KK + (kc+1)*32 + quad*8);
    }
    #pragma unroll
    for (int nt=0; nt<16; nt++){
      short8 b = ld_bf8(&Ws[(kc*16 + nt)*512 + lane*8]);
      acc0[nt] = __builtin_amdgcn_mfma_f32_16x16x32_bf16(a0, b, acc0[nt], 0,0,0);
      acc1[nt] = __builtin_amdgcn_mfma_f32_16x16x32_bf16(a1, b, acc1[nt], 0,0,0);
    }
    a0 = a0n; a1 = a1n;
  }

  float bv[16];
  #pragma unroll
  for (int nt=0; nt<16; nt++) bv[nt] = bias[nt*16 + l15];

  if (OUTM==0){
    auto epi = [&](f32x4 (&ac)[16], int tt){
      int rowb = r0 + tt*16 + quad*4;
      #pragma unroll
      for (int nt=0; nt<16; nt++)
        #pragma unroll
        for (int r=0; r<4; r++){
          float v = ac[nt][r] + bv[nt];
          v = (EPI==1) ? gelu_f(v) : v*cs;
          ((bf16_t*)Cv)[(size_t)(rowb + r)*256 + nt*16 + l15] = f2bf(v);
        }
    };
    epi(acc0, 0); epi(acc1, 1);
  } else if (OUTM==2){
    auto epi = [&](f32x4 (&ac)[16], int tt){
      int m = r0 + tt*16 + quad*4;
      #pragma unroll
      for (int nt=0; nt<16; nt++){
        int col = nt*16 + l15;
        uint2 pk = { pk_bf16(ac[nt][0]+bv[nt], ac[nt][1]+bv[nt]),
                     pk_bf16(ac[nt][2]+bv[nt], ac[nt][3]+bv[nt]) };
        *(uint2*)&((bf16_t*)Cv)[((size_t)((m>>9)*256 + col))*512 + (m&511)] = pk;
      }
    };
    epi(acc0, 0); epi(acc1, 1);
  } else {
    float gv[16], bbv[16], wv[16];
    #pragma unroll
    for (int nt=0; nt<16; nt++){ gv[nt] = g[nt*16+l15]; bbv[nt] = bb[nt*16+l15]; }
    if (OUTM==5)
      #pragma unroll
      for (int nt=0; nt<16; nt++) wv[nt] = oW[nt*16+l15];
    float ob0 = (OUTM==5) ? obp[0] : 0.f;

    auto epi = [&](f32x4 (&ac)[16], int tt){
      #pragma unroll
      for (int r=0; r<4; r++){
        int row = r0 + tt*16 + quad*4 + r;
        const bf16_t* pr = Pres + (size_t)row*256;
        float v[16]; float s = 0.f, q = 0.f;
        #pragma unroll
        for (int nt=0; nt<16; nt++){
          v[nt] = ac[nt][r] + bv[nt] + bf2f(pr[nt*16 + l15]);
          s += v[nt]; q += v[nt]*v[nt];
        }
        s += __shfl_xor(s,1); s += __shfl_xor(s,2);
        s += __shfl_xor(s,4); s += __shfl_xor(s,8);
        q += __shfl_xor(q,1); q += __shfl_xor(q,2);
        q += __shfl_xor(q,4); q += __shfl_xor(q,8);
        float mean = s*(1.0f/256.0f);
        float var  = q*(1.0f/256.0f) - mean*mean;
        float rstd = rsqrtf(var + 1e-5f);
        if (OUTM==3){
          bf16_t* po = (bf16_t*)Cv + (size_t)row*256;
          #pragma unroll
          for (int nt=0; nt<16; nt++)
            po[nt*16 + l15] = f2bf((v[nt]-mean)*rstd*gv[nt] + bbv[nt]);
        } else {
          float s2 = 0.f;
          #pragma unroll
          for (int nt=0; nt<16; nt++)
            s2 += ((v[nt]-mean)*rstd*gv[nt] + bbv[nt]) * wv[nt];
          s2 += __shfl_xor(s2,1); s2 += __shfl_xor(s2,2);
          s2 += __shfl_xor(s2,4); s2 += __shfl_xor(s2,8);
          if (l15==0) ((float*)Cv)[row] = s2 + ob0;
        }
      }
    };
    epi(acc0, 0); epi(acc1, 1);
  }
}

// ---------------- MFMA attention (r16: remap + exp2 + setprio) ----------------
__global__ __launch_bounds__(256) void k_attn(const bf16_t* __restrict__ Qm,
    const bf16_t* __restrict__ Km, const bf16_t* __restrict__ VT,
    const float* __restrict__ valid, bf16_t* __restrict__ AO)
{
  __shared__ bf16_t Pbuf[4][2][2][16][40];   // [wave][qtile][slot][q][key] 20 KB
  __shared__ float  Smask[512];              // 0 or -1e10*log2e
  int t = threadIdx.x, wave = t>>6, lane = t&63, l15 = lane&15, quad = lane>>4;
  int lid = blockIdx.x + 8*blockIdx.y + 1024*blockIdx.z;    // dispatch order
  int hp = lid & 3, pb = (lid>>2)&1, g = (lid>>3)&7, bh = lid>>6;
  int h  = hp*2 + (g&1);          // head: pair hp, parity from g
  int qc = g>>1;
  int b  = bh*2 + pb;
  int q0 = qc*128;

  Smask[t]     = (valid[b*Ss + t      ] != 0.f) ? 0.f : -1.44269504e10f;
  Smask[t+256] = (valid[b*Ss + t + 256] != 0.f) ? 0.f : -1.44269504e10f;
  __syncthreads();

  short8 aQ0 = ld_bf8(Qm + (size_t)(b*Ss + q0 + (wave*2  )*16 + l15)*256 + h*32 + quad*8);
  short8 aQ1 = ld_bf8(Qm + (size_t)(b*Ss + q0 + (wave*2+1)*16 + l15)*256 + h*32 + quad*8);
  const bf16_t* Kb = Km + (size_t)(b*Ss)*256 + h*32;          // + key*256
  const bf16_t* Vb = VT + ((size_t)b*256 + h*32)*512;         // + d*512 + key

  f32x4 z = {0.f,0.f,0.f,0.f};
  f32x4 O0[2] = {z,z}, O1[2] = {z,z};
  float ls0 = 0.f, ls1 = 0.f;

  auto process = [&](int kt2n, short8 K0, short8 K1){
    int s = kt2n & 1;
    #pragma unroll
    for (int half=0; half<2; half++){
      short8 aK = half ? K1 : K0;
      int ktile = kt2n*2 + half;
      __builtin_amdgcn_s_setprio(1);
      f32x4 s0 = __builtin_amdgcn_mfma_f32_16x16x32_bf16(aK, aQ0, z, 0,0,0);
      f32x4 s1 = __builtin_amdgcn_mfma_f32_16x16x32_bf16(aK, aQ1, z, 0,0,0);
      __builtin_amdgcn_s_setprio(0);
      float4 mb = *(const float4*)&Smask[ktile*16 + quad*4];
      float p00 = exp2_hw(s0[0] + mb.x);    // Q pre-scaled by QS*log2e
      float p01 = exp2_hw(s0[1] + mb.y);
      float p02 = exp2_hw(s0[2] + mb.z);
      float p03 = exp2_hw(s0[3] + mb.w);
      float p10 = exp2_hw(s1[0] + mb.x);
      float p11 = exp2_hw(s1[1] + mb.y);
      float p12 = exp2_hw(s1[2] + mb.z);
      float p13 = exp2_hw(s1[3] + mb.w);
      ls0 += (p00+p01)+(p02+p03);
      ls1 += (p10+p11)+(p12+p13);
      uint2 w0 = { pk_bf16(p00,p01), pk_bf16(p02,p03) };
      uint2 w1 = { pk_bf16(p10,p11), pk_bf16(p12,p13) };
      *(uint2*)&Pbuf[wave][0][s][l15][half*16 + quad*4] = w0;
      *(uint2*)&Pbuf[wave][1][s][l15][half*16 + quad*4] = w1;
    }
  };
  auto loadK = [&](int n, short8& K0, short8& K1){
    K0 = ld_bf8(Kb + (size_t)((n*2  )*16 + l15)*256 + quad*8);
    K1 = ld_bf8(Kb + (size_t)((n*2+1)*16 + l15)*256 + quad*8);
  };
  auto loadV = [&](int n, short8& V0, short8& V1){
    V0 = ld_bf8(Vb + (size_t)(l15   )*512 + n*32 + quad*8);
    V1 = ld_bf8(Vb + (size_t)(16+l15)*512 + n*32 + quad*8);
  };

  short8 cK0, cK1, pK0, pK1, nK0, nK1;
  short8 cV0, cV1, mV0, mV1, nV0, nV1;
  loadK(0, cK0, cK1);
  process(0, cK0, cK1);
  loadK(1, pK0, pK1);
  loadV(0, cV0, cV1);
  loadV(1, mV0, mV1);

  #pragma unroll 2
  for (int kt2=0; kt2<16; kt2++){
    if (kt2+2 < 16){ loadK(kt2+2, nK0, nK1); loadV(kt2+2, nV0, nV1); }
    int s = kt2 & 1;
    short8 aP0 = ld_bf8(&Pbuf[wave][0][s][l15][quad*8]);
    short8 aP1 = ld_bf8(&Pbuf[wave][1][s][l15][quad*8]);
    __builtin_amdgcn_s_setprio(1);
    O0[0] = __builtin_amdgcn_mfma_f32_16x16x32_bf16(aP0, cV0, O0[0], 0,0,0);
    O0[1] = __builtin_amdgcn_mfma_f32_16x16x32_bf16(aP0, cV1, O0[1], 0,0,0);
    O1[0] = __builtin_amdgcn_mfma_f32_16x16x32_bf16(aP1, cV0, O1[0], 0,0,0);
    O1[1] = __builtin_amdgcn_mfma_f32_16x16x32_bf16(aP1, cV1, O1[1], 0,0,0);
    __builtin_amdgcn_s_setprio(0);
    if (kt2+1 < 16) process(kt2+1, pK0, pK1);
    pK0 = nK0; pK1 = nK1;
    cV0 = mV0; cV1 = mV1; mV0 = nV0; mV1 = nV1;
  }

  ls0 += __shfl_xor(ls0,16); ls0 += __shfl_xor(ls0,32);
  ls1 += __shfl_xor(ls1,16); ls1 += __shfl_xor(ls1,32);
  float linv0 = (ls0 > 0.f) ? 1.0f/ls0 : 0.f;
  float linv1 = (ls1 > 0.f) ? 1.0f/ls1 : 0.f;
  float i0[4], i1[4];
  #pragma unroll
  for (int r=0; r<4; r++){
    i0[r] = __shfl(linv0, quad*4 + r);
    i1[r] = __shfl(linv1, quad*4 + r);
  }
  size_t r0 = (size_t)(b*Ss + q0 + (wave*2  )*16);
  size_t r1 = (size_t)(b*Ss + q0 + (wave*2+1)*16);
  #pragma unroll
  for (int nt=0; nt<2; nt++)
    #pragma unroll
    for (int r=0; r<4; r++){
      AO[(r0 + quad*4 + r)*256 + h*32 + nt*16 + l15] = f2bf(O0[nt][r]*i0[r]);
      AO[(r1 + quad*4 + r)*256 + h*32 + nt*16 + l15] = f2bf(O1[nt][r]*i1[r]);
    }
}

// ---------------- final: p = exp(logits)*valid, normalize per batch -----------
__global__ __launch_bounds__(256) void k_final(const float* __restrict__ L,
    const float* __restrict__ valid, float* __restrict__ out)
{
  __shared__ float wsum[4];
  int b = blockIdx.x, t = threadIdx.x;
  float e0 = __expf(L[b*Ss + t      ]) * valid[b*Ss + t      ];
  float e1 = __expf(L[b*Ss + 256 + t]) * valid[b*Ss + 256 + t];
  float s = e0 + e1;
  #pragma unroll
  for (int o=32;o>0;o>>=1) s += __shfl_xor(s,o);
  if ((t&63)==0) wsum[t>>6] = s;
  __syncthreads();
  float tot = wsum[0]+wsum[1]+wsum[2]+wsum[3];
  out[b*Ss + t      ] = e0/tot;
  out[b*Ss + 256 + t] = e1/tot;
}

// ============================================================================
extern "C" void kernel_launch(void* const* d_in, const int* in_sizes, int n_in,
                              void* d_out, int out_size, void* d_ws, size_t ws_size,
                              hipStream_t stream)
{
  #define F(i) ((const float*)d_in[(i)])
  bool sig = (in_sizes[33] == 256);   // signature order vs dict order
  const float* d_eqW  = F(sig?35:33); const float* d_eqb  = F(sig?36:34);
  const float* d_ekW  = F(sig?37:35); const float* d_ekb  = F(sig?38:36);
  const float* d_evW  = F(sig?39:37); const float* d_evb  = F(sig?40:38);
  const float* d_eoW  = F(sig?41:39); const float* d_eob  = F(sig?42:40);
  const float* d_ln1g = F(sig?33:41); const float* d_ln1b = F(sig?34:42);

  // ---- workspace (~163 MiB) ----
  char* w = (char*)d_ws;
  bf16_t* P0 = (bf16_t*)w; w += (size_t)Mm*Hh*2;   // 32 MiB residual (enc)
  bf16_t* P1 = (bf16_t*)w; w += (size_t)Mm*Hh*2;   // 32 MiB residual (dec)
  bf16_t* H0 = (bf16_t*)w; w += (size_t)Mm*Hh*2;   // 32 MiB Q / AO / gelu
  bf16_t* H1 = (bf16_t*)w;                          // 32 MiB K / xs alias
  bf16_t* xs = (bf16_t*)w; w += (size_t)Mm*Hh*2;
  bf16_t* H2 = (bf16_t*)w;                          // 32 MiB VT / xt alias
  bf16_t* xt = (bf16_t*)w; w += (size_t)Mm*Hh*2;
  bf16_t* Wa = (bf16_t*)w; w += (size_t)(2*16384 + 16*65536)*2;  // 2.1 MiB
  float*  valid  = (float*)w; w += (size_t)Mm*4;
  float*  logits = (float*)w; w += (size_t)Mm*4;
  float* out = (float*)d_out;

  unsigned o_sem = 0, o_tem = 16384;
  unsigned o_w[16]; for (int i=0;i<16;i++) o_w[i] = 32768 + i*65536u;
  Prep18 pp;
  const float* srcs[18] = { F(5), F(7), F(9), F(11), F(13), F(15), F(19), F(21),
                            F(25), F(27), F(29), F(31), d_eqW, d_ekW, d_evW, d_eoW,
                            F(45), F(47) };
  unsigned offs[18] = { o_sem, o_tem, o_w[0],o_w[1],o_w[2],o_w[3],o_w[4],o_w[5],
                        o_w[6],o_w[7],o_w[8],o_w[9],o_w[10],o_w[11],o_w[12],o_w[13],
                        o_w[14],o_w[15] };
  for (int i=0;i<18;i++){ pp.d[i].s = srcs[i]; pp.d[i].off = offs[i]; pp.d[i].K = (i<2)?64:256; }

  dim3 blk(256);
  dim3 blk512(512);
  dim3 gLN(Mm/4);
  dim3 gW(256);                     // 256 rows/block
  dim3 gA(NHh, Bb, 4);
  dim3 gP(256, 18);
  const float* NF = nullptr; const bf16_t* NB = nullptr;
  // 1/sqrt(32) * log2(e) folded into Q so attention uses native exp2
  const float QS = 0.17677669529663687f * 1.4426950408889634f;

  k_prep<<<gP, blk, 0, stream>>>(pp, Wa);
  k_ln0<<<gLN, blk, 0, stream>>>(F(0), F(1),F(2), F(3),F(4), xs, xt, valid);

  // emb pair (K=64)
  k_wgemm<0,0,64><<<gW, blk512, 0, stream>>>(xs, Wa+o_sem, F(6), P0, NB, NF,NF,NF,NF, 1.0f);
  k_wgemm<0,0,64><<<gW, blk512, 0, stream>>>(xt, Wa+o_tem, F(8), P1, NB, NF,NF,NF,NF, 1.0f);

  // ---- encoder ----
  k_wgemm<0,0,256><<<gW, blk512, 0, stream>>>(P0, Wa+o_w[0], F(10), H0, NB, NF,NF,NF,NF, QS);
  k_wgemm<0,0,256><<<gW, blk512, 0, stream>>>(P0, Wa+o_w[1], F(12), H1, NB, NF,NF,NF,NF, 1.0f);
  k_wgemm<0,2,256><<<gW, blk512, 0, stream>>>(P0, Wa+o_w[2], F(14), H2, NB, NF,NF,NF,NF, 1.0f);
  k_attn<<<gA, blk, 0, stream>>>(H0, H1, H2, valid, H0);
  k_wgemm<0,3,256><<<gW, blk512, 0, stream>>>(H0, Wa+o_w[3], F(16), P0, P0, F(17),F(18), NF,NF, 1.0f);
  k_wgemm<1,0,256><<<gW, blk512, 0, stream>>>(P0, Wa+o_w[4], F(20), H0, NB, NF,NF,NF,NF, 1.0f);
  k_wgemm<0,3,256><<<gW, blk512, 0, stream>>>(H0, Wa+o_w[5], F(22), P0, P0, F(23),F(24), NF,NF, 1.0f);

  // ---- decoder self-attention ----
  k_wgemm<0,0,256><<<gW, blk512, 0, stream>>>(P1, Wa+o_w[6], F(26), H0, NB, NF,NF,NF,NF, QS);
  k_wgemm<0,0,256><<<gW, blk512, 0, stream>>>(P1, Wa+o_w[7], F(28), H1, NB, NF,NF,NF,NF, 1.0f);
  k_wgemm<0,2,256><<<gW, blk512, 0, stream>>>(P1, Wa+o_w[8], F(30), H2, NB, NF,NF,NF,NF, 1.0f);
  k_attn<<<gA, blk, 0, stream>>>(H0, H1, H2, valid, H0);
  k_wgemm<0,3,256><<<gW, blk512, 0, stream>>>(H0, Wa+o_w[9], F(32), P1, P1, d_ln1g,d_ln1b, NF,NF, 1.0f);

  // ---- decoder cross-attention: Q from P1, K/V from P0 ----
  k_wgemm<0,0,256><<<gW, blk512, 0, stream>>>(P1, Wa+o_w[10], d_eqb, H0, NB, NF,NF,NF,NF, QS);
  k_wgemm<0,0,256><<<gW, blk512, 0, stream>>>(P0, Wa+o_w[11], d_ekb, H1, NB, NF,NF,NF,NF, 1.0f);
  k_wgemm<0,2,256><<<gW, blk512, 0, stream>>>(P0, Wa+o_w[12], d_evb, H2, NB, NF,NF,NF,NF, 1.0f);
  k_attn<<<gA, blk, 0, stream>>>(H0, H1, H2, valid, H0);
  k_wgemm<0,3,256><<<gW, blk512, 0, stream>>>(H0, Wa+o_w[13], d_eob, P1, P1, F(43),F(44), NF,NF, 1.0f);

  // ---- decoder FFN + fused ln3 + logits ----
  k_wgemm<1,0,256><<<gW, blk512, 0, stream>>>(P1, Wa+o_w[14], F(46), H0, NB, NF,NF,NF,NF, 1.0f);
  k_wgemm<0,5,256><<<gW, blk512, 0, stream>>>(H0, Wa+o_w[15], F(48), logits, P1, F(49),F(50), F(51),F(52), 1.0f);

  k_final<<<dim3(Bb), blk, 0, stream>>>(logits, valid, out);
  #undef F
}

// Round 15
// 926.628 us; speedup vs baseline: 1.4208x; 1.0023x over previous
//
#include <hip/hip_runtime.h>
#include <hip/hip_bf16.h>

// ============================================================================
// TransformerChoiceNet forward. Round 29: r14 anchor + ONE isolated k_attn
// change: 4 q-tiles per wave (64 q rows), grid z 4->2 (2048 blocks). Doubles
// per-wave ILP at every chain stage (4 indep QK chains, 8 PV MFMA per V load)
// and halves K/V load issue per unit work. Pbuf stays 20KB via single slot
// (PV reads issued before process overwrites; same-wave DS ordering).
// XCD residue (hp + 4*pb) unchanged. All other kernels byte-identical to r14
// (928.8us, absmax 3.05e-05).
// B=128 S=512 D=64 H=256 NH=8 HD=32, M=B*S=65536.
// ============================================================================

#define Bb  128
#define Ss  512
#define Hh  256
#define NHh 8
#define Mm  (Bb*Ss)

typedef unsigned short bf16_t;
typedef __attribute__((ext_vector_type(8))) short short8;
typedef __attribute__((ext_vector_type(4))) float f32x4;

__device__ __forceinline__ float bf2f(bf16_t h){
  union { unsigned int u; float f; } v; v.u = ((unsigned int)h)<<16; return v.f;
}
__device__ __forceinline__ bf16_t f2bf(float f){
  union { float f; unsigned int u; } v; v.f = f;
  unsigned int r = (v.u + 0x7fffu + ((v.u>>16)&1u)) >> 16;   // RNE
  return (bf16_t)r;
}
__device__ __forceinline__ unsigned pk_bf16(float a, float b){  // packed RNE cvt
  union { __hip_bfloat162 h; unsigned u; } v;
  v.h = __float22bfloat162_rn(float2{a,b});
  return v.u;
}
__device__ __forceinline__ short8 ld_bf8(const bf16_t* p){   // 16B load
  union { uint4 u; short8 s; } v; v.u = *(const uint4*)p; return v.s;
}
__device__ __forceinline__ void gload16(const bf16_t* g, bf16_t* l){
  __builtin_amdgcn_global_load_lds(
      (const __attribute__((address_space(1))) void*)g,
      (__attribute__((address_space(3))) void*)l, 16, 0, 0);
}
__device__ __forceinline__ float exp2_hw(float x){           // native 2^x
  float r; asm("v_exp_f32 %0, %1" : "=v"(r) : "v"(x)); return r;
}
__device__ __forceinline__ float gelu_f(float x){
  // NewGELU; tanh via native exp + rcp: tanh(u) = 1 - 2/(e^{2u}+1)
  float u = 0.7978845608028654f*(x + 0.044715f*x*x*x);
  float e = __expf(2.0f*u);
  float th = 1.0f - 2.0f*__builtin_amdgcn_rcpf(e + 1.0f);
  return 0.5f*x*(1.0f + th);
}

// ---------------- weight prep: fp32 W[k][n] -> bf16 Wt[n][k] ------------------
struct PrepDesc { const float* s; unsigned off; int K; };
struct Prep18  { PrepDesc d[18]; };

__global__ __launch_bounds__(256) void k_prep(Prep18 p, bf16_t* __restrict__ arena)
{
  PrepDesc dd = p.d[blockIdx.y];
  int i = blockIdx.x*256 + threadIdx.x;
  if (i < dd.K*256){
    int k = i>>8, n = i&255;
    arena[dd.off + n*dd.K + k] = f2bf(dd.s[i]);
  }
}

// ---------------- LN0 (two gains) + valid mask; bf16 out ----------------------
__global__ __launch_bounds__(256) void k_ln0(const float* __restrict__ src,
    const float* __restrict__ gs, const float* __restrict__ bs,
    const float* __restrict__ gt, const float* __restrict__ bt,
    bf16_t* __restrict__ xs, bf16_t* __restrict__ xt, float* __restrict__ valid)
{
  int row  = blockIdx.x*4 + (threadIdx.x>>6);
  int lane = threadIdx.x & 63;
  float x = src[(size_t)row*64 + lane];
  float s = x;
  #pragma unroll
  for (int o=32;o>0;o>>=1) s += __shfl_xor(s,o);
  float mean = s*(1.0f/64.0f);
  float d = x - mean;
  float ss = d*d;
  #pragma unroll
  for (int o=32;o>0;o>>=1) ss += __shfl_xor(ss,o);
  float r = rsqrtf(ss*(1.0f/64.0f) + 1e-5f);
  float xn = d*r;
  xs[(size_t)row*64+lane] = f2bf(xn*gs[lane] + bs[lane]);
  xt[(size_t)row*64+lane] = f2bf(xn*gt[lane] + bt[lane]);
  if (lane==0) valid[row] = (s != 0.0f) ? 1.0f : 0.0f;
}

// ---------------- weight-resident GEMM, barrier-free main loop (r6 exact) -----
template<int EPI, int OUTM, int KK>
__global__ __launch_bounds__(512,2) void k_wgemm(const bf16_t* __restrict__ A,
    const bf16_t* __restrict__ Wt, const float* __restrict__ bias,
    void* __restrict__ Cv, const bf16_t* __restrict__ Pres,
    const float* __restrict__ g, const float* __restrict__ bb,
    const float* __restrict__ oW, const float* __restrict__ obp, float cs)
{
  constexpr int NKC  = KK/32;       // 8 (K=256) or 2 (K=64)
  constexpr int IDS  = 16*NKC;      // frag blocks
  constexpr int PERW = IDS/8;
  __shared__ bf16_t Ws[IDS*512];    // 128 KB (K=256) / 32 KB (K=64)

  int t = threadIdx.x, w = t>>6, lane = t&63, l15 = lane&15, quad = lane>>4;
  int r0 = blockIdx.x*256 + w*32;

  #pragma unroll
  for (int j=0; j<PERW; j++){       // stage FULL W once, conflict-free layout
    int id = w*PERW + j; int kc = id>>4, nt = id&15;
    gload16(Wt + (size_t)(nt*16 + l15)*KK + kc*32 + quad*8, &Ws[id*512]);
  }
  // first A frags issued before the barrier (complete during W drain)
  short8 a0 = ld_bf8(A + (size_t)(r0      + l15)*KK + quad*8);
  short8 a1 = ld_bf8(A + (size_t)(r0 + 16 + l15)*KK + quad*8);
  __syncthreads();                  // ONLY barrier in the kernel

  f32x4 z = {0.f,0.f,0.f,0.f};
  f32x4 acc0[16], acc1[16];
  #pragma unroll
  for (int nt=0; nt<16; nt++){ acc0[nt] = z; acc1[nt] = z; }

  #pragma unroll
  for (int kc=0; kc<NKC; kc++){
    short8 a0n, a1n;
    if (kc+1 < NKC){                // prefetch next kc's A frags (L3-resident)
      a0n = ld_bf8(A + (size_t)(r0      + l15)*KK + (kc+1)*32 + quad*8);
      a1n = ld_bf8(A + (size_t)(r0 + 16 + l15)*KK + (kc+1)*32 + quad*8);
    }
    #pragma unroll
    for (int nt=0; nt<16; nt++){
      short8 b = ld_bf8(&Ws[(kc*16 + nt)*512 + lane*8]);
      acc0[nt] = __builtin_amdgcn_mfma_f32_16x16x32_bf16(a0, b, acc0[nt], 0,0,0);
      acc1[nt] = __builtin_amdgcn_mfma_f32_16x16x32_bf16(a1, b, acc1[nt], 0,0,0);
    }
    a0 = a0n; a1 = a1n;
  }

  float bv[16];
  #pragma unroll
  for (int nt=0; nt<16; nt++) bv[nt] = bias[nt*16 + l15];

  if (OUTM==0){
    auto epi = [&](f32x4 (&ac)[16], int tt){
      int rowb = r0 + tt*16 + quad*4;
      #pragma unroll
      for (int nt=0; nt<16; nt++)
        #pragma unroll
        for (int r=0; r<4; r++){
          float v = ac[nt][r] + bv[nt];
          v = (EPI==1) ? gelu_f(v) : v*cs;
          ((bf16_t*)Cv)[(size_t)(rowb + r)*256 + nt*16 + l15] = f2bf(v);
        }
    };
    epi(acc0, 0); epi(acc1, 1);
  } else if (OUTM==2){
    auto epi = [&](f32x4 (&ac)[16], int tt){
      int m = r0 + tt*16 + quad*4;
      #pragma unroll
      for (int nt=0; nt<16; nt++){
        int col = nt*16 + l15;
        uint2 pk = { pk_bf16(ac[nt][0]+bv[nt], ac[nt][1]+bv[nt]),
                     pk_bf16(ac[nt][2]+bv[nt], ac[nt][3]+bv[nt]) };
        *(uint2*)&((bf16_t*)Cv)[((size_t)((m>>9)*256 + col))*512 + (m&511)] = pk;
      }
    };
    epi(acc0, 0); epi(acc1, 1);
  } else {
    float gv[16], bbv[16], wv[16];
    #pragma unroll
    for (int nt=0; nt<16; nt++){ gv[nt] = g[nt*16+l15]; bbv[nt] = bb[nt*16+l15]; }
    if (OUTM==5)
      #pragma unroll
      for (int nt=0; nt<16; nt++) wv[nt] = oW[nt*16+l15];
    float ob0 = (OUTM==5) ? obp[0] : 0.f;

    auto epi = [&](f32x4 (&ac)[16], int tt){
      #pragma unroll
      for (int r=0; r<4; r++){
        int row = r0 + tt*16 + quad*4 + r;
        const bf16_t* pr = Pres + (size_t)row*256;
        float v[16]; float s = 0.f, q = 0.f;
        #pragma unroll
        for (int nt=0; nt<16; nt++){
          v[nt] = ac[nt][r] + bv[nt] + bf2f(pr[nt*16 + l15]);
          s += v[nt]; q += v[nt]*v[nt];
        }
        s += __shfl_xor(s,1); s += __shfl_xor(s,2);
        s += __shfl_xor(s,4); s += __shfl_xor(s,8);
        q += __shfl_xor(q,1); q += __shfl_xor(q,2);
        q += __shfl_xor(q,4); q += __shfl_xor(q,8);
        float mean = s*(1.0f/256.0f);
        float var  = q*(1.0f/256.0f) - mean*mean;
        float rstd = rsqrtf(var + 1e-5f);
        if (OUTM==3){
          bf16_t* po = (bf16_t*)Cv + (size_t)row*256;
          #pragma unroll
          for (int nt=0; nt<16; nt++)
            po[nt*16 + l15] = f2bf((v[nt]-mean)*rstd*gv[nt] + bbv[nt]);
        } else {
          float s2 = 0.f;
          #pragma unroll
          for (int nt=0; nt<16; nt++)
            s2 += ((v[nt]-mean)*rstd*gv[nt] + bbv[nt]) * wv[nt];
          s2 += __shfl_xor(s2,1); s2 += __shfl_xor(s2,2);
          s2 += __shfl_xor(s2,4); s2 += __shfl_xor(s2,8);
          if (l15==0) ((float*)Cv)[row] = s2 + ob0;
        }
      }
    };
    epi(acc0, 0); epi(acc1, 1);
  }
}

// ---------------- MFMA attention: 4 q-tiles/wave, single P slot ---------------
// Grid (8,128,2): lid = bx + 8by + 1024bz (0..2047, bijective).
// hp=lid&3, pb=bit2 (XCD residue hp+4pb unchanged), g=(lid>>3)&3:
// bit0 = head parity, bit1 = qc (256-row half); bh=lid>>5. Wave covers
// q0 = qc*256 + wave*64 .. +63 (4 q-tiles of 16). Single Pbuf slot: PV reads
// are issued before process(kt2+1) overwrites (same-wave DS ordering).
__global__ __launch_bounds__(256) void k_attn(const bf16_t* __restrict__ Qm,
    const bf16_t* __restrict__ Km, const bf16_t* __restrict__ VT,
    const float* __restrict__ valid, bf16_t* __restrict__ AO)
{
  __shared__ bf16_t Pbuf[4][4][16][40];      // [wave][qt][q][key] 20 KB
  __shared__ float  Smask[512];              // 0 or -1e10*log2e
  int t = threadIdx.x, wave = t>>6, lane = t&63, l15 = lane&15, quad = lane>>4;
  int lid = blockIdx.x + 8*blockIdx.y + 1024*blockIdx.z;
  int hp = lid & 3, pb = (lid>>2)&1, g = (lid>>3)&3, bh = lid>>5;
  int h  = hp*2 + (g&1);
  int qc = g>>1;
  int b  = bh*2 + pb;
  int q0 = qc*256 + wave*64;

  Smask[t]     = (valid[b*Ss + t      ] != 0.f) ? 0.f : -1.44269504e10f;
  Smask[t+256] = (valid[b*Ss + t + 256] != 0.f) ? 0.f : -1.44269504e10f;
  __syncthreads();

  short8 aQ[4];
  #pragma unroll
  for (int qt=0; qt<4; qt++)
    aQ[qt] = ld_bf8(Qm + (size_t)(b*Ss + q0 + qt*16 + l15)*256 + h*32 + quad*8);
  const bf16_t* Kb = Km + (size_t)(b*Ss)*256 + h*32;          // + key*256
  const bf16_t* Vb = VT + ((size_t)b*256 + h*32)*512;         // + d*512 + key

  f32x4 z = {0.f,0.f,0.f,0.f};
  f32x4 O[4][2];
  #pragma unroll
  for (int qt=0; qt<4; qt++){ O[qt][0] = z; O[qt][1] = z; }
  float ls[4] = {0.f,0.f,0.f,0.f};

  auto process = [&](int kt2n, short8 K0, short8 K1){
    #pragma unroll
    for (int half=0; half<2; half++){
      short8 aK = half ? K1 : K0;
      int ktile = kt2n*2 + half;
      float4 mb = *(const float4*)&Smask[ktile*16 + quad*4];
      #pragma unroll
      for (int qt=0; qt<4; qt++){
        __builtin_amdgcn_s_setprio(1);
        f32x4 sq = __builtin_amdgcn_mfma_f32_16x16x32_bf16(aK, aQ[qt], z, 0,0,0);
        __builtin_amdgcn_s_setprio(0);
        float p0 = exp2_hw(sq[0] + mb.x);    // Q pre-scaled by QS*log2e
        float p1 = exp2_hw(sq[1] + mb.y);
        float p2 = exp2_hw(sq[2] + mb.z);
        float p3 = exp2_hw(sq[3] + mb.w);
        ls[qt] += (p0+p1)+(p2+p3);
        uint2 wq = { pk_bf16(p0,p1), pk_bf16(p2,p3) };
        *(uint2*)&Pbuf[wave][qt][l15][half*16 + quad*4] = wq;
      }
    }
  };
  auto loadK = [&](int n, short8& K0, short8& K1){
    K0 = ld_bf8(Kb + (size_t)((n*2  )*16 + l15)*256 + quad*8);
    K1 = ld_bf8(Kb + (size_t)((n*2+1)*16 + l15)*256 + quad*8);
  };
  auto loadV = [&](int n, short8& V0, short8& V1){
    V0 = ld_bf8(Vb + (size_t)(l15   )*512 + n*32 + quad*8);
    V1 = ld_bf8(Vb + (size_t)(16+l15)*512 + n*32 + quad*8);
  };

  short8 cK0, cK1, pK0, pK1, nK0, nK1;
  short8 cV0, cV1, mV0, mV1, nV0, nV1;
  loadK(0, cK0, cK1);
  process(0, cK0, cK1);            // writes Pbuf (slot for iter 0)
  loadK(1, pK0, pK1);
  loadV(0, cV0, cV1);
  loadV(1, mV0, mV1);

  #pragma unroll 2
  for (int kt2=0; kt2<16; kt2++){
    if (kt2+2 < 16){ loadK(kt2+2, nK0, nK1); loadV(kt2+2, nV0, nV1); }
    short8 aP[4];
    #pragma unroll
    for (int qt=0; qt<4; qt++)
      aP[qt] = ld_bf8(&Pbuf[wave][qt][l15][quad*8]);   // read BEFORE overwrite
    __builtin_amdgcn_s_setprio(1);
    #pragma unroll
    for (int qt=0; qt<4; qt++){
      O[qt][0] = __builtin_amdgcn_mfma_f32_16x16x32_bf16(aP[qt], cV0, O[qt][0], 0,0,0);
      O[qt][1] = __builtin_amdgcn_mfma_f32_16x16x32_bf16(aP[qt], cV1, O[qt][1], 0,0,0);
    }
    __builtin_amdgcn_s_setprio(0);
    if (kt2+1 < 16) process(kt2+1, pK0, pK1);          // overwrite (reads done)
    pK0 = nK0; pK1 = nK1;
    cV0 = mV0; cV1 = mV1; mV0 = nV0; mV1 = nV1;
  }

  #pragma unroll
  for (int qt=0; qt<4; qt++){
    float l = ls[qt];
    l += __shfl_xor(l,16); l += __shfl_xor(l,32);
    float linv = (l > 0.f) ? 1.0f/l : 0.f;
    float iv[4];
    #pragma unroll
    for (int r=0; r<4; r++) iv[r] = __shfl(linv, quad*4 + r);
    size_t rq = (size_t)(b*Ss + q0 + qt*16);
    #pragma unroll
    for (int nt=0; nt<2; nt++)
      #pragma unroll
      for (int r=0; r<4; r++)
        AO[(rq + quad*4 + r)*256 + h*32 + nt*16 + l15] = f2bf(O[qt][nt][r]*iv[r]);
  }
}

// ---------------- final: p = exp(logits)*valid, normalize per batch -----------
__global__ __launch_bounds__(256) void k_final(const float* __restrict__ L,
    const float* __restrict__ valid, float* __restrict__ out)
{
  __shared__ float wsum[4];
  int b = blockIdx.x, t = threadIdx.x;
  float e0 = __expf(L[b*Ss + t      ]) * valid[b*Ss + t      ];
  float e1 = __expf(L[b*Ss + 256 + t]) * valid[b*Ss + 256 + t];
  float s = e0 + e1;
  #pragma unroll
  for (int o=32;o>0;o>>=1) s += __shfl_xor(s,o);
  if ((t&63)==0) wsum[t>>6] = s;
  __syncthreads();
  float tot = wsum[0]+wsum[1]+wsum[2]+wsum[3];
  out[b*Ss + t      ] = e0/tot;
  out[b*Ss + 256 + t] = e1/tot;
}

// ============================================================================
extern "C" void kernel_launch(void* const* d_in, const int* in_sizes, int n_in,
                              void* d_out, int out_size, void* d_ws, size_t ws_size,
                              hipStream_t stream)
{
  #define F(i) ((const float*)d_in[(i)])
  bool sig = (in_sizes[33] == 256);   // signature order vs dict order
  const float* d_eqW  = F(sig?35:33); const float* d_eqb  = F(sig?36:34);
  const float* d_ekW  = F(sig?37:35); const float* d_ekb  = F(sig?38:36);
  const float* d_evW  = F(sig?39:37); const float* d_evb  = F(sig?40:38);
  const float* d_eoW  = F(sig?41:39); const float* d_eob  = F(sig?42:40);
  const float* d_ln1g = F(sig?33:41); const float* d_ln1b = F(sig?34:42);

  // ---- workspace (~163 MiB) ----
  char* w = (char*)d_ws;
  bf16_t* P0 = (bf16_t*)w; w += (size_t)Mm*Hh*2;   // 32 MiB residual (enc)
  bf16_t* P1 = (bf16_t*)w; w += (size_t)Mm*Hh*2;   // 32 MiB residual (dec)
  bf16_t* H0 = (bf16_t*)w; w += (size_t)Mm*Hh*2;   // 32 MiB Q / AO / gelu
  bf16_t* H1 = (bf16_t*)w;                          // 32 MiB K / xs alias
  bf16_t* xs = (bf16_t*)w; w += (size_t)Mm*Hh*2;
  bf16_t* H2 = (bf16_t*)w;                          // 32 MiB VT / xt alias
  bf16_t* xt = (bf16_t*)w; w += (size_t)Mm*Hh*2;
  bf16_t* Wa = (bf16_t*)w; w += (size_t)(2*16384 + 16*65536)*2;  // 2.1 MiB
  float*  valid  = (float*)w; w += (size_t)Mm*4;
  float*  logits = (float*)w; w += (size_t)Mm*4;
  float* out = (float*)d_out;

  unsigned o_sem = 0, o_tem = 16384;
  unsigned o_w[16]; for (int i=0;i<16;i++) o_w[i] = 32768 + i*65536u;
  Prep18 pp;
  const float* srcs[18] = { F(5), F(7), F(9), F(11), F(13), F(15), F(19), F(21),
                            F(25), F(27), F(29), F(31), d_eqW, d_ekW, d_evW, d_eoW,
                            F(45), F(47) };
  unsigned offs[18] = { o_sem, o_tem, o_w[0],o_w[1],o_w[2],o_w[3],o_w[4],o_w[5],
                        o_w[6],o_w[7],o_w[8],o_w[9],o_w[10],o_w[11],o_w[12],o_w[13],
                        o_w[14],o_w[15] };
  for (int i=0;i<18;i++){ pp.d[i].s = srcs[i]; pp.d[i].off = offs[i]; pp.d[i].K = (i<2)?64:256; }

  dim3 blk(256);
  dim3 blk512(512);
  dim3 gLN(Mm/4);
  dim3 gW(256);                     // 256 rows/block
  dim3 gA(NHh, Bb, 2);              // 4 q-tiles/wave: z halves to 2
  dim3 gP(256, 18);
  const float* NF = nullptr; const bf16_t* NB = nullptr;
  // 1/sqrt(32) * log2(e) folded into Q so attention uses native exp2
  const float QS = 0.17677669529663687f * 1.4426950408889634f;

  k_prep<<<gP, blk, 0, stream>>>(pp, Wa);
  k_ln0<<<gLN, blk, 0, stream>>>(F(0), F(1),F(2), F(3),F(4), xs, xt, valid);

  // emb pair (K=64)
  k_wgemm<0,0,64><<<gW, blk512, 0, stream>>>(xs, Wa+o_sem, F(6), P0, NB, NF,NF,NF,NF, 1.0f);
  k_wgemm<0,0,64><<<gW, blk512, 0, stream>>>(xt, Wa+o_tem, F(8), P1, NB, NF,NF,NF,NF, 1.0f);

  // ---- encoder ----
  k_wgemm<0,0,256><<<gW, blk512, 0, stream>>>(P0, Wa+o_w[0], F(10), H0, NB, NF,NF,NF,NF, QS);
  k_wgemm<0,0,256><<<gW, blk512, 0, stream>>>(P0, Wa+o_w[1], F(12), H1, NB, NF,NF,NF,NF, 1.0f);
  k_wgemm<0,2,256><<<gW, blk512, 0, stream>>>(P0, Wa+o_w[2], F(14), H2, NB, NF,NF,NF,NF, 1.0f);
  k_attn<<<gA, blk, 0, stream>>>(H0, H1, H2, valid, H0);
  k_wgemm<0,3,256><<<gW, blk512, 0, stream>>>(H0, Wa+o_w[3], F(16), P0, P0, F(17),F(18), NF,NF, 1.0f);
  k_wgemm<1,0,256><<<gW, blk512, 0, stream>>>(P0, Wa+o_w[4], F(20), H0, NB, NF,NF,NF,NF, 1.0f);
  k_wgemm<0,3,256><<<gW, blk512, 0, stream>>>(H0, Wa+o_w[5], F(22), P0, P0, F(23),F(24), NF,NF, 1.0f);

  // ---- decoder self-attention ----
  k_wgemm<0,0,256><<<gW, blk512, 0, stream>>>(P1, Wa+o_w[6], F(26), H0, NB, NF,NF,NF,NF, QS);
  k_wgemm<0,0,256><<<gW, blk512, 0, stream>>>(P1, Wa+o_w[7], F(28), H1, NB, NF,NF,NF,NF, 1.0f);
  k_wgemm<0,2,256><<<gW, blk512, 0, stream>>>(P1, Wa+o_w[8], F(30), H2, NB, NF,NF,NF,NF, 1.0f);
  k_attn<<<gA, blk, 0, stream>>>(H0, H1, H2, valid, H0);
  k_wgemm<0,3,256><<<gW, blk512, 0, stream>>>(H0, Wa+o_w[9], F(32), P1, P1, d_ln1g,d_ln1b, NF,NF, 1.0f);

  // ---- decoder cross-attention: Q from P1, K/V from P0 ----
  k_wgemm<0,0,256><<<gW, blk512, 0, stream>>>(P1, Wa+o_w[10], d_eqb, H0, NB, NF,NF,NF,NF, QS);
  k_wgemm<0,0,256><<<gW, blk512, 0, stream>>>(P0, Wa+o_w[11], d_ekb, H1, NB, NF,NF,NF,NF, 1.0f);
  k_wgemm<0,2,256><<<gW, blk512, 0, stream>>>(P0, Wa+o_w[12], d_evb, H2, NB, NF,NF,NF,NF, 1.0f);
  k_attn<<<gA, blk, 0, stream>>>(H0, H1, H2, valid, H0);
  k_wgemm<0,3,256><<<gW, blk512, 0, stream>>>(H0, Wa+o_w[13], d_eob, P1, P1, F(43),F(44), NF,NF, 1.0f);

  // ---- decoder FFN + fused ln3 + logits ----
  k_wgemm<1,0,256><<<gW, blk512, 0, stream>>>(P1, Wa+o_w[14], F(46), H0, NB, NF,NF,NF,NF, 1.0f);
  k_wgemm<0,5,256><<<gW, blk512, 0, stream>>>(H0, Wa+o_w[15], F(48), logits, P1, F(49),F(50), F(51),F(52), 1.0f);

  k_final<<<dim3(Bb), blk, 0, stream>>>(logits, valid, out);
  #undef F
}

// Round 16
// 820.192 us; speedup vs baseline: 1.6052x; 1.1298x over previous
//
#include <hip/hip_runtime.h>
#include <hip/hip_bf16.h>

// ============================================================================
// TransformerChoiceNet forward. Round 30: r15 (926.6us, attn 102us verified) +
// ONE isolated wgemm change: A-prefetch ring deepened to 2 kc (3-slot,
// fully-unrolled compile-time indexing; +8 VGPR, no split-stage). Targets the
// exposed ~200cy L2/L3 A-latency per kc at 1 block/CU (no cross-block hiding).
// k_attn (4 q-tiles/wave) and all other kernels byte-identical to r15.
// B=128 S=512 D=64 H=256 NH=8 HD=32, M=B*S=65536.
// ============================================================================

#define Bb  128
#define Ss  512
#define Hh  256
#define NHh 8
#define Mm  (Bb*Ss)

typedef unsigned short bf16_t;
typedef __attribute__((ext_vector_type(8))) short short8;
typedef __attribute__((ext_vector_type(4))) float f32x4;

__device__ __forceinline__ float bf2f(bf16_t h){
  union { unsigned int u; float f; } v; v.u = ((unsigned int)h)<<16; return v.f;
}
__device__ __forceinline__ bf16_t f2bf(float f){
  union { float f; unsigned int u; } v; v.f = f;
  unsigned int r = (v.u + 0x7fffu + ((v.u>>16)&1u)) >> 16;   // RNE
  return (bf16_t)r;
}
__device__ __forceinline__ unsigned pk_bf16(float a, float b){  // packed RNE cvt
  union { __hip_bfloat162 h; unsigned u; } v;
  v.h = __float22bfloat162_rn(float2{a,b});
  return v.u;
}
__device__ __forceinline__ short8 ld_bf8(const bf16_t* p){   // 16B load
  union { uint4 u; short8 s; } v; v.u = *(const uint4*)p; return v.s;
}
__device__ __forceinline__ void gload16(const bf16_t* g, bf16_t* l){
  __builtin_amdgcn_global_load_lds(
      (const __attribute__((address_space(1))) void*)g,
      (__attribute__((address_space(3))) void*)l, 16, 0, 0);
}
__device__ __forceinline__ float exp2_hw(float x){           // native 2^x
  float r; asm("v_exp_f32 %0, %1" : "=v"(r) : "v"(x)); return r;
}
__device__ __forceinline__ float gelu_f(float x){
  // NewGELU; tanh via native exp + rcp: tanh(u) = 1 - 2/(e^{2u}+1)
  float u = 0.7978845608028654f*(x + 0.044715f*x*x*x);
  float e = __expf(2.0f*u);
  float th = 1.0f - 2.0f*__builtin_amdgcn_rcpf(e + 1.0f);
  return 0.5f*x*(1.0f + th);
}

// ---------------- weight prep: fp32 W[k][n] -> bf16 Wt[n][k] ------------------
struct PrepDesc { const float* s; unsigned off; int K; };
struct Prep18  { PrepDesc d[18]; };

__global__ __launch_bounds__(256) void k_prep(Prep18 p, bf16_t* __restrict__ arena)
{
  PrepDesc dd = p.d[blockIdx.y];
  int i = blockIdx.x*256 + threadIdx.x;
  if (i < dd.K*256){
    int k = i>>8, n = i&255;
    arena[dd.off + n*dd.K + k] = f2bf(dd.s[i]);
  }
}

// ---------------- LN0 (two gains) + valid mask; bf16 out ----------------------
__global__ __launch_bounds__(256) void k_ln0(const float* __restrict__ src,
    const float* __restrict__ gs, const float* __restrict__ bs,
    const float* __restrict__ gt, const float* __restrict__ bt,
    bf16_t* __restrict__ xs, bf16_t* __restrict__ xt, float* __restrict__ valid)
{
  int row  = blockIdx.x*4 + (threadIdx.x>>6);
  int lane = threadIdx.x & 63;
  float x = src[(size_t)row*64 + lane];
  float s = x;
  #pragma unroll
  for (int o=32;o>0;o>>=1) s += __shfl_xor(s,o);
  float mean = s*(1.0f/64.0f);
  float d = x - mean;
  float ss = d*d;
  #pragma unroll
  for (int o=32;o>0;o>>=1) ss += __shfl_xor(ss,o);
  float r = rsqrtf(ss*(1.0f/64.0f) + 1e-5f);
  float xn = d*r;
  xs[(size_t)row*64+lane] = f2bf(xn*gs[lane] + bs[lane]);
  xt[(size_t)row*64+lane] = f2bf(xn*gt[lane] + bt[lane]);
  if (lane==0) valid[row] = (s != 0.0f) ? 1.0f : 0.0f;
}

// ---------------- weight-resident GEMM, barrier-free main loop ----------------
// Block = 512 thr (8 waves), grid = 256 blocks, 256 rows/block, 32 rows/wave.
// W fully LDS-resident, frag-blocked: Ws[(kc*16+nt)*512 + lane*8].
// A-prefetch: 2-deep ring (3 slots, compile-time indexed under full unroll).
// OUTM: 0 bf16 C[M,256] (EPI 0=id(*cs) / 1=gelu) | 2 bf16 VT[b][n][s] |
//       3 LN(Pres+(acc+b)) -> bf16 | 5 LN -> dot outW -> fp32 logits.
template<int EPI, int OUTM, int KK>
__global__ __launch_bounds__(512,2) void k_wgemm(const bf16_t* __restrict__ A,
    const bf16_t* __restrict__ Wt, const float* __restrict__ bias,
    void* __restrict__ Cv, const bf16_t* __restrict__ Pres,
    const float* __restrict__ g, const float* __restrict__ bb,
    const float* __restrict__ oW, const float* __restrict__ obp, float cs)
{
  constexpr int NKC  = KK/32;       // 8 (K=256) or 2 (K=64)
  constexpr int IDS  = 16*NKC;      // frag blocks
  constexpr int PERW = IDS/8;
  __shared__ bf16_t Ws[IDS*512];    // 128 KB (K=256) / 32 KB (K=64)

  int t = threadIdx.x, w = t>>6, lane = t&63, l15 = lane&15, quad = lane>>4;
  int r0 = blockIdx.x*256 + w*32;

  #pragma unroll
  for (int j=0; j<PERW; j++){       // stage FULL W once, conflict-free layout
    int id = w*PERW + j; int kc = id>>4, nt = id&15;
    gload16(Wt + (size_t)(nt*16 + l15)*KK + kc*32 + quad*8, &Ws[id*512]);
  }
  // A prefetch ring, 2 deep — first two kc pairs issued before the barrier
  short8 af0[3], af1[3];
  af0[0] = ld_bf8(A + (size_t)(r0      + l15)*KK + quad*8);
  af1[0] = ld_bf8(A + (size_t)(r0 + 16 + l15)*KK + quad*8);
  if (NKC > 1){
    af0[1] = ld_bf8(A + (size_t)(r0      + l15)*KK + 32 + quad*8);
    af1[1] = ld_bf8(A + (size_t)(r0 + 16 + l15)*KK + 32 + quad*8);
  }
  __syncthreads();                  // ONLY barrier in the kernel

  f32x4 z = {0.f,0.f,0.f,0.f};
  f32x4 acc0[16], acc1[16];
  #pragma unroll
  for (int nt=0; nt<16; nt++){ acc0[nt] = z; acc1[nt] = z; }

  #pragma unroll
  for (int kc=0; kc<NKC; kc++){
    if (kc+2 < NKC){                // keep 2 kc in flight (L2/L3 ~200cy)
      af0[(kc+2)%3] = ld_bf8(A + (size_t)(r0      + l15)*KK + (kc+2)*32 + quad*8);
      af1[(kc+2)%3] = ld_bf8(A + (size_t)(r0 + 16 + l15)*KK + (kc+2)*32 + quad*8);
    }
    short8 a0 = af0[kc%3], a1 = af1[kc%3];
    #pragma unroll
    for (int nt=0; nt<16; nt++){
      short8 b = ld_bf8(&Ws[(kc*16 + nt)*512 + lane*8]);
      acc0[nt] = __builtin_amdgcn_mfma_f32_16x16x32_bf16(a0, b, acc0[nt], 0,0,0);
      acc1[nt] = __builtin_amdgcn_mfma_f32_16x16x32_bf16(a1, b, acc1[nt], 0,0,0);
    }
  }

  float bv[16];
  #pragma unroll
  for (int nt=0; nt<16; nt++) bv[nt] = bias[nt*16 + l15];

  if (OUTM==0){
    auto epi = [&](f32x4 (&ac)[16], int tt){
      int rowb = r0 + tt*16 + quad*4;
      #pragma unroll
      for (int nt=0; nt<16; nt++)
        #pragma unroll
        for (int r=0; r<4; r++){
          float v = ac[nt][r] + bv[nt];
          v = (EPI==1) ? gelu_f(v) : v*cs;
          ((bf16_t*)Cv)[(size_t)(rowb + r)*256 + nt*16 + l15] = f2bf(v);
        }
    };
    epi(acc0, 0); epi(acc1, 1);
  } else if (OUTM==2){
    auto epi = [&](f32x4 (&ac)[16], int tt){
      int m = r0 + tt*16 + quad*4;
      #pragma unroll
      for (int nt=0; nt<16; nt++){
        int col = nt*16 + l15;
        uint2 pk = { pk_bf16(ac[nt][0]+bv[nt], ac[nt][1]+bv[nt]),
                     pk_bf16(ac[nt][2]+bv[nt], ac[nt][3]+bv[nt]) };
        *(uint2*)&((bf16_t*)Cv)[((size_t)((m>>9)*256 + col))*512 + (m&511)] = pk;
      }
    };
    epi(acc0, 0); epi(acc1, 1);
  } else {
    float gv[16], bbv[16], wv[16];
    #pragma unroll
    for (int nt=0; nt<16; nt++){ gv[nt] = g[nt*16+l15]; bbv[nt] = bb[nt*16+l15]; }
    if (OUTM==5)
      #pragma unroll
      for (int nt=0; nt<16; nt++) wv[nt] = oW[nt*16+l15];
    float ob0 = (OUTM==5) ? obp[0] : 0.f;

    auto epi = [&](f32x4 (&ac)[16], int tt){
      #pragma unroll
      for (int r=0; r<4; r++){
        int row = r0 + tt*16 + quad*4 + r;
        const bf16_t* pr = Pres + (size_t)row*256;
        float v[16]; float s = 0.f, q = 0.f;
        #pragma unroll
        for (int nt=0; nt<16; nt++){
          v[nt] = ac[nt][r] + bv[nt] + bf2f(pr[nt*16 + l15]);
          s += v[nt]; q += v[nt]*v[nt];
        }
        s += __shfl_xor(s,1); s += __shfl_xor(s,2);
        s += __shfl_xor(s,4); s += __shfl_xor(s,8);
        q += __shfl_xor(q,1); q += __shfl_xor(q,2);
        q += __shfl_xor(q,4); q += __shfl_xor(q,8);
        float mean = s*(1.0f/256.0f);
        float var  = q*(1.0f/256.0f) - mean*mean;
        float rstd = rsqrtf(var + 1e-5f);
        if (OUTM==3){
          bf16_t* po = (bf16_t*)Cv + (size_t)row*256;
          #pragma unroll
          for (int nt=0; nt<16; nt++)
            po[nt*16 + l15] = f2bf((v[nt]-mean)*rstd*gv[nt] + bbv[nt]);
        } else {
          float s2 = 0.f;
          #pragma unroll
          for (int nt=0; nt<16; nt++)
            s2 += ((v[nt]-mean)*rstd*gv[nt] + bbv[nt]) * wv[nt];
          s2 += __shfl_xor(s2,1); s2 += __shfl_xor(s2,2);
          s2 += __shfl_xor(s2,4); s2 += __shfl_xor(s2,8);
          if (l15==0) ((float*)Cv)[row] = s2 + ob0;
        }
      }
    };
    epi(acc0, 0); epi(acc1, 1);
  }
}

// ---------------- MFMA attention: 4 q-tiles/wave, single P slot (r15) ---------
__global__ __launch_bounds__(256) void k_attn(const bf16_t* __restrict__ Qm,
    const bf16_t* __restrict__ Km, const bf16_t* __restrict__ VT,
    const float* __restrict__ valid, bf16_t* __restrict__ AO)
{
  __shared__ bf16_t Pbuf[4][4][16][40];      // [wave][qt][q][key] 20 KB
  __shared__ float  Smask[512];              // 0 or -1e10*log2e
  int t = threadIdx.x, wave = t>>6, lane = t&63, l15 = lane&15, quad = lane>>4;
  int lid = blockIdx.x + 8*blockIdx.y + 1024*blockIdx.z;
  int hp = lid & 3, pb = (lid>>2)&1, g = (lid>>3)&3, bh = lid>>5;
  int h  = hp*2 + (g&1);
  int qc = g>>1;
  int b  = bh*2 + pb;
  int q0 = qc*256 + wave*64;

  Smask[t]     = (valid[b*Ss + t      ] != 0.f) ? 0.f : -1.44269504e10f;
  Smask[t+256] = (valid[b*Ss + t + 256] != 0.f) ? 0.f : -1.44269504e10f;
  __syncthreads();

  short8 aQ[4];
  #pragma unroll
  for (int qt=0; qt<4; qt++)
    aQ[qt] = ld_bf8(Qm + (size_t)(b*Ss + q0 + qt*16 + l15)*256 + h*32 + quad*8);
  const bf16_t* Kb = Km + (size_t)(b*Ss)*256 + h*32;          // + key*256
  const bf16_t* Vb = VT + ((size_t)b*256 + h*32)*512;         // + d*512 + key

  f32x4 z = {0.f,0.f,0.f,0.f};
  f32x4 O[4][2];
  #pragma unroll
  for (int qt=0; qt<4; qt++){ O[qt][0] = z; O[qt][1] = z; }
  float ls[4] = {0.f,0.f,0.f,0.f};

  auto process = [&](int kt2n, short8 K0, short8 K1){
    #pragma unroll
    for (int half=0; half<2; half++){
      short8 aK = half ? K1 : K0;
      int ktile = kt2n*2 + half;
      float4 mb = *(const float4*)&Smask[ktile*16 + quad*4];
      #pragma unroll
      for (int qt=0; qt<4; qt++){
        __builtin_amdgcn_s_setprio(1);
        f32x4 sq = __builtin_amdgcn_mfma_f32_16x16x32_bf16(aK, aQ[qt], z, 0,0,0);
        __builtin_amdgcn_s_setprio(0);
        float p0 = exp2_hw(sq[0] + mb.x);    // Q pre-scaled by QS*log2e
        float p1 = exp2_hw(sq[1] + mb.y);
        float p2 = exp2_hw(sq[2] + mb.z);
        float p3 = exp2_hw(sq[3] + mb.w);
        ls[qt] += (p0+p1)+(p2+p3);
        uint2 wq = { pk_bf16(p0,p1), pk_bf16(p2,p3) };
        *(uint2*)&Pbuf[wave][qt][l15][half*16 + quad*4] = wq;
      }
    }
  };
  auto loadK = [&](int n, short8& K0, short8& K1){
    K0 = ld_bf8(Kb + (size_t)((n*2  )*16 + l15)*256 + quad*8);
    K1 = ld_bf8(Kb + (size_t)((n*2+1)*16 + l15)*256 + quad*8);
  };
  auto loadV = [&](int n, short8& V0, short8& V1){
    V0 = ld_bf8(Vb + (size_t)(l15   )*512 + n*32 + quad*8);
    V1 = ld_bf8(Vb + (size_t)(16+l15)*512 + n*32 + quad*8);
  };

  short8 cK0, cK1, pK0, pK1, nK0, nK1;
  short8 cV0, cV1, mV0, mV1, nV0, nV1;
  loadK(0, cK0, cK1);
  process(0, cK0, cK1);            // writes Pbuf (slot for iter 0)
  loadK(1, pK0, pK1);
  loadV(0, cV0, cV1);
  loadV(1, mV0, mV1);

  #pragma unroll 2
  for (int kt2=0; kt2<16; kt2++){
    if (kt2+2 < 16){ loadK(kt2+2, nK0, nK1); loadV(kt2+2, nV0, nV1); }
    short8 aP[4];
    #pragma unroll
    for (int qt=0; qt<4; qt++)
      aP[qt] = ld_bf8(&Pbuf[wave][qt][l15][quad*8]);   // read BEFORE overwrite
    __builtin_amdgcn_s_setprio(1);
    #pragma unroll
    for (int qt=0; qt<4; qt++){
      O[qt][0] = __builtin_amdgcn_mfma_f32_16x16x32_bf16(aP[qt], cV0, O[qt][0], 0,0,0);
      O[qt][1] = __builtin_amdgcn_mfma_f32_16x16x32_bf16(aP[qt], cV1, O[qt][1], 0,0,0);
    }
    __builtin_amdgcn_s_setprio(0);
    if (kt2+1 < 16) process(kt2+1, pK0, pK1);          // overwrite (reads done)
    pK0 = nK0; pK1 = nK1;
    cV0 = mV0; cV1 = mV1; mV0 = nV0; mV1 = nV1;
  }

  #pragma unroll
  for (int qt=0; qt<4; qt++){
    float l = ls[qt];
    l += __shfl_xor(l,16); l += __shfl_xor(l,32);
    float linv = (l > 0.f) ? 1.0f/l : 0.f;
    float iv[4];
    #pragma unroll
    for (int r=0; r<4; r++) iv[r] = __shfl(linv, quad*4 + r);
    size_t rq = (size_t)(b*Ss + q0 + qt*16);
    #pragma unroll
    for (int nt=0; nt<2; nt++)
      #pragma unroll
      for (int r=0; r<4; r++)
        AO[(rq + quad*4 + r)*256 + h*32 + nt*16 + l15] = f2bf(O[qt][nt][r]*iv[r]);
  }
}

// ---------------- final: p = exp(logits)*valid, normalize per batch -----------
__global__ __launch_bounds__(256) void k_final(const float* __restrict__ L,
    const float* __restrict__ valid, float* __restrict__ out)
{
  __shared__ float wsum[4];
  int b = blockIdx.x, t = threadIdx.x;
  float e0 = __expf(L[b*Ss + t      ]) * valid[b*Ss + t      ];
  float e1 = __expf(L[b*Ss + 256 + t]) * valid[b*Ss + 256 + t];
  float s = e0 + e1;
  #pragma unroll
  for (int o=32;o>0;o>>=1) s += __shfl_xor(s,o);
  if ((t&63)==0) wsum[t>>6] = s;
  __syncthreads();
  float tot = wsum[0]+wsum[1]+wsum[2]+wsum[3];
  out[b*Ss + t      ] = e0/tot;
  out[b*Ss + 256 + t] = e1/tot;
}

// ============================================================================
extern "C" void kernel_launch(void* const* d_in, const int* in_sizes, int n_in,
                              void* d_out, int out_size, void* d_ws, size_t ws_size,
                              hipStream_t stream)
{
  #define F(i) ((const float*)d_in[(i)])
  bool sig = (in_sizes[33] == 256);   // signature order vs dict order
  const float* d_eqW  = F(sig?35:33); const float* d_eqb  = F(sig?36:34);
  const float* d_ekW  = F(sig?37:35); const float* d_ekb  = F(sig?38:36);
  const float* d_evW  = F(sig?39:37); const float* d_evb  = F(sig?40:38);
  const float* d_eoW  = F(sig?41:39); const float* d_eob  = F(sig?42:40);
  const float* d_ln1g = F(sig?33:41); const float* d_ln1b = F(sig?34:42);

  // ---- workspace (~163 MiB) ----
  char* w = (char*)d_ws;
  bf16_t* P0 = (bf16_t*)w; w += (size_t)Mm*Hh*2;   // 32 MiB residual (enc)
  bf16_t* P1 = (bf16_t*)w; w += (size_t)Mm*Hh*2;   // 32 MiB residual (dec)
  bf16_t* H0 = (bf16_t*)w; w += (size_t)Mm*Hh*2;   // 32 MiB Q / AO / gelu
  bf16_t* H1 = (bf16_t*)w;                          // 32 MiB K / xs alias
  bf16_t* xs = (bf16_t*)w; w += (size_t)Mm*Hh*2;
  bf16_t* H2 = (bf16_t*)w;                          // 32 MiB VT / xt alias
  bf16_t* xt = (bf16_t*)w; w += (size_t)Mm*Hh*2;
  bf16_t* Wa = (bf16_t*)w; w += (size_t)(2*16384 + 16*65536)*2;  // 2.1 MiB
  float*  valid  = (float*)w; w += (size_t)Mm*4;
  float*  logits = (float*)w; w += (size_t)Mm*4;
  float* out = (float*)d_out;

  unsigned o_sem = 0, o_tem = 16384;
  unsigned o_w[16]; for (int i=0;i<16;i++) o_w[i] = 32768 + i*65536u;
  Prep18 pp;
  const float* srcs[18] = { F(5), F(7), F(9), F(11), F(13), F(15), F(19), F(21),
                            F(25), F(27), F(29), F(31), d_eqW, d_ekW, d_evW, d_eoW,
                            F(45), F(47) };
  unsigned offs[18] = { o_sem, o_tem, o_w[0],o_w[1],o_w[2],o_w[3],o_w[4],o_w[5],
                        o_w[6],o_w[7],o_w[8],o_w[9],o_w[10],o_w[11],o_w[12],o_w[13],
                        o_w[14],o_w[15] };
  for (int i=0;i<18;i++){ pp.d[i].s = srcs[i]; pp.d[i].off = offs[i]; pp.d[i].K = (i<2)?64:256; }

  dim3 blk(256);
  dim3 blk512(512);
  dim3 gLN(Mm/4);
  dim3 gW(256);                     // 256 rows/block
  dim3 gA(NHh, Bb, 2);              // 4 q-tiles/wave: z = 2
  dim3 gP(256, 18);
  const float* NF = nullptr; const bf16_t* NB = nullptr;
  // 1/sqrt(32) * log2(e) folded into Q so attention uses native exp2
  const float QS = 0.17677669529663687f * 1.4426950408889634f;

  k_prep<<<gP, blk, 0, stream>>>(pp, Wa);
  k_ln0<<<gLN, blk, 0, stream>>>(F(0), F(1),F(2), F(3),F(4), xs, xt, valid);

  // emb pair (K=64)
  k_wgemm<0,0,64><<<gW, blk512, 0, stream>>>(xs, Wa+o_sem, F(6), P0, NB, NF,NF,NF,NF, 1.0f);
  k_wgemm<0,0,64><<<gW, blk512, 0, stream>>>(xt, Wa+o_tem, F(8), P1, NB, NF,NF,NF,NF, 1.0f);

  // ---- encoder ----
  k_wgemm<0,0,256><<<gW, blk512, 0, stream>>>(P0, Wa+o_w[0], F(10), H0, NB, NF,NF,NF,NF, QS);
  k_wgemm<0,0,256><<<gW, blk512, 0, stream>>>(P0, Wa+o_w[1], F(12), H1, NB, NF,NF,NF,NF, 1.0f);
  k_wgemm<0,2,256><<<gW, blk512, 0, stream>>>(P0, Wa+o_w[2], F(14), H2, NB, NF,NF,NF,NF, 1.0f);
  k_attn<<<gA, blk, 0, stream>>>(H0, H1, H2, valid, H0);
  k_wgemm<0,3,256><<<gW, blk512, 0, stream>>>(H0, Wa+o_w[3], F(16), P0, P0, F(17),F(18), NF,NF, 1.0f);
  k_wgemm<1,0,256><<<gW, blk512, 0, stream>>>(P0, Wa+o_w[4], F(20), H0, NB, NF,NF,NF,NF, 1.0f);
  k_wgemm<0,3,256><<<gW, blk512, 0, stream>>>(H0, Wa+o_w[5], F(22), P0, P0, F(23),F(24), NF,NF, 1.0f);

  // ---- decoder self-attention ----
  k_wgemm<0,0,256><<<gW, blk512, 0, stream>>>(P1, Wa+o_w[6], F(26), H0, NB, NF,NF,NF,NF, QS);
  k_wgemm<0,0,256><<<gW, blk512, 0, stream>>>(P1, Wa+o_w[7], F(28), H1, NB, NF,NF,NF,NF, 1.0f);
  k_wgemm<0,2,256><<<gW, blk512, 0, stream>>>(P1, Wa+o_w[8], F(30), H2, NB, NF,NF,NF,NF, 1.0f);
  k_attn<<<gA, blk, 0, stream>>>(H0, H1, H2, valid, H0);
  k_wgemm<0,3,256><<<gW, blk512, 0, stream>>>(H0, Wa+o_w[9], F(32), P1, P1, d_ln1g,d_ln1b, NF,NF, 1.0f);

  // ---- decoder cross-attention: Q from P1, K/V from P0 ----
  k_wgemm<0,0,256><<<gW, blk512, 0, stream>>>(P1, Wa+o_w[10], d_eqb, H0, NB, NF,NF,NF,NF, QS);
  k_wgemm<0,0,256><<<gW, blk512, 0, stream>>>(P0, Wa+o_w[11], d_ekb, H1, NB, NF,NF,NF,NF, 1.0f);
  k_wgemm<0,2,256><<<gW, blk512, 0, stream>>>(P0, Wa+o_w[12], d_evb, H2, NB, NF,NF,NF,NF, 1.0f);
  k_attn<<<gA, blk, 0, stream>>>(H0, H1, H2, valid, H0);
  k_wgemm<0,3,256><<<gW, blk512, 0, stream>>>(H0, Wa+o_w[13], d_eob, P1, P1, F(43),F(44), NF,NF, 1.0f);

  // ---- decoder FFN + fused ln3 + logits ----
  k_wgemm<1,0,256><<<gW, blk512, 0, stream>>>(P1, Wa+o_w[14], F(46), H0, NB, NF,NF,NF,NF, 1.0f);
  k_wgemm<0,5,256><<<gW, blk512, 0, stream>>>(H0, Wa+o_w[15], F(48), logits, P1, F(49),F(50), F(51),F(52), 1.0f);

  k_final<<<dim3(Bb), blk, 0, stream>>>(logits, valid, out);
  #undef F
}

// Round 17
// 815.117 us; speedup vs baseline: 1.6152x; 1.0062x over previous
//
#include <hip/hip_runtime.h>
#include <hip/hip_bf16.h>

// ============================================================================
// TransformerChoiceNet forward. Round 31: r16 (820.2us) + ONE isolated wgemm
// change: split W-stage within the SAME LDS buffer — half1 (kc<NKC/2) staged
// before barrier1; half2 issued as async gload16 right AFTER barrier1 (zero
// VGPR cost) and drained by barrier2 after the half1 compute phase covers its
// latency. No extra LDS, no extra registers, one extra barrier. k_attn
// (4 q-tiles/wave) and all other kernels byte-identical to r16.
// B=128 S=512 D=64 H=256 NH=8 HD=32, M=B*S=65536.
// ============================================================================

#define Bb  128
#define Ss  512
#define Hh  256
#define NHh 8
#define Mm  (Bb*Ss)

typedef unsigned short bf16_t;
typedef __attribute__((ext_vector_type(8))) short short8;
typedef __attribute__((ext_vector_type(4))) float f32x4;

__device__ __forceinline__ float bf2f(bf16_t h){
  union { unsigned int u; float f; } v; v.u = ((unsigned int)h)<<16; return v.f;
}
__device__ __forceinline__ bf16_t f2bf(float f){
  union { float f; unsigned int u; } v; v.f = f;
  unsigned int r = (v.u + 0x7fffu + ((v.u>>16)&1u)) >> 16;   // RNE
  return (bf16_t)r;
}
__device__ __forceinline__ unsigned pk_bf16(float a, float b){  // packed RNE cvt
  union { __hip_bfloat162 h; unsigned u; } v;
  v.h = __float22bfloat162_rn(float2{a,b});
  return v.u;
}
__device__ __forceinline__ short8 ld_bf8(const bf16_t* p){   // 16B load
  union { uint4 u; short8 s; } v; v.u = *(const uint4*)p; return v.s;
}
__device__ __forceinline__ void gload16(const bf16_t* g, bf16_t* l){
  __builtin_amdgcn_global_load_lds(
      (const __attribute__((address_space(1))) void*)g,
      (__attribute__((address_space(3))) void*)l, 16, 0, 0);
}
__device__ __forceinline__ float exp2_hw(float x){           // native 2^x
  float r; asm("v_exp_f32 %0, %1" : "=v"(r) : "v"(x)); return r;
}
__device__ __forceinline__ float gelu_f(float x){
  // NewGELU; tanh via native exp + rcp: tanh(u) = 1 - 2/(e^{2u}+1)
  float u = 0.7978845608028654f*(x + 0.044715f*x*x*x);
  float e = __expf(2.0f*u);
  float th = 1.0f - 2.0f*__builtin_amdgcn_rcpf(e + 1.0f);
  return 0.5f*x*(1.0f + th);
}

// ---------------- weight prep: fp32 W[k][n] -> bf16 Wt[n][k] ------------------
struct PrepDesc { const float* s; unsigned off; int K; };
struct Prep18  { PrepDesc d[18]; };

__global__ __launch_bounds__(256) void k_prep(Prep18 p, bf16_t* __restrict__ arena)
{
  PrepDesc dd = p.d[blockIdx.y];
  int i = blockIdx.x*256 + threadIdx.x;
  if (i < dd.K*256){
    int k = i>>8, n = i&255;
    arena[dd.off + n*dd.K + k] = f2bf(dd.s[i]);
  }
}

// ---------------- LN0 (two gains) + valid mask; bf16 out ----------------------
__global__ __launch_bounds__(256) void k_ln0(const float* __restrict__ src,
    const float* __restrict__ gs, const float* __restrict__ bs,
    const float* __restrict__ gt, const float* __restrict__ bt,
    bf16_t* __restrict__ xs, bf16_t* __restrict__ xt, float* __restrict__ valid)
{
  int row  = blockIdx.x*4 + (threadIdx.x>>6);
  int lane = threadIdx.x & 63;
  float x = src[(size_t)row*64 + lane];
  float s = x;
  #pragma unroll
  for (int o=32;o>0;o>>=1) s += __shfl_xor(s,o);
  float mean = s*(1.0f/64.0f);
  float d = x - mean;
  float ss = d*d;
  #pragma unroll
  for (int o=32;o>0;o>>=1) ss += __shfl_xor(ss,o);
  float r = rsqrtf(ss*(1.0f/64.0f) + 1e-5f);
  float xn = d*r;
  xs[(size_t)row*64+lane] = f2bf(xn*gs[lane] + bs[lane]);
  xt[(size_t)row*64+lane] = f2bf(xn*gt[lane] + bt[lane]);
  if (lane==0) valid[row] = (s != 0.0f) ? 1.0f : 0.0f;
}

// ---------------- weight-resident GEMM, split W-stage -------------------------
// Block = 512 thr (8 waves), grid = 256 blocks, 256 rows/block, 32 rows/wave.
// W fully LDS-resident, frag-blocked: Ws[(kc*16+nt)*512 + lane*8].
// Stage: half1 (ids < IDS/2) before barrier1; half2 async after barrier1,
// drained by barrier2 (covered by half1 compute). A-prefetch 2-deep ring.
// OUTM: 0 bf16 C[M,256] (EPI 0=id(*cs) / 1=gelu) | 2 bf16 VT[b][n][s] |
//       3 LN(Pres+(acc+b)) -> bf16 | 5 LN -> dot outW -> fp32 logits.
template<int EPI, int OUTM, int KK>
__global__ __launch_bounds__(512,2) void k_wgemm(const bf16_t* __restrict__ A,
    const bf16_t* __restrict__ Wt, const float* __restrict__ bias,
    void* __restrict__ Cv, const bf16_t* __restrict__ Pres,
    const float* __restrict__ g, const float* __restrict__ bb,
    const float* __restrict__ oW, const float* __restrict__ obp, float cs)
{
  constexpr int NKC  = KK/32;       // 8 (K=256) or 2 (K=64)
  constexpr int IDS  = 16*NKC;      // frag blocks
  constexpr int PERW = IDS/8;
  constexpr int H1   = PERW/2;      // per-wave ids per half
  __shared__ bf16_t Ws[IDS*512];    // 128 KB (K=256) / 32 KB (K=64)

  int t = threadIdx.x, w = t>>6, lane = t&63, l15 = lane&15, quad = lane>>4;
  int r0 = blockIdx.x*256 + w*32;

  #pragma unroll
  for (int j=0; j<H1; j++){         // stage HALF 1: ids [0, IDS/2)
    int id = w*H1 + j; int kc = id>>4, nt = id&15;
    gload16(Wt + (size_t)(nt*16 + l15)*KK + kc*32 + quad*8, &Ws[id*512]);
  }
  // A prefetch ring, 2 deep — first two kc pairs issued before the barrier
  short8 af0[3], af1[3];
  af0[0] = ld_bf8(A + (size_t)(r0      + l15)*KK + quad*8);
  af1[0] = ld_bf8(A + (size_t)(r0 + 16 + l15)*KK + quad*8);
  if (NKC > 1){
    af0[1] = ld_bf8(A + (size_t)(r0      + l15)*KK + 32 + quad*8);
    af1[1] = ld_bf8(A + (size_t)(r0 + 16 + l15)*KK + 32 + quad*8);
  }
  __syncthreads();                  // half1 (+A0/A1) ready

  #pragma unroll
  for (int j=0; j<H1; j++){         // stage HALF 2 async: ids [IDS/2, IDS)
    int id = IDS/2 + w*H1 + j; int kc = id>>4, nt = id&15;
    gload16(Wt + (size_t)(nt*16 + l15)*KK + kc*32 + quad*8, &Ws[id*512]);
  }

  f32x4 z = {0.f,0.f,0.f,0.f};
  f32x4 acc0[16], acc1[16];
  #pragma unroll
  for (int nt=0; nt<16; nt++){ acc0[nt] = z; acc1[nt] = z; }

  #pragma unroll
  for (int kc=0; kc<NKC/2; kc++){   // compute half1 (half2 loads in flight)
    if (kc+2 < NKC){
      af0[(kc+2)%3] = ld_bf8(A + (size_t)(r0      + l15)*KK + (kc+2)*32 + quad*8);
      af1[(kc+2)%3] = ld_bf8(A + (size_t)(r0 + 16 + l15)*KK + (kc+2)*32 + quad*8);
    }
    short8 a0 = af0[kc%3], a1 = af1[kc%3];
    #pragma unroll
    for (int nt=0; nt<16; nt++){
      short8 b = ld_bf8(&Ws[(kc*16 + nt)*512 + lane*8]);
      acc0[nt] = __builtin_amdgcn_mfma_f32_16x16x32_bf16(a0, b, acc0[nt], 0,0,0);
      acc1[nt] = __builtin_amdgcn_mfma_f32_16x16x32_bf16(a1, b, acc1[nt], 0,0,0);
    }
  }
  __syncthreads();                  // half2 ready (drain covered by compute)
  #pragma unroll
  for (int kc=NKC/2; kc<NKC; kc++){ // compute half2
    if (kc+2 < NKC){
      af0[(kc+2)%3] = ld_bf8(A + (size_t)(r0      + l15)*KK + (kc+2)*32 + quad*8);
      af1[(kc+2)%3] = ld_bf8(A + (size_t)(r0 + 16 + l15)*KK + (kc+2)*32 + quad*8);
    }
    short8 a0 = af0[kc%3], a1 = af1[kc%3];
    #pragma unroll
    for (int nt=0; nt<16; nt++){
      short8 b = ld_bf8(&Ws[(kc*16 + nt)*512 + lane*8]);
      acc0[nt] = __builtin_amdgcn_mfma_f32_16x16x32_bf16(a0, b, acc0[nt], 0,0,0);
      acc1[nt] = __builtin_amdgcn_mfma_f32_16x16x32_bf16(a1, b, acc1[nt], 0,0,0);
    }
  }

  float bv[16];
  #pragma unroll
  for (int nt=0; nt<16; nt++) bv[nt] = bias[nt*16 + l15];

  if (OUTM==0){
    auto epi = [&](f32x4 (&ac)[16], int tt){
      int rowb = r0 + tt*16 + quad*4;
      #pragma unroll
      for (int nt=0; nt<16; nt++)
        #pragma unroll
        for (int r=0; r<4; r++){
          float v = ac[nt][r] + bv[nt];
          v = (EPI==1) ? gelu_f(v) : v*cs;
          ((bf16_t*)Cv)[(size_t)(rowb + r)*256 + nt*16 + l15] = f2bf(v);
        }
    };
    epi(acc0, 0); epi(acc1, 1);
  } else if (OUTM==2){
    auto epi = [&](f32x4 (&ac)[16], int tt){
      int m = r0 + tt*16 + quad*4;
      #pragma unroll
      for (int nt=0; nt<16; nt++){
        int col = nt*16 + l15;
        uint2 pk = { pk_bf16(ac[nt][0]+bv[nt], ac[nt][1]+bv[nt]),
                     pk_bf16(ac[nt][2]+bv[nt], ac[nt][3]+bv[nt]) };
        *(uint2*)&((bf16_t*)Cv)[((size_t)((m>>9)*256 + col))*512 + (m&511)] = pk;
      }
    };
    epi(acc0, 0); epi(acc1, 1);
  } else {
    float gv[16], bbv[16], wv[16];
    #pragma unroll
    for (int nt=0; nt<16; nt++){ gv[nt] = g[nt*16+l15]; bbv[nt] = bb[nt*16+l15]; }
    if (OUTM==5)
      #pragma unroll
      for (int nt=0; nt<16; nt++) wv[nt] = oW[nt*16+l15];
    float ob0 = (OUTM==5) ? obp[0] : 0.f;

    auto epi = [&](f32x4 (&ac)[16], int tt){
      #pragma unroll
      for (int r=0; r<4; r++){
        int row = r0 + tt*16 + quad*4 + r;
        const bf16_t* pr = Pres + (size_t)row*256;
        float v[16]; float s = 0.f, q = 0.f;
        #pragma unroll
        for (int nt=0; nt<16; nt++){
          v[nt] = ac[nt][r] + bv[nt] + bf2f(pr[nt*16 + l15]);
          s += v[nt]; q += v[nt]*v[nt];
        }
        s += __shfl_xor(s,1); s += __shfl_xor(s,2);
        s += __shfl_xor(s,4); s += __shfl_xor(s,8);
        q += __shfl_xor(q,1); q += __shfl_xor(q,2);
        q += __shfl_xor(q,4); q += __shfl_xor(q,8);
        float mean = s*(1.0f/256.0f);
        float var  = q*(1.0f/256.0f) - mean*mean;
        float rstd = rsqrtf(var + 1e-5f);
        if (OUTM==3){
          bf16_t* po = (bf16_t*)Cv + (size_t)row*256;
          #pragma unroll
          for (int nt=0; nt<16; nt++)
            po[nt*16 + l15] = f2bf((v[nt]-mean)*rstd*gv[nt] + bbv[nt]);
        } else {
          float s2 = 0.f;
          #pragma unroll
          for (int nt=0; nt<16; nt++)
            s2 += ((v[nt]-mean)*rstd*gv[nt] + bbv[nt]) * wv[nt];
          s2 += __shfl_xor(s2,1); s2 += __shfl_xor(s2,2);
          s2 += __shfl_xor(s2,4); s2 += __shfl_xor(s2,8);
          if (l15==0) ((float*)Cv)[row] = s2 + ob0;
        }
      }
    };
    epi(acc0, 0); epi(acc1, 1);
  }
}

// ---------------- MFMA attention: 4 q-tiles/wave, single P slot (r15) ---------
__global__ __launch_bounds__(256) void k_attn(const bf16_t* __restrict__ Qm,
    const bf16_t* __restrict__ Km, const bf16_t* __restrict__ VT,
    const float* __restrict__ valid, bf16_t* __restrict__ AO)
{
  __shared__ bf16_t Pbuf[4][4][16][40];      // [wave][qt][q][key] 20 KB
  __shared__ float  Smask[512];              // 0 or -1e10*log2e
  int t = threadIdx.x, wave = t>>6, lane = t&63, l15 = lane&15, quad = lane>>4;
  int lid = blockIdx.x + 8*blockIdx.y + 1024*blockIdx.z;
  int hp = lid & 3, pb = (lid>>2)&1, g = (lid>>3)&3, bh = lid>>5;
  int h  = hp*2 + (g&1);
  int qc = g>>1;
  int b  = bh*2 + pb;
  int q0 = qc*256 + wave*64;

  Smask[t]     = (valid[b*Ss + t      ] != 0.f) ? 0.f : -1.44269504e10f;
  Smask[t+256] = (valid[b*Ss + t + 256] != 0.f) ? 0.f : -1.44269504e10f;
  __syncthreads();

  short8 aQ[4];
  #pragma unroll
  for (int qt=0; qt<4; qt++)
    aQ[qt] = ld_bf8(Qm + (size_t)(b*Ss + q0 + qt*16 + l15)*256 + h*32 + quad*8);
  const bf16_t* Kb = Km + (size_t)(b*Ss)*256 + h*32;          // + key*256
  const bf16_t* Vb = VT + ((size_t)b*256 + h*32)*512;         // + d*512 + key

  f32x4 z = {0.f,0.f,0.f,0.f};
  f32x4 O[4][2];
  #pragma unroll
  for (int qt=0; qt<4; qt++){ O[qt][0] = z; O[qt][1] = z; }
  float ls[4] = {0.f,0.f,0.f,0.f};

  auto process = [&](int kt2n, short8 K0, short8 K1){
    #pragma unroll
    for (int half=0; half<2; half++){
      short8 aK = half ? K1 : K0;
      int ktile = kt2n*2 + half;
      float4 mb = *(const float4*)&Smask[ktile*16 + quad*4];
      #pragma unroll
      for (int qt=0; qt<4; qt++){
        __builtin_amdgcn_s_setprio(1);
        f32x4 sq = __builtin_amdgcn_mfma_f32_16x16x32_bf16(aK, aQ[qt], z, 0,0,0);
        __builtin_amdgcn_s_setprio(0);
        float p0 = exp2_hw(sq[0] + mb.x);    // Q pre-scaled by QS*log2e
        float p1 = exp2_hw(sq[1] + mb.y);
        float p2 = exp2_hw(sq[2] + mb.z);
        float p3 = exp2_hw(sq[3] + mb.w);
        ls[qt] += (p0+p1)+(p2+p3);
        uint2 wq = { pk_bf16(p0,p1), pk_bf16(p2,p3) };
        *(uint2*)&Pbuf[wave][qt][l15][half*16 + quad*4] = wq;
      }
    }
  };
  auto loadK = [&](int n, short8& K0, short8& K1){
    K0 = ld_bf8(Kb + (size_t)((n*2  )*16 + l15)*256 + quad*8);
    K1 = ld_bf8(Kb + (size_t)((n*2+1)*16 + l15)*256 + quad*8);
  };
  auto loadV = [&](int n, short8& V0, short8& V1){
    V0 = ld_bf8(Vb + (size_t)(l15   )*512 + n*32 + quad*8);
    V1 = ld_bf8(Vb + (size_t)(16+l15)*512 + n*32 + quad*8);
  };

  short8 cK0, cK1, pK0, pK1, nK0, nK1;
  short8 cV0, cV1, mV0, mV1, nV0, nV1;
  loadK(0, cK0, cK1);
  process(0, cK0, cK1);            // writes Pbuf (slot for iter 0)
  loadK(1, pK0, pK1);
  loadV(0, cV0, cV1);
  loadV(1, mV0, mV1);

  #pragma unroll 2
  for (int kt2=0; kt2<16; kt2++){
    if (kt2+2 < 16){ loadK(kt2+2, nK0, nK1); loadV(kt2+2, nV0, nV1); }
    short8 aP[4];
    #pragma unroll
    for (int qt=0; qt<4; qt++)
      aP[qt] = ld_bf8(&Pbuf[wave][qt][l15][quad*8]);   // read BEFORE overwrite
    __builtin_amdgcn_s_setprio(1);
    #pragma unroll
    for (int qt=0; qt<4; qt++){
      O[qt][0] = __builtin_amdgcn_mfma_f32_16x16x32_bf16(aP[qt], cV0, O[qt][0], 0,0,0);
      O[qt][1] = __builtin_amdgcn_mfma_f32_16x16x32_bf16(aP[qt], cV1, O[qt][1], 0,0,0);
    }
    __builtin_amdgcn_s_setprio(0);
    if (kt2+1 < 16) process(kt2+1, pK0, pK1);          // overwrite (reads done)
    pK0 = nK0; pK1 = nK1;
    cV0 = mV0; cV1 = mV1; mV0 = nV0; mV1 = nV1;
  }

  #pragma unroll
  for (int qt=0; qt<4; qt++){
    float l = ls[qt];
    l += __shfl_xor(l,16); l += __shfl_xor(l,32);
    float linv = (l > 0.f) ? 1.0f/l : 0.f;
    float iv[4];
    #pragma unroll
    for (int r=0; r<4; r++) iv[r] = __shfl(linv, quad*4 + r);
    size_t rq = (size_t)(b*Ss + q0 + qt*16);
    #pragma unroll
    for (int nt=0; nt<2; nt++)
      #pragma unroll
      for (int r=0; r<4; r++)
        AO[(rq + quad*4 + r)*256 + h*32 + nt*16 + l15] = f2bf(O[qt][nt][r]*iv[r]);
  }
}

// ---------------- final: p = exp(logits)*valid, normalize per batch -----------
__global__ __launch_bounds__(256) void k_final(const float* __restrict__ L,
    const float* __restrict__ valid, float* __restrict__ out)
{
  __shared__ float wsum[4];
  int b = blockIdx.x, t = threadIdx.x;
  float e0 = __expf(L[b*Ss + t      ]) * valid[b*Ss + t      ];
  float e1 = __expf(L[b*Ss + 256 + t]) * valid[b*Ss + 256 + t];
  float s = e0 + e1;
  #pragma unroll
  for (int o=32;o>0;o>>=1) s += __shfl_xor(s,o);
  if ((t&63)==0) wsum[t>>6] = s;
  __syncthreads();
  float tot = wsum[0]+wsum[1]+wsum[2]+wsum[3];
  out[b*Ss + t      ] = e0/tot;
  out[b*Ss + 256 + t] = e1/tot;
}

// ============================================================================
extern "C" void kernel_launch(void* const* d_in, const int* in_sizes, int n_in,
                              void* d_out, int out_size, void* d_ws, size_t ws_size,
                              hipStream_t stream)
{
  #define F(i) ((const float*)d_in[(i)])
  bool sig = (in_sizes[33] == 256);   // signature order vs dict order
  const float* d_eqW  = F(sig?35:33); const float* d_eqb  = F(sig?36:34);
  const float* d_ekW  = F(sig?37:35); const float* d_ekb  = F(sig?38:36);
  const float* d_evW  = F(sig?39:37); const float* d_evb  = F(sig?40:38);
  const float* d_eoW  = F(sig?41:39); const float* d_eob  = F(sig?42:40);
  const float* d_ln1g = F(sig?33:41); const float* d_ln1b = F(sig?34:42);

  // ---- workspace (~163 MiB) ----
  char* w = (char*)d_ws;
  bf16_t* P0 = (bf16_t*)w; w += (size_t)Mm*Hh*2;   // 32 MiB residual (enc)
  bf16_t* P1 = (bf16_t*)w; w += (size_t)Mm*Hh*2;   // 32 MiB residual (dec)
  bf16_t* H0 = (bf16_t*)w; w += (size_t)Mm*Hh*2;   // 32 MiB Q / AO / gelu
  bf16_t* H1 = (bf16_t*)w;                          // 32 MiB K / xs alias
  bf16_t* xs = (bf16_t*)w; w += (size_t)Mm*Hh*2;
  bf16_t* H2 = (bf16_t*)w;                          // 32 MiB VT / xt alias
  bf16_t* xt = (bf16_t*)w; w += (size_t)Mm*Hh*2;
  bf16_t* Wa = (bf16_t*)w; w += (size_t)(2*16384 + 16*65536)*2;  // 2.1 MiB
  float*  valid  = (float*)w; w += (size_t)Mm*4;
  float*  logits = (float*)w; w += (size_t)Mm*4;
  float* out = (float*)d_out;

  unsigned o_sem = 0, o_tem = 16384;
  unsigned o_w[16]; for (int i=0;i<16;i++) o_w[i] = 32768 + i*65536u;
  Prep18 pp;
  const float* srcs[18] = { F(5), F(7), F(9), F(11), F(13), F(15), F(19), F(21),
                            F(25), F(27), F(29), F(31), d_eqW, d_ekW, d_evW, d_eoW,
                            F(45), F(47) };
  unsigned offs[18] = { o_sem, o_tem, o_w[0],o_w[1],o_w[2],o_w[3],o_w[4],o_w[5],
                        o_w[6],o_w[7],o_w[8],o_w[9],o_w[10],o_w[11],o_w[12],o_w[13],
                        o_w[14],o_w[15] };
  for (int i=0;i<18;i++){ pp.d[i].s = srcs[i]; pp.d[i].off = offs[i]; pp.d[i].K = (i<2)?64:256; }

  dim3 blk(256);
  dim3 blk512(512);
  dim3 gLN(Mm/4);
  dim3 gW(256);                     // 256 rows/block
  dim3 gA(NHh, Bb, 2);              // 4 q-tiles/wave: z = 2
  dim3 gP(256, 18);
  const float* NF = nullptr; const bf16_t* NB = nullptr;
  // 1/sqrt(32) * log2(e) folded into Q so attention uses native exp2
  const float QS = 0.17677669529663687f * 1.4426950408889634f;

  k_prep<<<gP, blk, 0, stream>>>(pp, Wa);
  k_ln0<<<gLN, blk, 0, stream>>>(F(0), F(1),F(2), F(3),F(4), xs, xt, valid);

  // emb pair (K=64)
  k_wgemm<0,0,64><<<gW, blk512, 0, stream>>>(xs, Wa+o_sem, F(6), P0, NB, NF,NF,NF,NF, 1.0f);
  k_wgemm<0,0,64><<<gW, blk512, 0, stream>>>(xt, Wa+o_tem, F(8), P1, NB, NF,NF,NF,NF, 1.0f);

  // ---- encoder ----
  k_wgemm<0,0,256><<<gW, blk512, 0, stream>>>(P0, Wa+o_w[0], F(10), H0, NB, NF,NF,NF,NF, QS);
  k_wgemm<0,0,256><<<gW, blk512, 0, stream>>>(P0, Wa+o_w[1], F(12), H1, NB, NF,NF,NF,NF, 1.0f);
  k_wgemm<0,2,256><<<gW, blk512, 0, stream>>>(P0, Wa+o_w[2], F(14), H2, NB, NF,NF,NF,NF, 1.0f);
  k_attn<<<gA, blk, 0, stream>>>(H0, H1, H2, valid, H0);
  k_wgemm<0,3,256><<<gW, blk512, 0, stream>>>(H0, Wa+o_w[3], F(16), P0, P0, F(17),F(18), NF,NF, 1.0f);
  k_wgemm<1,0,256><<<gW, blk512, 0, stream>>>(P0, Wa+o_w[4], F(20), H0, NB, NF,NF,NF,NF, 1.0f);
  k_wgemm<0,3,256><<<gW, blk512, 0, stream>>>(H0, Wa+o_w[5], F(22), P0, P0, F(23),F(24), NF,NF, 1.0f);

  // ---- decoder self-attention ----
  k_wgemm<0,0,256><<<gW, blk512, 0, stream>>>(P1, Wa+o_w[6], F(26), H0, NB, NF,NF,NF,NF, QS);
  k_wgemm<0,0,256><<<gW, blk512, 0, stream>>>(P1, Wa+o_w[7], F(28), H1, NB, NF,NF,NF,NF, 1.0f);
  k_wgemm<0,2,256><<<gW, blk512, 0, stream>>>(P1, Wa+o_w[8], F(30), H2, NB, NF,NF,NF,NF, 1.0f);
  k_attn<<<gA, blk, 0, stream>>>(H0, H1, H2, valid, H0);
  k_wgemm<0,3,256><<<gW, blk512, 0, stream>>>(H0, Wa+o_w[9], F(32), P1, P1, d_ln1g,d_ln1b, NF,NF, 1.0f);

  // ---- decoder cross-attention: Q from P1, K/V from P0 ----
  k_wgemm<0,0,256><<<gW, blk512, 0, stream>>>(P1, Wa+o_w[10], d_eqb, H0, NB, NF,NF,NF,NF, QS);
  k_wgemm<0,0,256><<<gW, blk512, 0, stream>>>(P0, Wa+o_w[11], d_ekb, H1, NB, NF,NF,NF,NF, 1.0f);
  k_wgemm<0,2,256><<<gW, blk512, 0, stream>>>(P0, Wa+o_w[12], d_evb, H2, NB, NF,NF,NF,NF, 1.0f);
  k_attn<<<gA, blk, 0, stream>>>(H0, H1, H2, valid, H0);
  k_wgemm<0,3,256><<<gW, blk512, 0, stream>>>(H0, Wa+o_w[13], d_eob, P1, P1, F(43),F(44), NF,NF, 1.0f);

  // ---- decoder FFN + fused ln3 + logits ----
  k_wgemm<1,0,256><<<gW, blk512, 0, stream>>>(P1, Wa+o_w[14], F(46), H0, NB, NF,NF,NF,NF, 1.0f);
  k_wgemm<0,5,256><<<gW, blk512, 0, stream>>>(H0, Wa+o_w[15], F(48), logits, P1, F(49),F(50), F(51),F(52), 1.0f);

  k_final<<<dim3(Bb), blk, 0, stream>>>(logits, valid, out);
  #undef F
}